// Round 2
// baseline (225.635 us; speedup 1.0000x reference)
//
#include <hip/hip_runtime.h>
#include <hip/hip_bf16.h>
#include <math.h>

// Problem constants
#define DIM     192
#define HEADS   6
#define HEAD_DIM 32
#define NTOK    64          // tokens per window
#define IN_CC   16
#define TTOT    32768       // 8 * 64 * 64 tokens
#define NWIN    512

using bf16x8 = __attribute__((ext_vector_type(8))) short;
using f32x4  = __attribute__((ext_vector_type(4))) float;
typedef unsigned short ushort_t;

// fp32 -> bf16 round-to-nearest-even (finite inputs)
__device__ __forceinline__ ushort_t f2b(float f) {
    unsigned u = __float_as_uint(f);
    u += 0x7fffu + ((u >> 16) & 1u);
    return (ushort_t)(u >> 16);
}
__device__ __forceinline__ unsigned pk2(float a, float b) {
    return (unsigned)f2b(a) | ((unsigned)f2b(b) << 16);
}
__device__ __forceinline__ float b2f(ushort_t u) {
    return __uint_as_float(((unsigned)u) << 16);
}

// ---------------------------------------------------------------------------
// Merged weight fp32 -> bf16 conversion INTO MFMA FRAGMENT ORDER.
// W (NxK row-major) -> W' where element (o,k) lives at
//   frag = (o/16)*(K/8) + (k/8);  W'[frag*128 + (o%16)*8 + (k%8)]
// For the qkv weight ONLY: the Q and K parts (rows [0,384)) additionally get a
// within-head output-row permutation so that the qkv GEMM's C-fragment IS the
// QK^T MFMA A/B fragment (slot s=16j+4q+r holds natural channel c=8q+4j+r).
// QK^T is invariant under a common channel permutation of q and k; V rows and
// all other weights stay in natural order.
__global__ __launch_bounds__(256) void cvt_all_kernel(
    const float* __restrict__ s0, const float* __restrict__ s1,
    const float* __restrict__ s2, const float* __restrict__ s3,
    ushort_t* __restrict__ d0, ushort_t* __restrict__ d1,
    ushort_t* __restrict__ d2, ushort_t* __restrict__ d3)
{
    const int bid = blockIdx.x;
    const float* src; ushort_t* dst; int off, K; bool perm = false;
    if (bid < 108)      { src = s0; dst = d0; off = bid;       K = 192; perm = true; }
    else if (bid < 144) { src = s1; dst = d1; off = bid - 108; K = 192; }
    else if (bid < 288) { src = s2; dst = d2; off = bid - 144; K = 192; }
    else                { src = s3; dst = d3; off = bid - 288; K = 768; }
    const int K8 = K >> 3;
    const int d  = (off * 256 + threadIdx.x) * 4;
    const int frag = d >> 7, win = d & 127;
    const int m16w = win >> 3, k7 = win & 7;
    const int oblk = frag / K8, kblk = frag - oblk * K8;
    const int o = oblk * 16 + m16w, k = kblk * 8 + k7;
    int so = o;
    if (perm && o < 384) {
        const int s = o & 31;                           // slot within head block
        const int c = (((s >> 2) & 3) << 3) | (((s >> 4) & 1) << 2) | (s & 3);
        so = (o & ~31) | c;                             // natural channel row
    }
    float4 v = *(const float4*)(src + (size_t)so * K + k);
    ushort4 ov;
    ov.x = f2b(v.x); ov.y = f2b(v.y); ov.z = f2b(v.z); ov.w = f2b(v.w);
    *(ushort4*)(dst + d) = ov;
}

// ---------------------------------------------------------------------------
// Kernel 1: LayerNorm1 fused with (B,C,H,W) -> (T,C) transpose. bf16 out only.
__global__ __launch_bounds__(256) void ln1_kernel(
    const float* __restrict__ x, const float* __restrict__ g,
    const float* __restrict__ bb, ushort_t* __restrict__ outh)
{
    __shared__ float xs[64][193];
    __shared__ float mu_s[64], rs_s[64];
    __shared__ float gs[192], bs[192];
    const int tid = threadIdx.x;
    const int t0  = blockIdx.x * 64;
    const int b   = t0 >> 12;
    const int hw0 = t0 & 4095;
    if (tid < 192) { gs[tid] = g[tid]; bs[tid] = bb[tid]; }
    const int tok = tid & 63, qq = tid >> 6;
    const float* xb = x + (size_t)b * (DIM * 4096) + hw0 + tok;
    #pragma unroll
    for (int it = 0; it < 48; ++it) {
        int c = it * 4 + qq;
        xs[tok][c] = xb[(size_t)c * 4096];
    }
    __syncthreads();
    const int tok2 = tid >> 2, p = tid & 3;
    float sum = 0.f;
    #pragma unroll
    for (int c = 0; c < 48; ++c) sum += xs[tok2][p * 48 + c];
    sum += __shfl_xor(sum, 1);
    sum += __shfl_xor(sum, 2);
    const float m = sum * (1.0f / 192.0f);
    float ss = 0.f;
    #pragma unroll
    for (int c = 0; c < 48; ++c) { float d = xs[tok2][p * 48 + c] - m; ss += d * d; }
    ss += __shfl_xor(ss, 1);
    ss += __shfl_xor(ss, 2);
    if (p == 0) {
        mu_s[tok2] = m;
        rs_s[tok2] = 1.0f / sqrtf(ss * (1.0f / 192.0f) + 1e-5f);
    }
    __syncthreads();
    ushort_t* obh = outh + (size_t)t0 * DIM;
    #pragma unroll
    for (int it = 0; it < 48; ++it) {
        int idx = it * 256 + tid;
        int tk = idx / 192, c = idx % 192;
        obh[idx] = f2b((xs[tk][c] - mu_s[tk]) * rs_s[tk] * gs[c] + bs[c]);
    }
}

// ---------------------------------------------------------------------------
// MEGA-FUSED attention: per window (block), 6 waves (wave = head).
// v2 (occupancy round): LDS cut 98304 -> 63840 B so 2 blocks/CU fit
// (occupancy 6 -> 12 waves/CU; the 512-block grid becomes fully resident).
//  - Q/K never touch LDS: qkv weights for Q/K are row-permuted at convert
//    time so the qkv GEMM's C registers ARE the QK^T MFMA fragments.
//  - S-transpose buffer quartered ([16][68] f32), P buffer halved
//    ([32][72] bf16, PV in two i-pairs), rpb shared across waves,
//    proj C staging 2-pass ([64][20] f32).
// Wave-private phases keep the no-barrier in-order-LDS-pipe pattern.
__global__ __launch_bounds__(384, 3) void attn_fused(
    const ushort_t* __restrict__ sc_h, const ushort_t* __restrict__ wqf,
    const float* __restrict__ qkv_b, const float* __restrict__ rpb_table,
    const float* __restrict__ temp, const ushort_t* __restrict__ wpf,
    const float* __restrict__ proj_b, float* __restrict__ x2)
{
    __shared__ __align__(16) char smem[63840];   // 6 arenas x 9728 + rpb 5472
    const int tid  = threadIdx.x;
    const int wave = tid >> 6, n = tid & 63;
    char* arena = smem + wave * 9728;
    float*    Ssq = (float*)arena;               // [16][68] f32 transpose qtr
    ushort_t* Ph  = (ushort_t*)arena;            // [32][72] bf16 P half (ovl)
    ushort_t* Vt  = (ushort_t*)(arena + 4608);   // [32][72] V^T slot-permuted
    float*    ksb = (float*)(arena + 9216);      // [64] slot-ordered 1/||k||
    float*    qnb = (float*)(arena + 9472);      // [64] ssq of q per token
    float*    rpb = (float*)(smem + 58368) + wave * 228;   // shared rpb slice
    ushort_t (*AoT)[200] = (ushort_t(*)[200])smem;          // 25600 B overlay
    float* Cwj = (float*)(smem + 25600 + wave * 5120);      // [64][20] f32

    const int win = blockIdx.x;
    const int h   = wave;
    const int b   = win >> 6;
    const int wh  = (win >> 3) & 7, ww = win & 7;
    const int i1  = n >> 3, j1 = n & 7;
    const int m16 = n & 15, quad = n >> 4;

    for (int r = n; r < 225; r += 64) rpb[r] = rpb_table[r * 6 + h];

    // token rows this lane covers as MFMA A-row m16 (window-scattered)
    int trow[4];
    #pragma unroll
    for (int i = 0; i < 4; ++i) {
        const int row = 16 * i + m16;
        trow[i] = b * 4096 + (wh * 8 + (row >> 3)) * 64 + ww * 8 + (row & 7);
    }

    // ---- phase 1: q, k, v GEMMs. q,k stay in REGISTERS (fragment order
    // thanks to the weight permutation); v goes to LDS as V^T. ----
    bf16x8 qA[4], kB[4];
    #pragma unroll
    for (int part = 0; part < 3; ++part) {       // 0=q, 1=k, 2=v
        const int o0 = part * 192 + h * 32;
        f32x4 pa[4][2];
        #pragma unroll
        for (int i = 0; i < 4; ++i)
            #pragma unroll
            for (int j = 0; j < 2; ++j)
                pa[i][j] = (f32x4)(0.0f);
        const ushort_t* Wb = wqf + (size_t)(o0 >> 4) * 24 * 128 + m16 * 8;
        for (int ks = 0; ks < 192; ks += 32) {
            bf16x8 af[4], wv[2];
            #pragma unroll
            for (int i = 0; i < 4; ++i)
                af[i] = *(const bf16x8*)(sc_h + (size_t)trow[i] * 192 + ks + quad * 8);
            #pragma unroll
            for (int j = 0; j < 2; ++j)
                wv[j] = *(const bf16x8*)(Wb + (size_t)(j * 24 + (ks >> 3) + quad) * 128);
            #pragma unroll
            for (int i = 0; i < 4; ++i)
                #pragma unroll
                for (int j = 0; j < 2; ++j)
                    pa[i][j] = __builtin_amdgcn_mfma_f32_16x16x32_bf16(wv[j], af[i], pa[i][j], 0, 0, 0);
        }
        if (part < 2) {
            // permuted slots: lane holds channels 8*quad + (0..7) of its tokens
            const float4 bv0 = *(const float4*)&qkv_b[o0 + 8 * quad];
            const float4 bv1 = *(const float4*)&qkv_b[o0 + 8 * quad + 4];
            float ssq[4];
            #pragma unroll
            for (int i = 0; i < 4; ++i) {
                f32x4 v0 = pa[i][0], v1 = pa[i][1];
                v0[0] += bv0.x; v0[1] += bv0.y; v0[2] += bv0.z; v0[3] += bv0.w;
                v1[0] += bv1.x; v1[1] += bv1.y; v1[2] += bv1.z; v1[3] += bv1.w;
                float sq = 0.f;
                #pragma unroll
                for (int r = 0; r < 4; ++r) sq += v0[r] * v0[r] + v1[r] * v1[r];
                ssq[i] = sq;
                bf16x8 fr;
                fr[0] = (short)f2b(v0[0]); fr[1] = (short)f2b(v0[1]);
                fr[2] = (short)f2b(v0[2]); fr[3] = (short)f2b(v0[3]);
                fr[4] = (short)f2b(v1[0]); fr[5] = (short)f2b(v1[1]);
                fr[6] = (short)f2b(v1[2]); fr[7] = (short)f2b(v1[3]);
                if (part == 0) qA[i] = fr; else kB[i] = fr;
            }
            #pragma unroll
            for (int i = 0; i < 4; ++i) {
                ssq[i] += __shfl_xor(ssq[i], 16);
                ssq[i] += __shfl_xor(ssq[i], 32);
            }
            if (quad == 0) {
                #pragma unroll
                for (int i = 0; i < 4; ++i) {
                    if (part == 0) qnb[16 * i + m16] = ssq[i];
                    else           ksb[4 * m16 + i]  = 1.0f / fmaxf(sqrtf(ssq[i]), 1e-12f);
                }
            }
        } else {
            const float4 bv0 = *(const float4*)&qkv_b[o0 + quad * 4];
            const float4 bv1 = *(const float4*)&qkv_b[o0 + 16 + quad * 4];
            #pragma unroll
            for (int i = 0; i < 4; ++i) {
                f32x4 v0 = pa[i][0], v1 = pa[i][1];
                v0[0] += bv0.x; v0[1] += bv0.y; v0[2] += bv0.z; v0[3] += bv0.w;
                v1[0] += bv1.x; v1[1] += bv1.y; v1[2] += bv1.z; v1[3] += bv1.w;
                #pragma unroll
                for (int r = 0; r < 4; ++r) {
                    Vt[(quad * 4 + r) * 72 + 4 * m16 + i]      = f2b(v0[r]);
                    Vt[(16 + quad * 4 + r) * 72 + 4 * m16 + i] = f2b(v1[r]);
                }
            }
        }
    }

    // ---- phase 2: QK^T, register-to-register (16 back-to-back MFMAs) ----
    f32x4 acc[4][4];
    #pragma unroll
    for (int i = 0; i < 4; ++i)
        #pragma unroll
        for (int j = 0; j < 4; ++j)
            acc[i][j] = __builtin_amdgcn_mfma_f32_16x16x32_bf16(qA[i], kB[j], (f32x4)(0.0f), 0, 0, 0);

    // ---- transpose S via 16-row quarter buffer (wave-local) ----
    // slot c of a row holds true k-token m = 16*(c&3)+(c>>2)
    float s[64];
    #pragma unroll
    for (int i = 0; i < 4; ++i) {
        #pragma unroll
        for (int r = 0; r < 4; ++r) {
            f32x4 vv = { acc[i][0][r], acc[i][1][r], acc[i][2][r], acc[i][3][r] };
            *(f32x4*)&Ssq[(4 * quad + r) * 68 + 4 * m16] = vv;
        }
        if ((n >> 4) == i) {
            #pragma unroll
            for (int c = 0; c < 16; ++c)
                *(float4*)&s[4 * c] = *(const float4*)&Ssq[(n & 15) * 68 + 4 * c];
        }
    }

    // ---- cosine scales (positive; preserve top-k ordering) ----
    const float qs = temp[h] / fmaxf(sqrtf(qnb[n]), 1e-12f);
    #pragma unroll
    for (int c = 0; c < 16; ++c) {
        float4 kv = *(const float4*)&ksb[4 * c];
        s[4*c+0] *= qs * kv.x; s[4*c+1] *= qs * kv.y;
        s[4*c+2] *= qs * kv.z; s[4*c+3] *= qs * kv.w;
    }

    // ---- top-16 threshold ----
    float thr = 1e30f;
    for (int it = 0; it < IN_CC; ++it) {
        float mx = -1e30f;
        #pragma unroll
        for (int m = 0; m < 64; ++m) {
            float vv = (s[m] < thr) ? s[m] : -1e30f;
            mx = fmaxf(mx, vv);
        }
        thr = mx;
    }

    // ---- mask + rpb + softmax (slot c holds true m = 16*(c&3)+(c>>2)) ----
    const int basen = i1 * 15 + j1;
    float mx = -1e30f;
    #pragma unroll
    for (int c = 0; c < 64; ++c) {
        const int m = 16 * (c & 3) + (c >> 2);
        const int i2 = m >> 3, j2 = m & 7;
        float vv = ((s[c] >= thr) ? s[c] : -100.0f)
                 + rpb[basen + (7 - i2) * 15 + (7 - j2)];
        s[c] = vv;
        mx = fmaxf(mx, vv);
    }
    float sum = 0.f;
    #pragma unroll
    for (int c = 0; c < 64; ++c) { float e = __expf(s[c] - mx); s[c] = e; sum += e; }
    const float inv = 1.0f / sum;
    #pragma unroll
    for (int c = 0; c < 64; ++c) s[c] *= inv;

    // ---- PV via MFMA, P staged in two 32-row halves (region R overlay) ----
    bf16x8 vb[2][2];
    #pragma unroll
    for (int kh2 = 0; kh2 < 2; ++kh2)
        #pragma unroll
        for (int j2 = 0; j2 < 2; ++j2)
            vb[kh2][j2] = *(const bf16x8*)&Vt[(16 * j2 + m16) * 72 + kh2 * 32 + quad * 8];

    f32x4 o[4][2];
    #pragma unroll
    for (int i = 0; i < 4; ++i)
        #pragma unroll
        for (int j2 = 0; j2 < 2; ++j2)
            o[i][j2] = (f32x4)(0.0f);
    #pragma unroll
    for (int hf = 0; hf < 2; ++hf) {
        if ((n >> 5) == hf) {
            #pragma unroll
            for (int g = 0; g < 8; ++g) {
                uint4 w;
                w.x = pk2(s[8*g+0], s[8*g+1]); w.y = pk2(s[8*g+2], s[8*g+3]);
                w.z = pk2(s[8*g+4], s[8*g+5]); w.w = pk2(s[8*g+6], s[8*g+7]);
                *(uint4*)&Ph[(n & 31) * 72 + 8 * g] = w;
            }
        }
        #pragma unroll
        for (int ih = 0; ih < 2; ++ih) {
            const int i = 2 * hf + ih;
            #pragma unroll
            for (int kh2 = 0; kh2 < 2; ++kh2) {
                bf16x8 pafr = *(const bf16x8*)&Ph[(16 * ih + m16) * 72 + kh2 * 32 + quad * 8];
                o[i][0] = __builtin_amdgcn_mfma_f32_16x16x32_bf16(pafr, vb[kh2][0], o[i][0], 0, 0, 0);
                o[i][1] = __builtin_amdgcn_mfma_f32_16x16x32_bf16(pafr, vb[kh2][1], o[i][1], 0, 0, 0);
            }
        }
    }
    __syncthreads();   // all waves done with arenas -> AoT may overlay

    // ---- O -> shared AoT tile (bf16, token-major, stride 200) ----
    #pragma unroll
    for (int i = 0; i < 4; ++i) {
        #pragma unroll
        for (int r = 0; r < 4; ++r) {
            const int row = 16 * i + 4 * quad + r;
            AoT[row][h * 32 + m16]      = f2b(o[i][0][r]);
            AoT[row][h * 32 + 16 + m16] = f2b(o[i][1][r]);
        }
    }
    __syncthreads();

    // ---- proj: wave computes outs [wave*32, wave*32+32), K=192 ----
    f32x4 pacc[4][2];
    #pragma unroll
    for (int i = 0; i < 4; ++i)
        #pragma unroll
        for (int j = 0; j < 2; ++j)
            pacc[i][j] = (f32x4)(0.0f);
    const ushort_t* Wb = wpf + (size_t)(wave * 2) * 24 * 128 + m16 * 8;
    for (int ks = 0; ks < 192; ks += 32) {
        bf16x8 af[4], wv[2];
        #pragma unroll
        for (int i = 0; i < 4; ++i)
            af[i] = *(const bf16x8*)&AoT[16 * i + m16][quad * 8 + ks];
        #pragma unroll
        for (int j = 0; j < 2; ++j)
            wv[j] = *(const bf16x8*)(Wb + (size_t)(j * 24 + (ks >> 3) + quad) * 128);
        #pragma unroll
        for (int i = 0; i < 4; ++i)
            #pragma unroll
            for (int j = 0; j < 2; ++j)
                pacc[i][j] = __builtin_amdgcn_mfma_f32_16x16x32_bf16(wv[j], af[i], pacc[i][j], 0, 0, 0);
    }

    // ---- stage C^T (+bias) per 16-ch half into Cwj[64][20], then store
    //      x2 = proj + shortcut(bf16). Wave-local: no barrier needed. ----
    #pragma unroll
    for (int j = 0; j < 2; ++j) {
        const float4 bj = *(const float4*)&proj_b[wave * 32 + 16 * j + quad * 4];
        #pragma unroll
        for (int i = 0; i < 4; ++i) {
            f32x4 v = pacc[i][j];
            v[0] += bj.x; v[1] += bj.y; v[2] += bj.z; v[3] += bj.w;
            *(f32x4*)&Cwj[(16 * i + m16) * 20 + quad * 4] = v;
        }
        #pragma unroll
        for (int q = 0; q < 4; ++q) {
            const int idx = q * 64 + n;
            const int row = idx >> 2, c4 = (idx & 3) * 4;
            const int ii = row >> 3, jj = row & 7;
            const int tt = b * 4096 + (wh * 8 + ii) * 64 + ww * 8 + jj;
            const int oc = wave * 32 + 16 * j + c4;
            float4 vv = *(const float4*)&Cwj[row * 20 + c4];
            uint2 rv = *(const uint2*)&sc_h[(size_t)tt * 192 + oc];
            vv.x += b2f((ushort_t)(rv.x & 0xffffu));
            vv.y += b2f((ushort_t)(rv.x >> 16));
            vv.z += b2f((ushort_t)(rv.y & 0xffffu));
            vv.w += b2f((ushort_t)(rv.y >> 16));
            *(float4*)&x2[(size_t)tt * DIM + oc] = vv;
        }
    }
}

// ---------------------------------------------------------------------------
// FUSED MLP kernel (r11-validated): LN2 -> fc1+GELU -> fc2 -> +res -> NCHW.
__global__ __launch_bounds__(256) void mlp_fused(
    const float* __restrict__ x2, const ushort_t* __restrict__ w1f,
    const ushort_t* __restrict__ w2f, const float* __restrict__ fc1_b,
    const float* __restrict__ fc2_b, const float* __restrict__ g2,
    const float* __restrict__ b2, float* __restrict__ outp)
{
    __shared__ __align__(16) char smem[43008];
    ushort_t (*h_h)[200] = (ushort_t(*)[200])smem;            // [64][200]
    ushort_t (*a1c)[136] = (ushort_t(*)[136])(smem + 25600);  // [64][136]
    float* gs  = (float*)(smem + 25600);                      // phase-1 only
    float* bs  = gs + 192;

    const int tid  = threadIdx.x;
    const int wave = tid >> 6, lane = tid & 63;
    const int m16 = lane & 15, quad = lane >> 4;
    const int t0 = blockIdx.x * 64;
    const int b   = t0 >> 12;
    const int hw0 = t0 & 4095;

    if (tid < 192) { gs[tid] = g2[tid]; bs[tid] = b2[tid]; }
    __syncthreads();
    {
        const int tok = tid >> 2, p = tid & 3;
        const float* rp = x2 + (size_t)(t0 + tok) * DIM + p * 48;
        float xv[48];
        #pragma unroll
        for (int c4 = 0; c4 < 12; ++c4)
            *(float4*)&xv[c4 * 4] = *(const float4*)(rp + c4 * 4);
        float sum = 0.f;
        #pragma unroll
        for (int c = 0; c < 48; ++c) sum += xv[c];
        sum += __shfl_xor(sum, 1);
        sum += __shfl_xor(sum, 2);
        const float m = sum * (1.0f / 192.0f);
        float ss = 0.f;
        #pragma unroll
        for (int c = 0; c < 48; ++c) { float d = xv[c] - m; ss += d * d; }
        ss += __shfl_xor(ss, 1);
        ss += __shfl_xor(ss, 2);
        const float rs = 1.0f / sqrtf(ss * (1.0f / 192.0f) + 1e-5f);
        ushort_t* hp = &h_h[tok][p * 48];
        #pragma unroll
        for (int c2 = 0; c2 < 24; ++c2) {
            float v0 = (xv[2*c2]   - m) * rs * gs[p * 48 + 2*c2]   + bs[p * 48 + 2*c2];
            float v1 = (xv[2*c2+1] - m) * rs * gs[p * 48 + 2*c2+1] + bs[p * 48 + 2*c2+1];
            *(unsigned*)(hp + 2 * c2) = pk2(v0, v1);
        }
    }
    __syncthreads();

    f32x4 acc2[4][3];
    #pragma unroll
    for (int i = 0; i < 4; ++i)
        #pragma unroll
        for (int j = 0; j < 3; ++j)
            acc2[i][j] = (f32x4)(0.0f);

    for (int c = 0; c < 6; ++c) {
        f32x4 acc1[4][2];
        #pragma unroll
        for (int i = 0; i < 4; ++i)
            #pragma unroll
            for (int j = 0; j < 2; ++j)
                acc1[i][j] = (f32x4)(0.0f);
        const ushort_t* Wb1 = w1f + (size_t)(c * 8 + wave * 2) * 24 * 128 + m16 * 8;
        for (int ks = 0; ks < 192; ks += 32) {
            bf16x8 af[4], wv[2];
            #pragma unroll
            for (int i = 0; i < 4; ++i)
                af[i] = *(const bf16x8*)&h_h[16 * i + m16][quad * 8 + ks];
            #pragma unroll
            for (int j = 0; j < 2; ++j)
                wv[j] = *(const bf16x8*)(Wb1 + (size_t)(j * 24 + (ks >> 3) + quad) * 128);
            #pragma unroll
            for (int i = 0; i < 4; ++i)
                #pragma unroll
                for (int j = 0; j < 2; ++j)
                    acc1[i][j] = __builtin_amdgcn_mfma_f32_16x16x32_bf16(wv[j], af[i], acc1[i][j], 0, 0, 0);
        }
        #pragma unroll
        for (int j = 0; j < 2; ++j) {
            const int o = c * 128 + wave * 32 + 16 * j + quad * 4;
            const float4 bv = *(const float4*)&fc1_b[o];
            #pragma unroll
            for (int i = 0; i < 4; ++i) {
                f32x4 v = acc1[i][j];
                v[0] += bv.x; v[1] += bv.y; v[2] += bv.z; v[3] += bv.w;
                #pragma unroll
                for (int r = 0; r < 4; ++r) {
                    float xg = v[r];
                    float e1 = __expf(xg * (1.5957691f + 0.0713548f * xg * xg)) + 1.0f;
                    v[r] = xg - xg * __builtin_amdgcn_rcpf(e1);
                }
                uint2 pkd;
                pkd.x = pk2(v[0], v[1]); pkd.y = pk2(v[2], v[3]);
                *(uint2*)&a1c[16 * i + m16][wave * 32 + 16 * j + quad * 4] = pkd;
            }
        }
        __syncthreads();
        const ushort_t* Wb2 = w2f + (size_t)(wave * 3) * 96 * 128 + m16 * 8;
        for (int ks = 0; ks < 128; ks += 32) {
            bf16x8 af2[4], wv2[3];
            #pragma unroll
            for (int i = 0; i < 4; ++i)
                af2[i] = *(const bf16x8*)&a1c[16 * i + m16][quad * 8 + ks];
            #pragma unroll
            for (int j = 0; j < 3; ++j)
                wv2[j] = *(const bf16x8*)(Wb2 + (size_t)(j * 96 + c * 16 + (ks >> 3) + quad) * 128);
            #pragma unroll
            for (int i = 0; i < 4; ++i)
                #pragma unroll
                for (int j = 0; j < 3; ++j)
                    acc2[i][j] = __builtin_amdgcn_mfma_f32_16x16x32_bf16(wv2[j], af2[i], acc2[i][j], 0, 0, 0);
        }
        __syncthreads();
    }

    float (*Cw)[68] = (float(*)[68])(smem + wave * 8704);
    float4 b2j[3];
    #pragma unroll
    for (int j = 0; j < 3; ++j)
        b2j[j] = *(const float4*)&fc2_b[wave * 48 + 16 * j + quad * 4];
    #pragma unroll
    for (int p = 0; p < 2; ++p) {
        #pragma unroll
        for (int ih = 0; ih < 2; ++ih) {
            const int i = 2 * p + ih;
            #pragma unroll
            for (int j = 0; j < 3; ++j) {
                f32x4 v = acc2[i][j];
                v[0] += b2j[j].x; v[1] += b2j[j].y; v[2] += b2j[j].z; v[3] += b2j[j].w;
                *(f32x4*)&Cw[ih * 16 + m16][16 * j + quad * 4] = v;
            }
        }
        #pragma unroll
        for (int q = 0; q < 6; ++q) {
            const int idx = q * 64 + lane;
            const int cc = idx >> 3, t4 = (idx & 7) * 4;
            const int o  = wave * 48 + cc;
            const int tb = t0 + p * 32 + t4;
            float4 vv;
            vv.x = Cw[t4 + 0][cc] + x2[(size_t)(tb + 0) * DIM + o];
            vv.y = Cw[t4 + 1][cc] + x2[(size_t)(tb + 1) * DIM + o];
            vv.z = Cw[t4 + 2][cc] + x2[(size_t)(tb + 2) * DIM + o];
            vv.w = Cw[t4 + 3][cc] + x2[(size_t)(tb + 3) * DIM + o];
            *(float4*)&outp[(size_t)b * (DIM * 4096) + (size_t)o * 4096
                            + hw0 + p * 32 + t4] = vv;
        }
    }
}

// ---------------------------------------------------------------------------
extern "C" void kernel_launch(void* const* d_in, const int* in_sizes, int n_in,
                              void* d_out, int out_size, void* d_ws, size_t ws_size,
                              hipStream_t stream)
{
    const float* x        = (const float*)d_in[0];
    const float* norm1_g  = (const float*)d_in[1];
    const float* norm1_b  = (const float*)d_in[2];
    const float* qkv_w    = (const float*)d_in[3];
    const float* qkv_b    = (const float*)d_in[4];
    const float* proj_w   = (const float*)d_in[5];
    const float* proj_b   = (const float*)d_in[6];
    const float* rpbt     = (const float*)d_in[7];
    const float* temp     = (const float*)d_in[8];
    const float* norm2_g  = (const float*)d_in[9];
    const float* norm2_b  = (const float*)d_in[10];
    const float* fc1_w    = (const float*)d_in[11];
    const float* fc1_b    = (const float*)d_in[12];
    const float* fc2_w    = (const float*)d_in[13];
    const float* fc2_b    = (const float*)d_in[14];
    float* out = (float*)d_out;

    // ws layout (bytes):
    //   [0,        12582912)  shortcut bf16 (LN1 out)
    //   [12582912, 37748736)  x2 f32
    //   [125829120,...)       weights bf16 (fragment order; qkv Q/K permuted)
    char* wsb = (char*)d_ws;
    ushort_t* shortcut_h = (ushort_t*)wsb;
    float*    x2         = (float*)(wsb + 12582912);
    ushort_t* wq  = (ushort_t*)(wsb + 125829120);      // 576x192 = 110592
    ushort_t* wp  = wq + 110592;                       // 192x192 = 36864
    ushort_t* w1  = wp + 36864;                        // 768x192 = 147456
    ushort_t* w2  = w1 + 147456;                       // 192x768 = 147456

    // 0. merged weight conversions into fragment order, one launch
    hipLaunchKernelGGL(cvt_all_kernel, dim3(432), dim3(256), 0, stream,
                       qkv_w, proj_w, fc1_w, fc2_w, wq, wp, w1, w2);

    // 1. LN1 + transpose -> shortcut bf16
    hipLaunchKernelGGL(ln1_kernel, dim3(TTOT / 64), dim3(256), 0, stream,
                       x, norm1_g, norm1_b, shortcut_h);
    // 2. fused qkv + attention + proj + residual -> x2
    hipLaunchKernelGGL(attn_fused, dim3(NWIN), dim3(384), 0, stream,
                       shortcut_h, wq, qkv_b, rpbt, temp, wp, proj_b, x2);
    // 3. fused LN2 + fc1 + GELU + fc2 + residual + NCHW transpose
    hipLaunchKernelGGL(mlp_fused, dim3(TTOT / 64), dim3(256), 0, stream,
                       x2, w1, w2, fc1_b, fc2_b, norm2_g, norm2_b, out);
}

// Round 3
// 207.250 us; speedup vs baseline: 1.0887x; 1.0887x over previous
//
#include <hip/hip_runtime.h>
#include <hip/hip_bf16.h>
#include <math.h>

// Problem constants
#define DIM     192
#define HEADS   6
#define HEAD_DIM 32
#define NTOK    64          // tokens per window
#define IN_CC   16
#define TTOT    32768       // 8 * 64 * 64 tokens
#define NWIN    512

using bf16x8 = __attribute__((ext_vector_type(8))) short;
using f32x4  = __attribute__((ext_vector_type(4))) float;
typedef unsigned short ushort_t;

// fp32 -> bf16 round-to-nearest-even (finite inputs)
__device__ __forceinline__ ushort_t f2b(float f) {
    unsigned u = __float_as_uint(f);
    u += 0x7fffu + ((u >> 16) & 1u);
    return (ushort_t)(u >> 16);
}
__device__ __forceinline__ unsigned pk2(float a, float b) {
    return (unsigned)f2b(a) | ((unsigned)f2b(b) << 16);
}
__device__ __forceinline__ float b2f(ushort_t u) {
    return __uint_as_float(((unsigned)u) << 16);
}

// ---------------------------------------------------------------------------
// Merged weight fp32 -> bf16 conversion INTO MFMA FRAGMENT ORDER.
// W (NxK row-major) -> W' where element (o,k) lives at
//   frag = (o/16)*(K/8) + (k/8);  W'[frag*128 + (o%16)*8 + (k%8)]
// For the qkv weight ONLY: the Q and K parts (rows [0,384)) additionally get a
// within-head output-row permutation so that the qkv GEMM's C-fragment IS the
// QK^T MFMA A/B fragment (slot s=16j+4q+r holds natural channel c=8q+4j+r).
// QK^T is invariant under a common channel permutation of q and k; V rows and
// all other weights stay in natural order.
__global__ __launch_bounds__(256) void cvt_all_kernel(
    const float* __restrict__ s0, const float* __restrict__ s1,
    const float* __restrict__ s2, const float* __restrict__ s3,
    ushort_t* __restrict__ d0, ushort_t* __restrict__ d1,
    ushort_t* __restrict__ d2, ushort_t* __restrict__ d3)
{
    const int bid = blockIdx.x;
    const float* src; ushort_t* dst; int off, K; bool perm = false;
    if (bid < 108)      { src = s0; dst = d0; off = bid;       K = 192; perm = true; }
    else if (bid < 144) { src = s1; dst = d1; off = bid - 108; K = 192; }
    else if (bid < 288) { src = s2; dst = d2; off = bid - 144; K = 192; }
    else                { src = s3; dst = d3; off = bid - 288; K = 768; }
    const int K8 = K >> 3;
    const int d  = (off * 256 + threadIdx.x) * 4;
    const int frag = d >> 7, win = d & 127;
    const int m16w = win >> 3, k7 = win & 7;
    const int oblk = frag / K8, kblk = frag - oblk * K8;
    const int o = oblk * 16 + m16w, k = kblk * 8 + k7;
    int so = o;
    if (perm && o < 384) {
        const int s = o & 31;                           // slot within head block
        const int c = (((s >> 2) & 3) << 3) | (((s >> 4) & 1) << 2) | (s & 3);
        so = (o & ~31) | c;                             // natural channel row
    }
    float4 v = *(const float4*)(src + (size_t)so * K + k);
    ushort4 ov;
    ov.x = f2b(v.x); ov.y = f2b(v.y); ov.z = f2b(v.z); ov.w = f2b(v.w);
    *(ushort4*)(dst + d) = ov;
}

// ---------------------------------------------------------------------------
// Kernel 1: LayerNorm1 fused with (B,C,H,W) -> (T,C) transpose. bf16 out only.
__global__ __launch_bounds__(256) void ln1_kernel(
    const float* __restrict__ x, const float* __restrict__ g,
    const float* __restrict__ bb, ushort_t* __restrict__ outh)
{
    __shared__ float xs[64][193];
    __shared__ float mu_s[64], rs_s[64];
    __shared__ float gs[192], bs[192];
    const int tid = threadIdx.x;
    const int t0  = blockIdx.x * 64;
    const int b   = t0 >> 12;
    const int hw0 = t0 & 4095;
    if (tid < 192) { gs[tid] = g[tid]; bs[tid] = bb[tid]; }
    const int tok = tid & 63, qq = tid >> 6;
    const float* xb = x + (size_t)b * (DIM * 4096) + hw0 + tok;
    #pragma unroll
    for (int it = 0; it < 48; ++it) {
        int c = it * 4 + qq;
        xs[tok][c] = xb[(size_t)c * 4096];
    }
    __syncthreads();
    const int tok2 = tid >> 2, p = tid & 3;
    float sum = 0.f;
    #pragma unroll
    for (int c = 0; c < 48; ++c) sum += xs[tok2][p * 48 + c];
    sum += __shfl_xor(sum, 1);
    sum += __shfl_xor(sum, 2);
    const float m = sum * (1.0f / 192.0f);
    float ss = 0.f;
    #pragma unroll
    for (int c = 0; c < 48; ++c) { float d = xs[tok2][p * 48 + c] - m; ss += d * d; }
    ss += __shfl_xor(ss, 1);
    ss += __shfl_xor(ss, 2);
    if (p == 0) {
        mu_s[tok2] = m;
        rs_s[tok2] = 1.0f / sqrtf(ss * (1.0f / 192.0f) + 1e-5f);
    }
    __syncthreads();
    ushort_t* obh = outh + (size_t)t0 * DIM;
    #pragma unroll
    for (int it = 0; it < 48; ++it) {
        int idx = it * 256 + tid;
        int tk = idx / 192, c = idx % 192;
        obh[idx] = f2b((xs[tk][c] - mu_s[tk]) * rs_s[tk] * gs[c] + bs[c]);
    }
}

// ---------------------------------------------------------------------------
// MEGA-FUSED attention v3: one block = TWO windows x 6 heads = 12 waves
// (768 threads). Grid = 256 blocks = exactly 1 block/CU, all resident ->
// 3 waves/SIMD latency hiding WITHOUT needing multi-workgroup co-residency
// (which round-2 showed the scheduler refused at 64 KB LDS).
//  - Q/K never touch LDS (weight rows pre-permuted; qkv C-regs ARE the
//    QK^T fragments).
//  - x2 store reverted to FULL 128-B-line writes (round-2's 64-B split
//    doubled HBM traffic via L2 read-modify-write): per i-group staging
//    through wave-local Cwi[16][36].
// LDS 127680 B static: 12 arenas x 9728 + 12 rpb x 912; phase-3 overlays
// (2x AoT 25600 + 12x Cwi 2304 = 78848) fit inside the dead arena region.
// Wave-private phases keep the no-barrier in-order-LDS-pipe pattern.
__global__ __launch_bounds__(768, 3) void attn_fused(
    const ushort_t* __restrict__ sc_h, const ushort_t* __restrict__ wqf,
    const float* __restrict__ qkv_b, const float* __restrict__ rpb_table,
    const float* __restrict__ temp, const ushort_t* __restrict__ wpf,
    const float* __restrict__ proj_b, float* __restrict__ x2)
{
    __shared__ __align__(16) char smem[127680];
    const int tid  = threadIdx.x;
    const int wave = tid >> 6, n = tid & 63;
    char* arena = smem + wave * 9728;
    float*    Ssq = (float*)arena;               // [16][68] f32 transpose qtr
    ushort_t* Ph  = (ushort_t*)arena;            // [32][72] bf16 P half (ovl)
    ushort_t* Vt  = (ushort_t*)(arena + 4608);   // [32][72] V^T slot-permuted
    float*    ksb = (float*)(arena + 9216);      // [64] slot-ordered 1/||k||
    float*    qnb = (float*)(arena + 9472);      // [64] ssq of q per token
    float*    rpb = (float*)(smem + 116736) + wave * 228;  // private rpb

    const int wloc = (wave >= 6) ? 1 : 0;        // window within block
    const int h    = wave - 6 * wloc;            // head
    ushort_t (*AoT)[200] = (ushort_t(*)[200])(smem + wloc * 25600); // overlay
    float* Cwi = (float*)(smem + 51200 + wave * 2304);   // [16][36] f32 ovl

    const int win = blockIdx.x * 2 + wloc;
    const int b   = win >> 6;
    const int wh  = (win >> 3) & 7, ww = win & 7;
    const int i1  = n >> 3, j1 = n & 7;
    const int m16 = n & 15, quad = n >> 4;

    for (int r = n; r < 225; r += 64) rpb[r] = rpb_table[r * 6 + h];

    // token rows this lane covers as MFMA A-row m16 (window-scattered)
    int trow[4];
    #pragma unroll
    for (int i = 0; i < 4; ++i) {
        const int row = 16 * i + m16;
        trow[i] = b * 4096 + (wh * 8 + (row >> 3)) * 64 + ww * 8 + (row & 7);
    }

    // ---- phase 1: q, k, v GEMMs. q,k stay in REGISTERS (fragment order
    // thanks to the weight permutation); v goes to LDS as V^T. ----
    bf16x8 qA[4], kB[4];
    #pragma unroll
    for (int part = 0; part < 3; ++part) {       // 0=q, 1=k, 2=v
        const int o0 = part * 192 + h * 32;
        f32x4 pa[4][2];
        #pragma unroll
        for (int i = 0; i < 4; ++i)
            #pragma unroll
            for (int j = 0; j < 2; ++j)
                pa[i][j] = (f32x4)(0.0f);
        const ushort_t* Wb = wqf + (size_t)(o0 >> 4) * 24 * 128 + m16 * 8;
        for (int ks = 0; ks < 192; ks += 32) {
            bf16x8 af[4], wv[2];
            #pragma unroll
            for (int i = 0; i < 4; ++i)
                af[i] = *(const bf16x8*)(sc_h + (size_t)trow[i] * 192 + ks + quad * 8);
            #pragma unroll
            for (int j = 0; j < 2; ++j)
                wv[j] = *(const bf16x8*)(Wb + (size_t)(j * 24 + (ks >> 3) + quad) * 128);
            #pragma unroll
            for (int i = 0; i < 4; ++i)
                #pragma unroll
                for (int j = 0; j < 2; ++j)
                    pa[i][j] = __builtin_amdgcn_mfma_f32_16x16x32_bf16(wv[j], af[i], pa[i][j], 0, 0, 0);
        }
        if (part < 2) {
            // permuted slots: lane holds channels 8*quad + (0..7) of its tokens
            const float4 bv0 = *(const float4*)&qkv_b[o0 + 8 * quad];
            const float4 bv1 = *(const float4*)&qkv_b[o0 + 8 * quad + 4];
            float ssq[4];
            #pragma unroll
            for (int i = 0; i < 4; ++i) {
                f32x4 v0 = pa[i][0], v1 = pa[i][1];
                v0[0] += bv0.x; v0[1] += bv0.y; v0[2] += bv0.z; v0[3] += bv0.w;
                v1[0] += bv1.x; v1[1] += bv1.y; v1[2] += bv1.z; v1[3] += bv1.w;
                float sq = 0.f;
                #pragma unroll
                for (int r = 0; r < 4; ++r) sq += v0[r] * v0[r] + v1[r] * v1[r];
                ssq[i] = sq;
                bf16x8 fr;
                fr[0] = (short)f2b(v0[0]); fr[1] = (short)f2b(v0[1]);
                fr[2] = (short)f2b(v0[2]); fr[3] = (short)f2b(v0[3]);
                fr[4] = (short)f2b(v1[0]); fr[5] = (short)f2b(v1[1]);
                fr[6] = (short)f2b(v1[2]); fr[7] = (short)f2b(v1[3]);
                if (part == 0) qA[i] = fr; else kB[i] = fr;
            }
            #pragma unroll
            for (int i = 0; i < 4; ++i) {
                ssq[i] += __shfl_xor(ssq[i], 16);
                ssq[i] += __shfl_xor(ssq[i], 32);
            }
            if (quad == 0) {
                #pragma unroll
                for (int i = 0; i < 4; ++i) {
                    if (part == 0) qnb[16 * i + m16] = ssq[i];
                    else           ksb[4 * m16 + i]  = 1.0f / fmaxf(sqrtf(ssq[i]), 1e-12f);
                }
            }
        } else {
            const float4 bv0 = *(const float4*)&qkv_b[o0 + quad * 4];
            const float4 bv1 = *(const float4*)&qkv_b[o0 + 16 + quad * 4];
            #pragma unroll
            for (int i = 0; i < 4; ++i) {
                f32x4 v0 = pa[i][0], v1 = pa[i][1];
                v0[0] += bv0.x; v0[1] += bv0.y; v0[2] += bv0.z; v0[3] += bv0.w;
                v1[0] += bv1.x; v1[1] += bv1.y; v1[2] += bv1.z; v1[3] += bv1.w;
                #pragma unroll
                for (int r = 0; r < 4; ++r) {
                    Vt[(quad * 4 + r) * 72 + 4 * m16 + i]      = f2b(v0[r]);
                    Vt[(16 + quad * 4 + r) * 72 + 4 * m16 + i] = f2b(v1[r]);
                }
            }
        }
    }

    // ---- phase 2: QK^T, register-to-register (16 back-to-back MFMAs) ----
    f32x4 acc[4][4];
    #pragma unroll
    for (int i = 0; i < 4; ++i)
        #pragma unroll
        for (int j = 0; j < 4; ++j)
            acc[i][j] = __builtin_amdgcn_mfma_f32_16x16x32_bf16(qA[i], kB[j], (f32x4)(0.0f), 0, 0, 0);

    // ---- transpose S via 16-row quarter buffer (wave-local) ----
    // slot c of a row holds true k-token m = 16*(c&3)+(c>>2)
    float s[64];
    #pragma unroll
    for (int i = 0; i < 4; ++i) {
        #pragma unroll
        for (int r = 0; r < 4; ++r) {
            f32x4 vv = { acc[i][0][r], acc[i][1][r], acc[i][2][r], acc[i][3][r] };
            *(f32x4*)&Ssq[(4 * quad + r) * 68 + 4 * m16] = vv;
        }
        if ((n >> 4) == i) {
            #pragma unroll
            for (int c = 0; c < 16; ++c)
                *(float4*)&s[4 * c] = *(const float4*)&Ssq[(n & 15) * 68 + 4 * c];
        }
    }

    // ---- cosine scales (positive; preserve top-k ordering) ----
    const float qs = temp[h] / fmaxf(sqrtf(qnb[n]), 1e-12f);
    #pragma unroll
    for (int c = 0; c < 16; ++c) {
        float4 kv = *(const float4*)&ksb[4 * c];
        s[4*c+0] *= qs * kv.x; s[4*c+1] *= qs * kv.y;
        s[4*c+2] *= qs * kv.z; s[4*c+3] *= qs * kv.w;
    }

    // ---- top-16 threshold ----
    float thr = 1e30f;
    for (int it = 0; it < IN_CC; ++it) {
        float mx = -1e30f;
        #pragma unroll
        for (int m = 0; m < 64; ++m) {
            float vv = (s[m] < thr) ? s[m] : -1e30f;
            mx = fmaxf(mx, vv);
        }
        thr = mx;
    }

    // ---- mask + rpb + softmax (slot c holds true m = 16*(c&3)+(c>>2)) ----
    const int basen = i1 * 15 + j1;
    float mx = -1e30f;
    #pragma unroll
    for (int c = 0; c < 64; ++c) {
        const int m = 16 * (c & 3) + (c >> 2);
        const int i2 = m >> 3, j2 = m & 7;
        float vv = ((s[c] >= thr) ? s[c] : -100.0f)
                 + rpb[basen + (7 - i2) * 15 + (7 - j2)];
        s[c] = vv;
        mx = fmaxf(mx, vv);
    }
    float sum = 0.f;
    #pragma unroll
    for (int c = 0; c < 64; ++c) { float e = __expf(s[c] - mx); s[c] = e; sum += e; }
    const float inv = 1.0f / sum;
    #pragma unroll
    for (int c = 0; c < 64; ++c) s[c] *= inv;

    // ---- PV via MFMA, P staged in two 32-row halves (region R overlay) ----
    bf16x8 vb[2][2];
    #pragma unroll
    for (int kh2 = 0; kh2 < 2; ++kh2)
        #pragma unroll
        for (int j2 = 0; j2 < 2; ++j2)
            vb[kh2][j2] = *(const bf16x8*)&Vt[(16 * j2 + m16) * 72 + kh2 * 32 + quad * 8];

    f32x4 o[4][2];
    #pragma unroll
    for (int i = 0; i < 4; ++i)
        #pragma unroll
        for (int j2 = 0; j2 < 2; ++j2)
            o[i][j2] = (f32x4)(0.0f);
    #pragma unroll
    for (int hf = 0; hf < 2; ++hf) {
        if ((n >> 5) == hf) {
            #pragma unroll
            for (int g = 0; g < 8; ++g) {
                uint4 w;
                w.x = pk2(s[8*g+0], s[8*g+1]); w.y = pk2(s[8*g+2], s[8*g+3]);
                w.z = pk2(s[8*g+4], s[8*g+5]); w.w = pk2(s[8*g+6], s[8*g+7]);
                *(uint4*)&Ph[(n & 31) * 72 + 8 * g] = w;
            }
        }
        #pragma unroll
        for (int ih = 0; ih < 2; ++ih) {
            const int i = 2 * hf + ih;
            #pragma unroll
            for (int kh2 = 0; kh2 < 2; ++kh2) {
                bf16x8 pafr = *(const bf16x8*)&Ph[(16 * ih + m16) * 72 + kh2 * 32 + quad * 8];
                o[i][0] = __builtin_amdgcn_mfma_f32_16x16x32_bf16(pafr, vb[kh2][0], o[i][0], 0, 0, 0);
                o[i][1] = __builtin_amdgcn_mfma_f32_16x16x32_bf16(pafr, vb[kh2][1], o[i][1], 0, 0, 0);
            }
        }
    }
    __syncthreads();   // all waves done with arenas -> AoT may overlay

    // ---- O -> shared AoT tile (bf16, token-major, stride 200) ----
    #pragma unroll
    for (int i = 0; i < 4; ++i) {
        #pragma unroll
        for (int r = 0; r < 4; ++r) {
            const int row = 16 * i + 4 * quad + r;
            AoT[row][h * 32 + m16]      = f2b(o[i][0][r]);
            AoT[row][h * 32 + 16 + m16] = f2b(o[i][1][r]);
        }
    }
    __syncthreads();

    // ---- proj: wave computes outs [h*32, h*32+32) of its window, K=192 ----
    f32x4 pacc[4][2];
    #pragma unroll
    for (int i = 0; i < 4; ++i)
        #pragma unroll
        for (int j = 0; j < 2; ++j)
            pacc[i][j] = (f32x4)(0.0f);
    const ushort_t* Wb = wpf + (size_t)(h * 2) * 24 * 128 + m16 * 8;
    for (int ks = 0; ks < 192; ks += 32) {
        bf16x8 af[4], wv[2];
        #pragma unroll
        for (int i = 0; i < 4; ++i)
            af[i] = *(const bf16x8*)&AoT[16 * i + m16][quad * 8 + ks];
        #pragma unroll
        for (int j = 0; j < 2; ++j)
            wv[j] = *(const bf16x8*)(Wb + (size_t)(j * 24 + (ks >> 3) + quad) * 128);
        #pragma unroll
        for (int i = 0; i < 4; ++i)
            #pragma unroll
            for (int j = 0; j < 2; ++j)
                pacc[i][j] = __builtin_amdgcn_mfma_f32_16x16x32_bf16(wv[j], af[i], pacc[i][j], 0, 0, 0);
    }

    // ---- per i-group: stage C^T (+bias) into Cwi[16][36], then store
    //      x2 = proj + shortcut(bf16) as FULL 128-B lines (one pass).
    //      Wave-local staging: no barrier needed (in-order LDS pipe). ----
    const float4 bj0 = *(const float4*)&proj_b[h * 32 + quad * 4];
    const float4 bj1 = *(const float4*)&proj_b[h * 32 + 16 + quad * 4];
    const int rr = n >> 2, ccc = n & 3;
    #pragma unroll
    for (int i = 0; i < 4; ++i) {
        f32x4 v0 = pacc[i][0], v1 = pacc[i][1];
        v0[0] += bj0.x; v0[1] += bj0.y; v0[2] += bj0.z; v0[3] += bj0.w;
        v1[0] += bj1.x; v1[1] += bj1.y; v1[2] += bj1.z; v1[3] += bj1.w;
        *(f32x4*)&Cwi[m16 * 36 + quad * 4]      = v0;
        *(f32x4*)&Cwi[m16 * 36 + 16 + quad * 4] = v1;
        const int tok = 16 * i + rr;
        const int ii = tok >> 3, jj = tok & 7;
        const int tt = b * 4096 + (wh * 8 + ii) * 64 + ww * 8 + jj;
        const int oc = h * 32 + ccc * 8;
        float4 w0 = *(const float4*)&Cwi[rr * 36 + ccc * 8];
        float4 w1 = *(const float4*)&Cwi[rr * 36 + ccc * 8 + 4];
        uint4 rv = *(const uint4*)&sc_h[(size_t)tt * 192 + oc];
        w0.x += b2f((ushort_t)(rv.x & 0xffffu)); w0.y += b2f((ushort_t)(rv.x >> 16));
        w0.z += b2f((ushort_t)(rv.y & 0xffffu)); w0.w += b2f((ushort_t)(rv.y >> 16));
        w1.x += b2f((ushort_t)(rv.z & 0xffffu)); w1.y += b2f((ushort_t)(rv.z >> 16));
        w1.z += b2f((ushort_t)(rv.w & 0xffffu)); w1.w += b2f((ushort_t)(rv.w >> 16));
        *(float4*)&x2[(size_t)tt * DIM + oc]     = w0;
        *(float4*)&x2[(size_t)tt * DIM + oc + 4] = w1;
    }
}

// ---------------------------------------------------------------------------
// FUSED MLP kernel (r11-validated): LN2 -> fc1+GELU -> fc2 -> +res -> NCHW.
__global__ __launch_bounds__(256) void mlp_fused(
    const float* __restrict__ x2, const ushort_t* __restrict__ w1f,
    const ushort_t* __restrict__ w2f, const float* __restrict__ fc1_b,
    const float* __restrict__ fc2_b, const float* __restrict__ g2,
    const float* __restrict__ b2, float* __restrict__ outp)
{
    __shared__ __align__(16) char smem[43008];
    ushort_t (*h_h)[200] = (ushort_t(*)[200])smem;            // [64][200]
    ushort_t (*a1c)[136] = (ushort_t(*)[136])(smem + 25600);  // [64][136]
    float* gs  = (float*)(smem + 25600);                      // phase-1 only
    float* bs  = gs + 192;

    const int tid  = threadIdx.x;
    const int wave = tid >> 6, lane = tid & 63;
    const int m16 = lane & 15, quad = lane >> 4;
    const int t0 = blockIdx.x * 64;
    const int b   = t0 >> 12;
    const int hw0 = t0 & 4095;

    if (tid < 192) { gs[tid] = g2[tid]; bs[tid] = b2[tid]; }
    __syncthreads();
    {
        const int tok = tid >> 2, p = tid & 3;
        const float* rp = x2 + (size_t)(t0 + tok) * DIM + p * 48;
        float xv[48];
        #pragma unroll
        for (int c4 = 0; c4 < 12; ++c4)
            *(float4*)&xv[c4 * 4] = *(const float4*)(rp + c4 * 4);
        float sum = 0.f;
        #pragma unroll
        for (int c = 0; c < 48; ++c) sum += xv[c];
        sum += __shfl_xor(sum, 1);
        sum += __shfl_xor(sum, 2);
        const float m = sum * (1.0f / 192.0f);
        float ss = 0.f;
        #pragma unroll
        for (int c = 0; c < 48; ++c) { float d = xv[c] - m; ss += d * d; }
        ss += __shfl_xor(ss, 1);
        ss += __shfl_xor(ss, 2);
        const float rs = 1.0f / sqrtf(ss * (1.0f / 192.0f) + 1e-5f);
        ushort_t* hp = &h_h[tok][p * 48];
        #pragma unroll
        for (int c2 = 0; c2 < 24; ++c2) {
            float v0 = (xv[2*c2]   - m) * rs * gs[p * 48 + 2*c2]   + bs[p * 48 + 2*c2];
            float v1 = (xv[2*c2+1] - m) * rs * gs[p * 48 + 2*c2+1] + bs[p * 48 + 2*c2+1];
            *(unsigned*)(hp + 2 * c2) = pk2(v0, v1);
        }
    }
    __syncthreads();

    f32x4 acc2[4][3];
    #pragma unroll
    for (int i = 0; i < 4; ++i)
        #pragma unroll
        for (int j = 0; j < 3; ++j)
            acc2[i][j] = (f32x4)(0.0f);

    for (int c = 0; c < 6; ++c) {
        f32x4 acc1[4][2];
        #pragma unroll
        for (int i = 0; i < 4; ++i)
            #pragma unroll
            for (int j = 0; j < 2; ++j)
                acc1[i][j] = (f32x4)(0.0f);
        const ushort_t* Wb1 = w1f + (size_t)(c * 8 + wave * 2) * 24 * 128 + m16 * 8;
        for (int ks = 0; ks < 192; ks += 32) {
            bf16x8 af[4], wv[2];
            #pragma unroll
            for (int i = 0; i < 4; ++i)
                af[i] = *(const bf16x8*)&h_h[16 * i + m16][quad * 8 + ks];
            #pragma unroll
            for (int j = 0; j < 2; ++j)
                wv[j] = *(const bf16x8*)(Wb1 + (size_t)(j * 24 + (ks >> 3) + quad) * 128);
            #pragma unroll
            for (int i = 0; i < 4; ++i)
                #pragma unroll
                for (int j = 0; j < 2; ++j)
                    acc1[i][j] = __builtin_amdgcn_mfma_f32_16x16x32_bf16(wv[j], af[i], acc1[i][j], 0, 0, 0);
        }
        #pragma unroll
        for (int j = 0; j < 2; ++j) {
            const int o = c * 128 + wave * 32 + 16 * j + quad * 4;
            const float4 bv = *(const float4*)&fc1_b[o];
            #pragma unroll
            for (int i = 0; i < 4; ++i) {
                f32x4 v = acc1[i][j];
                v[0] += bv.x; v[1] += bv.y; v[2] += bv.z; v[3] += bv.w;
                #pragma unroll
                for (int r = 0; r < 4; ++r) {
                    float xg = v[r];
                    float e1 = __expf(xg * (1.5957691f + 0.0713548f * xg * xg)) + 1.0f;
                    v[r] = xg - xg * __builtin_amdgcn_rcpf(e1);
                }
                uint2 pkd;
                pkd.x = pk2(v[0], v[1]); pkd.y = pk2(v[2], v[3]);
                *(uint2*)&a1c[16 * i + m16][wave * 32 + 16 * j + quad * 4] = pkd;
            }
        }
        __syncthreads();
        const ushort_t* Wb2 = w2f + (size_t)(wave * 3) * 96 * 128 + m16 * 8;
        for (int ks = 0; ks < 128; ks += 32) {
            bf16x8 af2[4], wv2[3];
            #pragma unroll
            for (int i = 0; i < 4; ++i)
                af2[i] = *(const bf16x8*)&a1c[16 * i + m16][quad * 8 + ks];
            #pragma unroll
            for (int j = 0; j < 3; ++j)
                wv2[j] = *(const bf16x8*)(Wb2 + (size_t)(j * 96 + c * 16 + (ks >> 3) + quad) * 128);
            #pragma unroll
            for (int i = 0; i < 4; ++i)
                #pragma unroll
                for (int j = 0; j < 3; ++j)
                    acc2[i][j] = __builtin_amdgcn_mfma_f32_16x16x32_bf16(wv2[j], af2[i], acc2[i][j], 0, 0, 0);
        }
        __syncthreads();
    }

    float (*Cw)[68] = (float(*)[68])(smem + wave * 8704);
    float4 b2j[3];
    #pragma unroll
    for (int j = 0; j < 3; ++j)
        b2j[j] = *(const float4*)&fc2_b[wave * 48 + 16 * j + quad * 4];
    #pragma unroll
    for (int p = 0; p < 2; ++p) {
        #pragma unroll
        for (int ih = 0; ih < 2; ++ih) {
            const int i = 2 * p + ih;
            #pragma unroll
            for (int j = 0; j < 3; ++j) {
                f32x4 v = acc2[i][j];
                v[0] += b2j[j].x; v[1] += b2j[j].y; v[2] += b2j[j].z; v[3] += b2j[j].w;
                *(f32x4*)&Cw[ih * 16 + m16][16 * j + quad * 4] = v;
            }
        }
        #pragma unroll
        for (int q = 0; q < 6; ++q) {
            const int idx = q * 64 + lane;
            const int cc = idx >> 3, t4 = (idx & 7) * 4;
            const int o  = wave * 48 + cc;
            const int tb = t0 + p * 32 + t4;
            float4 vv;
            vv.x = Cw[t4 + 0][cc] + x2[(size_t)(tb + 0) * DIM + o];
            vv.y = Cw[t4 + 1][cc] + x2[(size_t)(tb + 1) * DIM + o];
            vv.z = Cw[t4 + 2][cc] + x2[(size_t)(tb + 2) * DIM + o];
            vv.w = Cw[t4 + 3][cc] + x2[(size_t)(tb + 3) * DIM + o];
            *(float4*)&outp[(size_t)b * (DIM * 4096) + (size_t)o * 4096
                            + hw0 + p * 32 + t4] = vv;
        }
    }
}

// ---------------------------------------------------------------------------
extern "C" void kernel_launch(void* const* d_in, const int* in_sizes, int n_in,
                              void* d_out, int out_size, void* d_ws, size_t ws_size,
                              hipStream_t stream)
{
    const float* x        = (const float*)d_in[0];
    const float* norm1_g  = (const float*)d_in[1];
    const float* norm1_b  = (const float*)d_in[2];
    const float* qkv_w    = (const float*)d_in[3];
    const float* qkv_b    = (const float*)d_in[4];
    const float* proj_w   = (const float*)d_in[5];
    const float* proj_b   = (const float*)d_in[6];
    const float* rpbt     = (const float*)d_in[7];
    const float* temp     = (const float*)d_in[8];
    const float* norm2_g  = (const float*)d_in[9];
    const float* norm2_b  = (const float*)d_in[10];
    const float* fc1_w    = (const float*)d_in[11];
    const float* fc1_b    = (const float*)d_in[12];
    const float* fc2_w    = (const float*)d_in[13];
    const float* fc2_b    = (const float*)d_in[14];
    float* out = (float*)d_out;

    // ws layout (bytes):
    //   [0,        12582912)  shortcut bf16 (LN1 out)
    //   [12582912, 37748736)  x2 f32
    //   [125829120,...)       weights bf16 (fragment order; qkv Q/K permuted)
    char* wsb = (char*)d_ws;
    ushort_t* shortcut_h = (ushort_t*)wsb;
    float*    x2         = (float*)(wsb + 12582912);
    ushort_t* wq  = (ushort_t*)(wsb + 125829120);      // 576x192 = 110592
    ushort_t* wp  = wq + 110592;                       // 192x192 = 36864
    ushort_t* w1  = wp + 36864;                        // 768x192 = 147456
    ushort_t* w2  = w1 + 147456;                       // 192x768 = 147456

    // 0. merged weight conversions into fragment order, one launch
    hipLaunchKernelGGL(cvt_all_kernel, dim3(432), dim3(256), 0, stream,
                       qkv_w, proj_w, fc1_w, fc2_w, wq, wp, w1, w2);

    // 1. LN1 + transpose -> shortcut bf16
    hipLaunchKernelGGL(ln1_kernel, dim3(TTOT / 64), dim3(256), 0, stream,
                       x, norm1_g, norm1_b, shortcut_h);
    // 2. fused qkv + attention + proj + residual -> x2 (2 windows/block)
    hipLaunchKernelGGL(attn_fused, dim3(NWIN / 2), dim3(768), 0, stream,
                       shortcut_h, wq, qkv_b, rpbt, temp, wp, proj_b, x2);
    // 3. fused LN2 + fc1 + GELU + fc2 + residual + NCHW transpose
    hipLaunchKernelGGL(mlp_fused, dim3(TTOT / 64), dim3(256), 0, stream,
                       x2, w1, w2, fc1_b, fc2_b, norm2_g, norm2_b, out);
}

// Round 4
// 193.997 us; speedup vs baseline: 1.1631x; 1.0683x over previous
//
#include <hip/hip_runtime.h>
#include <hip/hip_bf16.h>
#include <math.h>

// Problem constants
#define DIM     192
#define HEADS   6
#define HEAD_DIM 32
#define NTOK    64          // tokens per window
#define IN_CC   16
#define TTOT    32768       // 8 * 64 * 64 tokens
#define NWIN    512

using bf16x8 = __attribute__((ext_vector_type(8))) short;
using f32x4  = __attribute__((ext_vector_type(4))) float;
typedef unsigned short ushort_t;

// fp32 -> bf16 round-to-nearest-even (finite inputs)
__device__ __forceinline__ ushort_t f2b(float f) {
    unsigned u = __float_as_uint(f);
    u += 0x7fffu + ((u >> 16) & 1u);
    return (ushort_t)(u >> 16);
}
__device__ __forceinline__ unsigned pk2(float a, float b) {
    return (unsigned)f2b(a) | ((unsigned)f2b(b) << 16);
}
__device__ __forceinline__ float b2f(ushort_t u) {
    return __uint_as_float(((unsigned)u) << 16);
}
__device__ __forceinline__ float m3(float a, float b, float c) {
    return fmaxf(fmaxf(a, b), c);     // clang fuses to v_max3_f32
}

// ---------------------------------------------------------------------------
// Merged weight fp32 -> bf16 conversion INTO MFMA FRAGMENT ORDER.
// W (NxK row-major) -> W' where element (o,k) lives at
//   frag = (o/16)*(K/8) + (k/8);  W'[frag*128 + (o%16)*8 + (k%8)]
// qkv weight ONLY: Q and K parts (rows [0,384)) get a within-head output-row
// permutation so the qkv GEMM's C-fragment IS the QK^T MFMA A/B fragment
// (slot s=16j+4q+r holds natural channel c=8q+4j+r). QK^T is invariant under
// a common channel permutation of q and k.
__global__ __launch_bounds__(256) void cvt_all_kernel(
    const float* __restrict__ s0, const float* __restrict__ s1,
    const float* __restrict__ s2, const float* __restrict__ s3,
    ushort_t* __restrict__ d0, ushort_t* __restrict__ d1,
    ushort_t* __restrict__ d2, ushort_t* __restrict__ d3)
{
    const int bid = blockIdx.x;
    const float* src; ushort_t* dst; int off, K; bool perm = false;
    if (bid < 108)      { src = s0; dst = d0; off = bid;       K = 192; perm = true; }
    else if (bid < 144) { src = s1; dst = d1; off = bid - 108; K = 192; }
    else if (bid < 288) { src = s2; dst = d2; off = bid - 144; K = 192; }
    else                { src = s3; dst = d3; off = bid - 288; K = 768; }
    const int K8 = K >> 3;
    const int d  = (off * 256 + threadIdx.x) * 4;
    const int frag = d >> 7, win = d & 127;
    const int m16w = win >> 3, k7 = win & 7;
    const int oblk = frag / K8, kblk = frag - oblk * K8;
    const int o = oblk * 16 + m16w, k = kblk * 8 + k7;
    int so = o;
    if (perm && o < 384) {
        const int s = o & 31;                           // slot within head block
        const int c = (((s >> 2) & 3) << 3) | (((s >> 4) & 1) << 2) | (s & 3);
        so = (o & ~31) | c;                             // natural channel row
    }
    float4 v = *(const float4*)(src + (size_t)so * K + k);
    ushort4 ov;
    ov.x = f2b(v.x); ov.y = f2b(v.y); ov.z = f2b(v.z); ov.w = f2b(v.w);
    *(ushort4*)(dst + d) = ov;
}

// ---------------------------------------------------------------------------
// Kernel 1: LayerNorm1 fused with (B,C,H,W) -> (T,C) transpose. bf16 out only.
__global__ __launch_bounds__(256) void ln1_kernel(
    const float* __restrict__ x, const float* __restrict__ g,
    const float* __restrict__ bb, ushort_t* __restrict__ outh)
{
    __shared__ float xs[64][193];
    __shared__ float mu_s[64], rs_s[64];
    __shared__ float gs[192], bs[192];
    const int tid = threadIdx.x;
    const int t0  = blockIdx.x * 64;
    const int b   = t0 >> 12;
    const int hw0 = t0 & 4095;
    if (tid < 192) { gs[tid] = g[tid]; bs[tid] = bb[tid]; }
    const int tok = tid & 63, qq = tid >> 6;
    const float* xb = x + (size_t)b * (DIM * 4096) + hw0 + tok;
    #pragma unroll
    for (int it = 0; it < 48; ++it) {
        int c = it * 4 + qq;
        xs[tok][c] = xb[(size_t)c * 4096];
    }
    __syncthreads();
    const int tok2 = tid >> 2, p = tid & 3;
    float sum = 0.f;
    #pragma unroll
    for (int c = 0; c < 48; ++c) sum += xs[tok2][p * 48 + c];
    sum += __shfl_xor(sum, 1);
    sum += __shfl_xor(sum, 2);
    const float m = sum * (1.0f / 192.0f);
    float ss = 0.f;
    #pragma unroll
    for (int c = 0; c < 48; ++c) { float d = xs[tok2][p * 48 + c] - m; ss += d * d; }
    ss += __shfl_xor(ss, 1);
    ss += __shfl_xor(ss, 2);
    if (p == 0) {
        mu_s[tok2] = m;
        rs_s[tok2] = 1.0f / sqrtf(ss * (1.0f / 192.0f) + 1e-5f);
    }
    __syncthreads();
    ushort_t* obh = outh + (size_t)t0 * DIM;
    #pragma unroll
    for (int it = 0; it < 48; ++it) {
        int idx = it * 256 + tid;
        int tk = idx / 192, c = idx % 192;
        obh[idx] = f2b((xs[tk][c] - mu_s[tk]) * rs_s[tk] * gs[c] + bs[c]);
    }
}

// ---------------------------------------------------------------------------
// MEGA-FUSED attention v4: one block = TWO windows x 6 heads = 12 waves.
// New this round:
//  - window token tile staged ONCE in LDS ([64][200] bf16, 400-B stride for
//    balanced ds_read_b128 bank classes); phase-1 fragment reads become
//    immediate-offset LDS reads (72 global loads/wave -> 4 staging loads).
//  - Q,K GEMMs fused in one loop sharing each af fragment; V in a second
//    loop (af re-read from LDS, cheap).
//  - QK^T placed right after q/k epilogue (register-only), V GEMM fills
//    the MFMA shadow.
//  - x2 stores: per-instruction full 128-B-granule coverage (round-2/3's
//    partial-granule RMW cost 15 MB of extra HBM writes).
//  - residual shortcut prefetched into registers right after phase 1.
//  - top-16 selection with v_max3 trees (bit-identical, ~25% fewer ops).
// LDS map (127680 B):
//  [0,55296)        12 x 4608 R-blocks (Ssq[16][68] f32 / Ph[32][72] bf16)
//                   overlay: 2 window tiles [64][200] bf16 (phase 0-1),
//                   later 2 AoT tiles [64][200] bf16 (proj phase)
//  [55296,116736)   12 x 5120: Vt[32][72] bf16 + ksb[64] + qnb[64]
//                   overlay after PV barrier: 12 x Cwi[16][36] f32 staging
//  [116736,127680)  12 x 228 f32 private rpb
// Barriers: B1 post-staging, B2 pre-transpose (tile dead -> R usable),
// B3 post-PV (arenas dead -> AoT), B4 post-AoT (proj may read).
__global__ __launch_bounds__(768, 3) void attn_fused(
    const ushort_t* __restrict__ sc_h, const ushort_t* __restrict__ wqf,
    const float* __restrict__ qkv_b, const float* __restrict__ rpb_table,
    const float* __restrict__ temp, const ushort_t* __restrict__ wpf,
    const float* __restrict__ proj_b, float* __restrict__ x2)
{
    __shared__ __align__(16) char smem[127680];
    const int tid  = threadIdx.x;
    const int wave = tid >> 6, n = tid & 63;

    char* Rb = smem + wave * 4608;
    float*    Ssq = (float*)Rb;                  // [16][68] f32 transpose qtr
    ushort_t* Ph  = (ushort_t*)Rb;               // [32][72] bf16 P half (ovl)
    char* Ab = smem + 55296 + wave * 5120;
    ushort_t* Vt  = (ushort_t*)Ab;               // [32][72] V^T slot-permuted
    float*    ksb = (float*)(Ab + 4608);         // [64] slot-ordered 1/||k||
    float*    qnb = (float*)(Ab + 4864);         // [64] ssq of q per token
    float*    rpb = (float*)(smem + 116736) + wave * 228;

    const int wloc = (wave >= 6) ? 1 : 0;        // window within block
    const int h    = wave - 6 * wloc;            // head
    ushort_t* tile = (ushort_t*)(smem + wloc * 25600);       // [64][200] bf16
    ushort_t (*AoT)[200] = (ushort_t(*)[200])(smem + wloc * 25600);
    float* Cwi = (float*)(smem + 55296 + wave * 2304);       // [16][36] f32

    const int win = blockIdx.x * 2 + wloc;
    const int b   = win >> 6;
    const int wh  = (win >> 3) & 7, ww = win & 7;
    const int wb  = b * 4096 + wh * 512 + ww * 8;
    const int i1  = n >> 3, j1 = n & 7;
    const int m16 = n & 15, quad = n >> 4;

    for (int r = n; r < 225; r += 64) rpb[r] = rpb_table[r * 6 + h];

    // ---- phase 0: stage this window's shortcut tile into LDS (once) ----
    // 1536 16-B chunks per window; wave h stages chunks [h*256, h*256+256).
    #pragma unroll
    for (int l = 0; l < 4; ++l) {
        const int g = h * 256 + l * 64 + n;
        const int t = (g * 2731) >> 16;          // g / 24
        const int r = g - t * 24;
        const int tt = wb + ((t >> 3) << 6) + (t & 7);
        uint4 v = *(const uint4*)(sc_h + (size_t)tt * 192 + r * 8);
        *(uint4*)(tile + t * 200 + r * 8) = v;
    }
    __syncthreads();                              // B1: tile ready

    // ---- phase 1a: q & k GEMMs sharing af fragments (all LDS reads) ----
    const ushort_t* tb = tile + m16 * 200 + quad * 8;
    f32x4 pq[4][2], pk[4][2];
    #pragma unroll
    for (int i = 0; i < 4; ++i)
        #pragma unroll
        for (int j = 0; j < 2; ++j) { pq[i][j] = (f32x4)(0.0f); pk[i][j] = (f32x4)(0.0f); }
    {
        const ushort_t* WbQ = wqf + (size_t)(2 * h) * 3072 + m16 * 8;
        const ushort_t* WbK = wqf + (size_t)(12 + 2 * h) * 3072 + m16 * 8;
        for (int ks = 0; ks < 192; ks += 32) {
            bf16x8 af[4], wq2[2], wk2[2];
            #pragma unroll
            for (int i = 0; i < 4; ++i)
                af[i] = *(const bf16x8*)(tb + i * 3200 + ks);
            #pragma unroll
            for (int j = 0; j < 2; ++j) {
                wq2[j] = *(const bf16x8*)(WbQ + (size_t)(j * 24 + (ks >> 3) + quad) * 128);
                wk2[j] = *(const bf16x8*)(WbK + (size_t)(j * 24 + (ks >> 3) + quad) * 128);
            }
            #pragma unroll
            for (int i = 0; i < 4; ++i)
                #pragma unroll
                for (int j = 0; j < 2; ++j) {
                    pq[i][j] = __builtin_amdgcn_mfma_f32_16x16x32_bf16(wq2[j], af[i], pq[i][j], 0, 0, 0);
                    pk[i][j] = __builtin_amdgcn_mfma_f32_16x16x32_bf16(wk2[j], af[i], pk[i][j], 0, 0, 0);
                }
        }
    }
    // q/k epilogue: bias, ssq, pack to QK^T fragments (permuted slots)
    bf16x8 qA[4], kB[4];
    #pragma unroll
    for (int part = 0; part < 2; ++part) {
        const int o0 = part * 192 + h * 32;
        const float4 bv0 = *(const float4*)&qkv_b[o0 + 8 * quad];
        const float4 bv1 = *(const float4*)&qkv_b[o0 + 8 * quad + 4];
        float ssq[4];
        #pragma unroll
        for (int i = 0; i < 4; ++i) {
            f32x4 v0 = part ? pk[i][0] : pq[i][0];
            f32x4 v1 = part ? pk[i][1] : pq[i][1];
            v0[0] += bv0.x; v0[1] += bv0.y; v0[2] += bv0.z; v0[3] += bv0.w;
            v1[0] += bv1.x; v1[1] += bv1.y; v1[2] += bv1.z; v1[3] += bv1.w;
            float sq = 0.f;
            #pragma unroll
            for (int r = 0; r < 4; ++r) sq += v0[r] * v0[r] + v1[r] * v1[r];
            ssq[i] = sq;
            bf16x8 fr;
            fr[0] = (short)f2b(v0[0]); fr[1] = (short)f2b(v0[1]);
            fr[2] = (short)f2b(v0[2]); fr[3] = (short)f2b(v0[3]);
            fr[4] = (short)f2b(v1[0]); fr[5] = (short)f2b(v1[1]);
            fr[6] = (short)f2b(v1[2]); fr[7] = (short)f2b(v1[3]);
            if (part == 0) qA[i] = fr; else kB[i] = fr;
        }
        #pragma unroll
        for (int i = 0; i < 4; ++i) {
            ssq[i] += __shfl_xor(ssq[i], 16);
            ssq[i] += __shfl_xor(ssq[i], 32);
        }
        if (quad == 0) {
            #pragma unroll
            for (int i = 0; i < 4; ++i) {
                if (part == 0) qnb[16 * i + m16] = ssq[i];
                else           ksb[4 * m16 + i]  = 1.0f / fmaxf(sqrtf(ssq[i]), 1e-12f);
            }
        }
    }

    // ---- phase 2: QK^T, register-to-register (V GEMM fills the shadow) ----
    f32x4 acc[4][4];
    #pragma unroll
    for (int i = 0; i < 4; ++i)
        #pragma unroll
        for (int j = 0; j < 4; ++j)
            acc[i][j] = __builtin_amdgcn_mfma_f32_16x16x32_bf16(qA[i], kB[j], (f32x4)(0.0f), 0, 0, 0);

    // ---- phase 1b: v GEMM (af re-read from LDS) ----
    {
        f32x4 pv[4][2];
        #pragma unroll
        for (int i = 0; i < 4; ++i)
            #pragma unroll
            for (int j = 0; j < 2; ++j) pv[i][j] = (f32x4)(0.0f);
        const ushort_t* WbV = wqf + (size_t)(24 + 2 * h) * 3072 + m16 * 8;
        for (int ks = 0; ks < 192; ks += 32) {
            bf16x8 af[4], wv2[2];
            #pragma unroll
            for (int i = 0; i < 4; ++i)
                af[i] = *(const bf16x8*)(tb + i * 3200 + ks);
            #pragma unroll
            for (int j = 0; j < 2; ++j)
                wv2[j] = *(const bf16x8*)(WbV + (size_t)(j * 24 + (ks >> 3) + quad) * 128);
            #pragma unroll
            for (int i = 0; i < 4; ++i)
                #pragma unroll
                for (int j = 0; j < 2; ++j)
                    pv[i][j] = __builtin_amdgcn_mfma_f32_16x16x32_bf16(wv2[j], af[i], pv[i][j], 0, 0, 0);
        }
        const int o0 = 384 + h * 32;
        const float4 bv0 = *(const float4*)&qkv_b[o0 + quad * 4];
        const float4 bv1 = *(const float4*)&qkv_b[o0 + 16 + quad * 4];
        #pragma unroll
        for (int i = 0; i < 4; ++i) {
            f32x4 v0 = pv[i][0], v1 = pv[i][1];
            v0[0] += bv0.x; v0[1] += bv0.y; v0[2] += bv0.z; v0[3] += bv0.w;
            v1[0] += bv1.x; v1[1] += bv1.y; v1[2] += bv1.z; v1[3] += bv1.w;
            #pragma unroll
            for (int r = 0; r < 4; ++r) {
                Vt[(quad * 4 + r) * 72 + 4 * m16 + i]      = f2b(v0[r]);
                Vt[(16 + quad * 4 + r) * 72 + 4 * m16 + i] = f2b(v1[r]);
            }
        }
    }

    // ---- residual prefetch (used ~2000 instrs later at the x2 store) ----
    const int r8 = n >> 3, c4 = (n & 7) * 4;
    uint2 rv[4][2];
    #pragma unroll
    for (int i = 0; i < 4; ++i)
        #pragma unroll
        for (int q = 0; q < 2; ++q) {
            const int tok = 16 * i + 8 * q + r8;
            const int tt = wb + ((tok >> 3) << 6) + (tok & 7);
            rv[i][q] = *(const uint2*)(sc_h + (size_t)tt * 192 + h * 32 + c4);
        }

    __syncthreads();                              // B2: tiles dead, R usable

    // ---- transpose S via 16-row quarter buffer (wave-local) ----
    // slot c of a row holds true k-token m = 16*(c&3)+(c>>2)
    float s[64];
    #pragma unroll
    for (int i = 0; i < 4; ++i) {
        #pragma unroll
        for (int r = 0; r < 4; ++r) {
            f32x4 vv = { acc[i][0][r], acc[i][1][r], acc[i][2][r], acc[i][3][r] };
            *(f32x4*)&Ssq[(4 * quad + r) * 68 + 4 * m16] = vv;
        }
        if ((n >> 4) == i) {
            #pragma unroll
            for (int c = 0; c < 16; ++c)
                *(float4*)&s[4 * c] = *(const float4*)&Ssq[(n & 15) * 68 + 4 * c];
        }
    }

    // ---- cosine scales (positive; preserve top-k ordering) ----
    const float qs = temp[h] / fmaxf(sqrtf(qnb[n]), 1e-12f);
    #pragma unroll
    for (int c = 0; c < 16; ++c) {
        float4 kv = *(const float4*)&ksb[4 * c];
        s[4*c+0] *= qs * kv.x; s[4*c+1] *= qs * kv.y;
        s[4*c+2] *= qs * kv.z; s[4*c+3] *= qs * kv.w;
    }

    // ---- top-16 threshold via masked v_max3 trees (bit-identical) ----
    float thr = 1e30f;
    for (int it = 0; it < IN_CC; ++it) {
        #define MK(c) ((s[(c)] < thr) ? s[(c)] : -1e30f)
        float w[22];
        #pragma unroll
        for (int g = 0; g < 21; ++g) w[g] = m3(MK(3*g), MK(3*g+1), MK(3*g+2));
        w[21] = MK(63);
        #undef MK
        float y[8];
        #pragma unroll
        for (int g = 0; g < 7; ++g) y[g] = m3(w[3*g], w[3*g+1], w[3*g+2]);
        y[7] = w[21];
        thr = m3(m3(y[0], y[1], y[2]), m3(y[3], y[4], y[5]), fmaxf(y[6], y[7]));
    }

    // ---- mask + rpb + softmax (slot c holds true m = 16*(c&3)+(c>>2)) ----
    const int basen = i1 * 15 + j1;
    float mxp[8];
    #pragma unroll
    for (int c = 0; c < 64; ++c) {
        const int m = 16 * (c & 3) + (c >> 2);
        const int i2 = m >> 3, j2 = m & 7;
        float vv = ((s[c] >= thr) ? s[c] : -100.0f)
                 + rpb[basen + (7 - i2) * 15 + (7 - j2)];
        s[c] = vv;
        if (c < 8) mxp[c] = vv; else mxp[c & 7] = fmaxf(mxp[c & 7], vv);
    }
    const float mx = m3(m3(mxp[0], mxp[1], mxp[2]), m3(mxp[3], mxp[4], mxp[5]),
                        fmaxf(mxp[6], mxp[7]));
    float sum = 0.f;
    #pragma unroll
    for (int c = 0; c < 64; ++c) { float e = __expf(s[c] - mx); s[c] = e; sum += e; }
    const float inv = 1.0f / sum;
    #pragma unroll
    for (int c = 0; c < 64; ++c) s[c] *= inv;

    // ---- PV via MFMA, P staged in two 32-row halves (R overlay) ----
    bf16x8 vb[2][2];
    #pragma unroll
    for (int kh2 = 0; kh2 < 2; ++kh2)
        #pragma unroll
        for (int j2 = 0; j2 < 2; ++j2)
            vb[kh2][j2] = *(const bf16x8*)&Vt[(16 * j2 + m16) * 72 + kh2 * 32 + quad * 8];

    f32x4 o[4][2];
    #pragma unroll
    for (int i = 0; i < 4; ++i)
        #pragma unroll
        for (int j2 = 0; j2 < 2; ++j2)
            o[i][j2] = (f32x4)(0.0f);
    #pragma unroll
    for (int hf = 0; hf < 2; ++hf) {
        if ((n >> 5) == hf) {
            #pragma unroll
            for (int g = 0; g < 8; ++g) {
                uint4 w;
                w.x = pk2(s[8*g+0], s[8*g+1]); w.y = pk2(s[8*g+2], s[8*g+3]);
                w.z = pk2(s[8*g+4], s[8*g+5]); w.w = pk2(s[8*g+6], s[8*g+7]);
                *(uint4*)&Ph[(n & 31) * 72 + 8 * g] = w;
            }
        }
        #pragma unroll
        for (int ih = 0; ih < 2; ++ih) {
            const int i = 2 * hf + ih;
            #pragma unroll
            for (int kh2 = 0; kh2 < 2; ++kh2) {
                bf16x8 pafr = *(const bf16x8*)&Ph[(16 * ih + m16) * 72 + kh2 * 32 + quad * 8];
                o[i][0] = __builtin_amdgcn_mfma_f32_16x16x32_bf16(pafr, vb[kh2][0], o[i][0], 0, 0, 0);
                o[i][1] = __builtin_amdgcn_mfma_f32_16x16x32_bf16(pafr, vb[kh2][1], o[i][1], 0, 0, 0);
            }
        }
    }
    __syncthreads();   // B3: all waves done with arenas -> AoT may overlay

    // ---- O -> shared AoT tile (bf16, token-major, stride 200) ----
    #pragma unroll
    for (int i = 0; i < 4; ++i) {
        #pragma unroll
        for (int r = 0; r < 4; ++r) {
            const int row = 16 * i + 4 * quad + r;
            AoT[row][h * 32 + m16]      = f2b(o[i][0][r]);
            AoT[row][h * 32 + 16 + m16] = f2b(o[i][1][r]);
        }
    }
    __syncthreads();   // B4

    // ---- proj: wave computes outs [h*32, h*32+32) of its window, K=192 ----
    f32x4 pacc[4][2];
    #pragma unroll
    for (int i = 0; i < 4; ++i)
        #pragma unroll
        for (int j = 0; j < 2; ++j)
            pacc[i][j] = (f32x4)(0.0f);
    const ushort_t* Wb = wpf + (size_t)(h * 2) * 24 * 128 + m16 * 8;
    for (int ks = 0; ks < 192; ks += 32) {
        bf16x8 af[4], wv[2];
        #pragma unroll
        for (int i = 0; i < 4; ++i)
            af[i] = *(const bf16x8*)&AoT[16 * i + m16][quad * 8 + ks];
        #pragma unroll
        for (int j = 0; j < 2; ++j)
            wv[j] = *(const bf16x8*)(Wb + (size_t)(j * 24 + (ks >> 3) + quad) * 128);
        #pragma unroll
        for (int i = 0; i < 4; ++i)
            #pragma unroll
            for (int j = 0; j < 2; ++j)
                pacc[i][j] = __builtin_amdgcn_mfma_f32_16x16x32_bf16(wv[j], af[i], pacc[i][j], 0, 0, 0);
    }

    // ---- per i-group: stage C^T (+bias) into Cwi[16][36]; store x2 with
    //      full 128-B-granule coverage per instruction (8 lanes x 16 B
    //      contiguous per token row). Wave-local: in-order LDS pipe. ----
    const float4 bj0 = *(const float4*)&proj_b[h * 32 + quad * 4];
    const float4 bj1 = *(const float4*)&proj_b[h * 32 + 16 + quad * 4];
    #pragma unroll
    for (int i = 0; i < 4; ++i) {
        f32x4 v0 = pacc[i][0], v1 = pacc[i][1];
        v0[0] += bj0.x; v0[1] += bj0.y; v0[2] += bj0.z; v0[3] += bj0.w;
        v1[0] += bj1.x; v1[1] += bj1.y; v1[2] += bj1.z; v1[3] += bj1.w;
        *(f32x4*)&Cwi[m16 * 36 + quad * 4]      = v0;
        *(f32x4*)&Cwi[m16 * 36 + 16 + quad * 4] = v1;
        #pragma unroll
        for (int q = 0; q < 2; ++q) {
            const int row = 8 * q + r8;
            const int tok = 16 * i + row;
            const int tt = wb + ((tok >> 3) << 6) + (tok & 7);
            float4 vv = *(const float4*)&Cwi[row * 36 + c4];
            const uint2 rr = rv[i][q];
            vv.x += b2f((ushort_t)(rr.x & 0xffffu));
            vv.y += b2f((ushort_t)(rr.x >> 16));
            vv.z += b2f((ushort_t)(rr.y & 0xffffu));
            vv.w += b2f((ushort_t)(rr.y >> 16));
            *(float4*)&x2[(size_t)tt * DIM + h * 32 + c4] = vv;
        }
    }
}

// ---------------------------------------------------------------------------
// FUSED MLP kernel (r11-validated): LN2 -> fc1+GELU -> fc2 -> +res -> NCHW.
__global__ __launch_bounds__(256) void mlp_fused(
    const float* __restrict__ x2, const ushort_t* __restrict__ w1f,
    const ushort_t* __restrict__ w2f, const float* __restrict__ fc1_b,
    const float* __restrict__ fc2_b, const float* __restrict__ g2,
    const float* __restrict__ b2, float* __restrict__ outp)
{
    __shared__ __align__(16) char smem[43008];
    ushort_t (*h_h)[200] = (ushort_t(*)[200])smem;            // [64][200]
    ushort_t (*a1c)[136] = (ushort_t(*)[136])(smem + 25600);  // [64][136]
    float* gs  = (float*)(smem + 25600);                      // phase-1 only
    float* bs  = gs + 192;

    const int tid  = threadIdx.x;
    const int wave = tid >> 6, lane = tid & 63;
    const int m16 = lane & 15, quad = lane >> 4;
    const int t0 = blockIdx.x * 64;
    const int b   = t0 >> 12;
    const int hw0 = t0 & 4095;

    if (tid < 192) { gs[tid] = g2[tid]; bs[tid] = b2[tid]; }
    __syncthreads();
    {
        const int tok = tid >> 2, p = tid & 3;
        const float* rp = x2 + (size_t)(t0 + tok) * DIM + p * 48;
        float xv[48];
        #pragma unroll
        for (int c4 = 0; c4 < 12; ++c4)
            *(float4*)&xv[c4 * 4] = *(const float4*)(rp + c4 * 4);
        float sum = 0.f;
        #pragma unroll
        for (int c = 0; c < 48; ++c) sum += xv[c];
        sum += __shfl_xor(sum, 1);
        sum += __shfl_xor(sum, 2);
        const float m = sum * (1.0f / 192.0f);
        float ss = 0.f;
        #pragma unroll
        for (int c = 0; c < 48; ++c) { float d = xv[c] - m; ss += d * d; }
        ss += __shfl_xor(ss, 1);
        ss += __shfl_xor(ss, 2);
        const float rs = 1.0f / sqrtf(ss * (1.0f / 192.0f) + 1e-5f);
        ushort_t* hp = &h_h[tok][p * 48];
        #pragma unroll
        for (int c2 = 0; c2 < 24; ++c2) {
            float v0 = (xv[2*c2]   - m) * rs * gs[p * 48 + 2*c2]   + bs[p * 48 + 2*c2];
            float v1 = (xv[2*c2+1] - m) * rs * gs[p * 48 + 2*c2+1] + bs[p * 48 + 2*c2+1];
            *(unsigned*)(hp + 2 * c2) = pk2(v0, v1);
        }
    }
    __syncthreads();

    f32x4 acc2[4][3];
    #pragma unroll
    for (int i = 0; i < 4; ++i)
        #pragma unroll
        for (int j = 0; j < 3; ++j)
            acc2[i][j] = (f32x4)(0.0f);

    for (int c = 0; c < 6; ++c) {
        f32x4 acc1[4][2];
        #pragma unroll
        for (int i = 0; i < 4; ++i)
            #pragma unroll
            for (int j = 0; j < 2; ++j)
                acc1[i][j] = (f32x4)(0.0f);
        const ushort_t* Wb1 = w1f + (size_t)(c * 8 + wave * 2) * 24 * 128 + m16 * 8;
        for (int ks = 0; ks < 192; ks += 32) {
            bf16x8 af[4], wv[2];
            #pragma unroll
            for (int i = 0; i < 4; ++i)
                af[i] = *(const bf16x8*)&h_h[16 * i + m16][quad * 8 + ks];
            #pragma unroll
            for (int j = 0; j < 2; ++j)
                wv[j] = *(const bf16x8*)(Wb1 + (size_t)(j * 24 + (ks >> 3) + quad) * 128);
            #pragma unroll
            for (int i = 0; i < 4; ++i)
                #pragma unroll
                for (int j = 0; j < 2; ++j)
                    acc1[i][j] = __builtin_amdgcn_mfma_f32_16x16x32_bf16(wv[j], af[i], acc1[i][j], 0, 0, 0);
        }
        #pragma unroll
        for (int j = 0; j < 2; ++j) {
            const int o = c * 128 + wave * 32 + 16 * j + quad * 4;
            const float4 bv = *(const float4*)&fc1_b[o];
            #pragma unroll
            for (int i = 0; i < 4; ++i) {
                f32x4 v = acc1[i][j];
                v[0] += bv.x; v[1] += bv.y; v[2] += bv.z; v[3] += bv.w;
                #pragma unroll
                for (int r = 0; r < 4; ++r) {
                    float xg = v[r];
                    float e1 = __expf(xg * (1.5957691f + 0.0713548f * xg * xg)) + 1.0f;
                    v[r] = xg - xg * __builtin_amdgcn_rcpf(e1);
                }
                uint2 pkd;
                pkd.x = pk2(v[0], v[1]); pkd.y = pk2(v[2], v[3]);
                *(uint2*)&a1c[16 * i + m16][wave * 32 + 16 * j + quad * 4] = pkd;
            }
        }
        __syncthreads();
        const ushort_t* Wb2 = w2f + (size_t)(wave * 3) * 96 * 128 + m16 * 8;
        for (int ks = 0; ks < 128; ks += 32) {
            bf16x8 af2[4], wv2[3];
            #pragma unroll
            for (int i = 0; i < 4; ++i)
                af2[i] = *(const bf16x8*)&a1c[16 * i + m16][quad * 8 + ks];
            #pragma unroll
            for (int j = 0; j < 3; ++j)
                wv2[j] = *(const bf16x8*)(Wb2 + (size_t)(j * 96 + c * 16 + (ks >> 3) + quad) * 128);
            #pragma unroll
            for (int i = 0; i < 4; ++i)
                #pragma unroll
                for (int j = 0; j < 3; ++j)
                    acc2[i][j] = __builtin_amdgcn_mfma_f32_16x16x32_bf16(wv2[j], af2[i], acc2[i][j], 0, 0, 0);
        }
        __syncthreads();
    }

    float (*Cw)[68] = (float(*)[68])(smem + wave * 8704);
    float4 b2j[3];
    #pragma unroll
    for (int j = 0; j < 3; ++j)
        b2j[j] = *(const float4*)&fc2_b[wave * 48 + 16 * j + quad * 4];
    #pragma unroll
    for (int p = 0; p < 2; ++p) {
        #pragma unroll
        for (int ih = 0; ih < 2; ++ih) {
            const int i = 2 * p + ih;
            #pragma unroll
            for (int j = 0; j < 3; ++j) {
                f32x4 v = acc2[i][j];
                v[0] += b2j[j].x; v[1] += b2j[j].y; v[2] += b2j[j].z; v[3] += b2j[j].w;
                *(f32x4*)&Cw[ih * 16 + m16][16 * j + quad * 4] = v;
            }
        }
        #pragma unroll
        for (int q = 0; q < 6; ++q) {
            const int idx = q * 64 + lane;
            const int cc = idx >> 3, t4 = (idx & 7) * 4;
            const int o  = wave * 48 + cc;
            const int tb = t0 + p * 32 + t4;
            float4 vv;
            vv.x = Cw[t4 + 0][cc] + x2[(size_t)(tb + 0) * DIM + o];
            vv.y = Cw[t4 + 1][cc] + x2[(size_t)(tb + 1) * DIM + o];
            vv.z = Cw[t4 + 2][cc] + x2[(size_t)(tb + 2) * DIM + o];
            vv.w = Cw[t4 + 3][cc] + x2[(size_t)(tb + 3) * DIM + o];
            *(float4*)&outp[(size_t)b * (DIM * 4096) + (size_t)o * 4096
                            + hw0 + p * 32 + t4] = vv;
        }
    }
}

// ---------------------------------------------------------------------------
extern "C" void kernel_launch(void* const* d_in, const int* in_sizes, int n_in,
                              void* d_out, int out_size, void* d_ws, size_t ws_size,
                              hipStream_t stream)
{
    const float* x        = (const float*)d_in[0];
    const float* norm1_g  = (const float*)d_in[1];
    const float* norm1_b  = (const float*)d_in[2];
    const float* qkv_w    = (const float*)d_in[3];
    const float* qkv_b    = (const float*)d_in[4];
    const float* proj_w   = (const float*)d_in[5];
    const float* proj_b   = (const float*)d_in[6];
    const float* rpbt     = (const float*)d_in[7];
    const float* temp     = (const float*)d_in[8];
    const float* norm2_g  = (const float*)d_in[9];
    const float* norm2_b  = (const float*)d_in[10];
    const float* fc1_w    = (const float*)d_in[11];
    const float* fc1_b    = (const float*)d_in[12];
    const float* fc2_w    = (const float*)d_in[13];
    const float* fc2_b    = (const float*)d_in[14];
    float* out = (float*)d_out;

    // ws layout (bytes):
    //   [0,        12582912)  shortcut bf16 (LN1 out)
    //   [12582912, 37748736)  x2 f32
    //   [125829120,...)       weights bf16 (fragment order; qkv Q/K permuted)
    char* wsb = (char*)d_ws;
    ushort_t* shortcut_h = (ushort_t*)wsb;
    float*    x2         = (float*)(wsb + 12582912);
    ushort_t* wq  = (ushort_t*)(wsb + 125829120);      // 576x192 = 110592
    ushort_t* wp  = wq + 110592;                       // 192x192 = 36864
    ushort_t* w1  = wp + 36864;                        // 768x192 = 147456
    ushort_t* w2  = w1 + 147456;                       // 192x768 = 147456

    // 0. merged weight conversions into fragment order, one launch
    hipLaunchKernelGGL(cvt_all_kernel, dim3(432), dim3(256), 0, stream,
                       qkv_w, proj_w, fc1_w, fc2_w, wq, wp, w1, w2);

    // 1. LN1 + transpose -> shortcut bf16
    hipLaunchKernelGGL(ln1_kernel, dim3(TTOT / 64), dim3(256), 0, stream,
                       x, norm1_g, norm1_b, shortcut_h);
    // 2. fused qkv + attention + proj + residual -> x2 (2 windows/block)
    hipLaunchKernelGGL(attn_fused, dim3(NWIN / 2), dim3(768), 0, stream,
                       shortcut_h, wq, qkv_b, rpbt, temp, wp, proj_b, x2);
    // 3. fused LN2 + fc1 + GELU + fc2 + residual + NCHW transpose
    hipLaunchKernelGGL(mlp_fused, dim3(TTOT / 64), dim3(256), 0, stream,
                       x2, w1, w2, fc1_b, fc2_b, norm2_g, norm2_b, out);
}

// Round 5
// 192.025 us; speedup vs baseline: 1.1750x; 1.0103x over previous
//
#include <hip/hip_runtime.h>
#include <hip/hip_bf16.h>
#include <math.h>

// Problem constants
#define DIM     192
#define HEADS   6
#define HEAD_DIM 32
#define NTOK    64          // tokens per window
#define IN_CC   16
#define TTOT    32768       // 8 * 64 * 64 tokens
#define NWIN    512

using bf16x8 = __attribute__((ext_vector_type(8))) short;
using f32x4  = __attribute__((ext_vector_type(4))) float;
typedef unsigned short ushort_t;

// fp32 -> bf16 round-to-nearest-even (finite inputs)
__device__ __forceinline__ ushort_t f2b(float f) {
    unsigned u = __float_as_uint(f);
    u += 0x7fffu + ((u >> 16) & 1u);
    return (ushort_t)(u >> 16);
}
__device__ __forceinline__ unsigned pk2(float a, float b) {
    return (unsigned)f2b(a) | ((unsigned)f2b(b) << 16);
}
__device__ __forceinline__ float b2f(ushort_t u) {
    return __uint_as_float(((unsigned)u) << 16);
}
__device__ __forceinline__ float m3(float a, float b, float c) {
    return fmaxf(fmaxf(a, b), c);     // clang fuses to v_max3_f32
}

// ---------------------------------------------------------------------------
// Merged weight fp32 -> bf16 conversion INTO MFMA FRAGMENT ORDER.
// W (NxK row-major) -> W' where element (o,k) lives at
//   frag = (o/16)*(K/8) + (k/8);  W'[frag*128 + (o%16)*8 + (k%8)]
// qkv weight ONLY: Q and K parts (rows [0,384)) get a within-head output-row
// permutation so the qkv GEMM's C-fragment IS the QK^T MFMA A/B fragment
// (slot s=16j+4q+r holds natural channel c=8q+4j+r). QK^T is invariant under
// a common channel permutation of q and k.
__global__ __launch_bounds__(256) void cvt_all_kernel(
    const float* __restrict__ s0, const float* __restrict__ s1,
    const float* __restrict__ s2, const float* __restrict__ s3,
    ushort_t* __restrict__ d0, ushort_t* __restrict__ d1,
    ushort_t* __restrict__ d2, ushort_t* __restrict__ d3)
{
    const int bid = blockIdx.x;
    const float* src; ushort_t* dst; int off, K; bool perm = false;
    if (bid < 108)      { src = s0; dst = d0; off = bid;       K = 192; perm = true; }
    else if (bid < 144) { src = s1; dst = d1; off = bid - 108; K = 192; }
    else if (bid < 288) { src = s2; dst = d2; off = bid - 144; K = 192; }
    else                { src = s3; dst = d3; off = bid - 288; K = 768; }
    const int K8 = K >> 3;
    const int d  = (off * 256 + threadIdx.x) * 4;
    const int frag = d >> 7, win = d & 127;
    const int m16w = win >> 3, k7 = win & 7;
    const int oblk = frag / K8, kblk = frag - oblk * K8;
    const int o = oblk * 16 + m16w, k = kblk * 8 + k7;
    int so = o;
    if (perm && o < 384) {
        const int s = o & 31;                           // slot within head block
        const int c = (((s >> 2) & 3) << 3) | (((s >> 4) & 1) << 2) | (s & 3);
        so = (o & ~31) | c;                             // natural channel row
    }
    float4 v = *(const float4*)(src + (size_t)so * K + k);
    ushort4 ov;
    ov.x = f2b(v.x); ov.y = f2b(v.y); ov.z = f2b(v.z); ov.w = f2b(v.w);
    *(ushort4*)(dst + d) = ov;
}

// ---------------------------------------------------------------------------
// Kernel 1: LayerNorm1 fused with (B,C,H,W) -> (T,C) transpose. bf16 out only.
__global__ __launch_bounds__(256) void ln1_kernel(
    const float* __restrict__ x, const float* __restrict__ g,
    const float* __restrict__ bb, ushort_t* __restrict__ outh)
{
    __shared__ float xs[64][193];
    __shared__ float mu_s[64], rs_s[64];
    __shared__ float gs[192], bs[192];
    const int tid = threadIdx.x;
    const int t0  = blockIdx.x * 64;
    const int b   = t0 >> 12;
    const int hw0 = t0 & 4095;
    if (tid < 192) { gs[tid] = g[tid]; bs[tid] = bb[tid]; }
    const int tok = tid & 63, qq = tid >> 6;
    const float* xb = x + (size_t)b * (DIM * 4096) + hw0 + tok;
    #pragma unroll
    for (int it = 0; it < 48; ++it) {
        int c = it * 4 + qq;
        xs[tok][c] = xb[(size_t)c * 4096];
    }
    __syncthreads();
    const int tok2 = tid >> 2, p = tid & 3;
    float sum = 0.f;
    #pragma unroll
    for (int c = 0; c < 48; ++c) sum += xs[tok2][p * 48 + c];
    sum += __shfl_xor(sum, 1);
    sum += __shfl_xor(sum, 2);
    const float m = sum * (1.0f / 192.0f);
    float ss = 0.f;
    #pragma unroll
    for (int c = 0; c < 48; ++c) { float d = xs[tok2][p * 48 + c] - m; ss += d * d; }
    ss += __shfl_xor(ss, 1);
    ss += __shfl_xor(ss, 2);
    if (p == 0) {
        mu_s[tok2] = m;
        rs_s[tok2] = 1.0f / sqrtf(ss * (1.0f / 192.0f) + 1e-5f);
    }
    __syncthreads();
    ushort_t* obh = outh + (size_t)t0 * DIM;
    #pragma unroll
    for (int it = 0; it < 48; ++it) {
        int idx = it * 256 + tid;
        int tk = idx / 192, c = idx % 192;
        obh[idx] = f2b((xs[tk][c] - mu_s[tk]) * rs_s[tk] * gs[c] + bs[c]);
    }
}

// ---------------------------------------------------------------------------
// MEGA-FUSED attention v4 (unchanged from round 4; 52 us, validated).
__global__ __launch_bounds__(768, 3) void attn_fused(
    const ushort_t* __restrict__ sc_h, const ushort_t* __restrict__ wqf,
    const float* __restrict__ qkv_b, const float* __restrict__ rpb_table,
    const float* __restrict__ temp, const ushort_t* __restrict__ wpf,
    const float* __restrict__ proj_b, float* __restrict__ x2)
{
    __shared__ __align__(16) char smem[127680];
    const int tid  = threadIdx.x;
    const int wave = tid >> 6, n = tid & 63;

    char* Rb = smem + wave * 4608;
    float*    Ssq = (float*)Rb;                  // [16][68] f32 transpose qtr
    ushort_t* Ph  = (ushort_t*)Rb;               // [32][72] bf16 P half (ovl)
    char* Ab = smem + 55296 + wave * 5120;
    ushort_t* Vt  = (ushort_t*)Ab;               // [32][72] V^T slot-permuted
    float*    ksb = (float*)(Ab + 4608);         // [64] slot-ordered 1/||k||
    float*    qnb = (float*)(Ab + 4864);         // [64] ssq of q per token
    float*    rpb = (float*)(smem + 116736) + wave * 228;

    const int wloc = (wave >= 6) ? 1 : 0;        // window within block
    const int h    = wave - 6 * wloc;            // head
    ushort_t* tile = (ushort_t*)(smem + wloc * 25600);       // [64][200] bf16
    ushort_t (*AoT)[200] = (ushort_t(*)[200])(smem + wloc * 25600);
    float* Cwi = (float*)(smem + 55296 + wave * 2304);       // [16][36] f32

    const int win = blockIdx.x * 2 + wloc;
    const int b   = win >> 6;
    const int wh  = (win >> 3) & 7, ww = win & 7;
    const int wb  = b * 4096 + wh * 512 + ww * 8;
    const int i1  = n >> 3, j1 = n & 7;
    const int m16 = n & 15, quad = n >> 4;

    for (int r = n; r < 225; r += 64) rpb[r] = rpb_table[r * 6 + h];

    // ---- phase 0: stage this window's shortcut tile into LDS (once) ----
    #pragma unroll
    for (int l = 0; l < 4; ++l) {
        const int g = h * 256 + l * 64 + n;
        const int t = (g * 2731) >> 16;          // g / 24
        const int r = g - t * 24;
        const int tt = wb + ((t >> 3) << 6) + (t & 7);
        uint4 v = *(const uint4*)(sc_h + (size_t)tt * 192 + r * 8);
        *(uint4*)(tile + t * 200 + r * 8) = v;
    }
    __syncthreads();                              // B1: tile ready

    // ---- phase 1a: q & k GEMMs sharing af fragments (all LDS reads) ----
    const ushort_t* tb = tile + m16 * 200 + quad * 8;
    f32x4 pq[4][2], pk[4][2];
    #pragma unroll
    for (int i = 0; i < 4; ++i)
        #pragma unroll
        for (int j = 0; j < 2; ++j) { pq[i][j] = (f32x4)(0.0f); pk[i][j] = (f32x4)(0.0f); }
    {
        const ushort_t* WbQ = wqf + (size_t)(2 * h) * 3072 + m16 * 8;
        const ushort_t* WbK = wqf + (size_t)(12 + 2 * h) * 3072 + m16 * 8;
        for (int ks = 0; ks < 192; ks += 32) {
            bf16x8 af[4], wq2[2], wk2[2];
            #pragma unroll
            for (int i = 0; i < 4; ++i)
                af[i] = *(const bf16x8*)(tb + i * 3200 + ks);
            #pragma unroll
            for (int j = 0; j < 2; ++j) {
                wq2[j] = *(const bf16x8*)(WbQ + (size_t)(j * 24 + (ks >> 3) + quad) * 128);
                wk2[j] = *(const bf16x8*)(WbK + (size_t)(j * 24 + (ks >> 3) + quad) * 128);
            }
            #pragma unroll
            for (int i = 0; i < 4; ++i)
                #pragma unroll
                for (int j = 0; j < 2; ++j) {
                    pq[i][j] = __builtin_amdgcn_mfma_f32_16x16x32_bf16(wq2[j], af[i], pq[i][j], 0, 0, 0);
                    pk[i][j] = __builtin_amdgcn_mfma_f32_16x16x32_bf16(wk2[j], af[i], pk[i][j], 0, 0, 0);
                }
        }
    }
    // q/k epilogue: bias, ssq, pack to QK^T fragments (permuted slots)
    bf16x8 qA[4], kB[4];
    #pragma unroll
    for (int part = 0; part < 2; ++part) {
        const int o0 = part * 192 + h * 32;
        const float4 bv0 = *(const float4*)&qkv_b[o0 + 8 * quad];
        const float4 bv1 = *(const float4*)&qkv_b[o0 + 8 * quad + 4];
        float ssq[4];
        #pragma unroll
        for (int i = 0; i < 4; ++i) {
            f32x4 v0 = part ? pk[i][0] : pq[i][0];
            f32x4 v1 = part ? pk[i][1] : pq[i][1];
            v0[0] += bv0.x; v0[1] += bv0.y; v0[2] += bv0.z; v0[3] += bv0.w;
            v1[0] += bv1.x; v1[1] += bv1.y; v1[2] += bv1.z; v1[3] += bv1.w;
            float sq = 0.f;
            #pragma unroll
            for (int r = 0; r < 4; ++r) sq += v0[r] * v0[r] + v1[r] * v1[r];
            ssq[i] = sq;
            bf16x8 fr;
            fr[0] = (short)f2b(v0[0]); fr[1] = (short)f2b(v0[1]);
            fr[2] = (short)f2b(v0[2]); fr[3] = (short)f2b(v0[3]);
            fr[4] = (short)f2b(v1[0]); fr[5] = (short)f2b(v1[1]);
            fr[6] = (short)f2b(v1[2]); fr[7] = (short)f2b(v1[3]);
            if (part == 0) qA[i] = fr; else kB[i] = fr;
        }
        #pragma unroll
        for (int i = 0; i < 4; ++i) {
            ssq[i] += __shfl_xor(ssq[i], 16);
            ssq[i] += __shfl_xor(ssq[i], 32);
        }
        if (quad == 0) {
            #pragma unroll
            for (int i = 0; i < 4; ++i) {
                if (part == 0) qnb[16 * i + m16] = ssq[i];
                else           ksb[4 * m16 + i]  = 1.0f / fmaxf(sqrtf(ssq[i]), 1e-12f);
            }
        }
    }

    // ---- phase 2: QK^T, register-to-register (V GEMM fills the shadow) ----
    f32x4 acc[4][4];
    #pragma unroll
    for (int i = 0; i < 4; ++i)
        #pragma unroll
        for (int j = 0; j < 4; ++j)
            acc[i][j] = __builtin_amdgcn_mfma_f32_16x16x32_bf16(qA[i], kB[j], (f32x4)(0.0f), 0, 0, 0);

    // ---- phase 1b: v GEMM (af re-read from LDS) ----
    {
        f32x4 pv[4][2];
        #pragma unroll
        for (int i = 0; i < 4; ++i)
            #pragma unroll
            for (int j = 0; j < 2; ++j) pv[i][j] = (f32x4)(0.0f);
        const ushort_t* WbV = wqf + (size_t)(24 + 2 * h) * 3072 + m16 * 8;
        for (int ks = 0; ks < 192; ks += 32) {
            bf16x8 af[4], wv2[2];
            #pragma unroll
            for (int i = 0; i < 4; ++i)
                af[i] = *(const bf16x8*)(tb + i * 3200 + ks);
            #pragma unroll
            for (int j = 0; j < 2; ++j)
                wv2[j] = *(const bf16x8*)(WbV + (size_t)(j * 24 + (ks >> 3) + quad) * 128);
            #pragma unroll
            for (int i = 0; i < 4; ++i)
                #pragma unroll
                for (int j = 0; j < 2; ++j)
                    pv[i][j] = __builtin_amdgcn_mfma_f32_16x16x32_bf16(wv2[j], af[i], pv[i][j], 0, 0, 0);
        }
        const int o0 = 384 + h * 32;
        const float4 bv0 = *(const float4*)&qkv_b[o0 + quad * 4];
        const float4 bv1 = *(const float4*)&qkv_b[o0 + 16 + quad * 4];
        #pragma unroll
        for (int i = 0; i < 4; ++i) {
            f32x4 v0 = pv[i][0], v1 = pv[i][1];
            v0[0] += bv0.x; v0[1] += bv0.y; v0[2] += bv0.z; v0[3] += bv0.w;
            v1[0] += bv1.x; v1[1] += bv1.y; v1[2] += bv1.z; v1[3] += bv1.w;
            #pragma unroll
            for (int r = 0; r < 4; ++r) {
                Vt[(quad * 4 + r) * 72 + 4 * m16 + i]      = f2b(v0[r]);
                Vt[(16 + quad * 4 + r) * 72 + 4 * m16 + i] = f2b(v1[r]);
            }
        }
    }

    // ---- residual prefetch (used ~2000 instrs later at the x2 store) ----
    const int r8 = n >> 3, c4 = (n & 7) * 4;
    uint2 rv[4][2];
    #pragma unroll
    for (int i = 0; i < 4; ++i)
        #pragma unroll
        for (int q = 0; q < 2; ++q) {
            const int tok = 16 * i + 8 * q + r8;
            const int tt = wb + ((tok >> 3) << 6) + (tok & 7);
            rv[i][q] = *(const uint2*)(sc_h + (size_t)tt * 192 + h * 32 + c4);
        }

    __syncthreads();                              // B2: tiles dead, R usable

    // ---- transpose S via 16-row quarter buffer (wave-local) ----
    float s[64];
    #pragma unroll
    for (int i = 0; i < 4; ++i) {
        #pragma unroll
        for (int r = 0; r < 4; ++r) {
            f32x4 vv = { acc[i][0][r], acc[i][1][r], acc[i][2][r], acc[i][3][r] };
            *(f32x4*)&Ssq[(4 * quad + r) * 68 + 4 * m16] = vv;
        }
        if ((n >> 4) == i) {
            #pragma unroll
            for (int c = 0; c < 16; ++c)
                *(float4*)&s[4 * c] = *(const float4*)&Ssq[(n & 15) * 68 + 4 * c];
        }
    }

    // ---- cosine scales (positive; preserve top-k ordering) ----
    const float qs = temp[h] / fmaxf(sqrtf(qnb[n]), 1e-12f);
    #pragma unroll
    for (int c = 0; c < 16; ++c) {
        float4 kv = *(const float4*)&ksb[4 * c];
        s[4*c+0] *= qs * kv.x; s[4*c+1] *= qs * kv.y;
        s[4*c+2] *= qs * kv.z; s[4*c+3] *= qs * kv.w;
    }

    // ---- top-16 threshold via masked v_max3 trees (bit-identical) ----
    float thr = 1e30f;
    for (int it = 0; it < IN_CC; ++it) {
        #define MK(c) ((s[(c)] < thr) ? s[(c)] : -1e30f)
        float w[22];
        #pragma unroll
        for (int g = 0; g < 21; ++g) w[g] = m3(MK(3*g), MK(3*g+1), MK(3*g+2));
        w[21] = MK(63);
        #undef MK
        float y[8];
        #pragma unroll
        for (int g = 0; g < 7; ++g) y[g] = m3(w[3*g], w[3*g+1], w[3*g+2]);
        y[7] = w[21];
        thr = m3(m3(y[0], y[1], y[2]), m3(y[3], y[4], y[5]), fmaxf(y[6], y[7]));
    }

    // ---- mask + rpb + softmax (slot c holds true m = 16*(c&3)+(c>>2)) ----
    const int basen = i1 * 15 + j1;
    float mxp[8];
    #pragma unroll
    for (int c = 0; c < 64; ++c) {
        const int m = 16 * (c & 3) + (c >> 2);
        const int i2 = m >> 3, j2 = m & 7;
        float vv = ((s[c] >= thr) ? s[c] : -100.0f)
                 + rpb[basen + (7 - i2) * 15 + (7 - j2)];
        s[c] = vv;
        if (c < 8) mxp[c] = vv; else mxp[c & 7] = fmaxf(mxp[c & 7], vv);
    }
    const float mx = m3(m3(mxp[0], mxp[1], mxp[2]), m3(mxp[3], mxp[4], mxp[5]),
                        fmaxf(mxp[6], mxp[7]));
    float sum = 0.f;
    #pragma unroll
    for (int c = 0; c < 64; ++c) { float e = __expf(s[c] - mx); s[c] = e; sum += e; }
    const float inv = 1.0f / sum;
    #pragma unroll
    for (int c = 0; c < 64; ++c) s[c] *= inv;

    // ---- PV via MFMA, P staged in two 32-row halves (R overlay) ----
    bf16x8 vb[2][2];
    #pragma unroll
    for (int kh2 = 0; kh2 < 2; ++kh2)
        #pragma unroll
        for (int j2 = 0; j2 < 2; ++j2)
            vb[kh2][j2] = *(const bf16x8*)&Vt[(16 * j2 + m16) * 72 + kh2 * 32 + quad * 8];

    f32x4 o[4][2];
    #pragma unroll
    for (int i = 0; i < 4; ++i)
        #pragma unroll
        for (int j2 = 0; j2 < 2; ++j2)
            o[i][j2] = (f32x4)(0.0f);
    #pragma unroll
    for (int hf = 0; hf < 2; ++hf) {
        if ((n >> 5) == hf) {
            #pragma unroll
            for (int g = 0; g < 8; ++g) {
                uint4 w;
                w.x = pk2(s[8*g+0], s[8*g+1]); w.y = pk2(s[8*g+2], s[8*g+3]);
                w.z = pk2(s[8*g+4], s[8*g+5]); w.w = pk2(s[8*g+6], s[8*g+7]);
                *(uint4*)&Ph[(n & 31) * 72 + 8 * g] = w;
            }
        }
        #pragma unroll
        for (int ih = 0; ih < 2; ++ih) {
            const int i = 2 * hf + ih;
            #pragma unroll
            for (int kh2 = 0; kh2 < 2; ++kh2) {
                bf16x8 pafr = *(const bf16x8*)&Ph[(16 * ih + m16) * 72 + kh2 * 32 + quad * 8];
                o[i][0] = __builtin_amdgcn_mfma_f32_16x16x32_bf16(pafr, vb[kh2][0], o[i][0], 0, 0, 0);
                o[i][1] = __builtin_amdgcn_mfma_f32_16x16x32_bf16(pafr, vb[kh2][1], o[i][1], 0, 0, 0);
            }
        }
    }
    __syncthreads();   // B3: all waves done with arenas -> AoT may overlay

    // ---- O -> shared AoT tile (bf16, token-major, stride 200) ----
    #pragma unroll
    for (int i = 0; i < 4; ++i) {
        #pragma unroll
        for (int r = 0; r < 4; ++r) {
            const int row = 16 * i + 4 * quad + r;
            AoT[row][h * 32 + m16]      = f2b(o[i][0][r]);
            AoT[row][h * 32 + 16 + m16] = f2b(o[i][1][r]);
        }
    }
    __syncthreads();   // B4

    // ---- proj: wave computes outs [h*32, h*32+32) of its window, K=192 ----
    f32x4 pacc[4][2];
    #pragma unroll
    for (int i = 0; i < 4; ++i)
        #pragma unroll
        for (int j = 0; j < 2; ++j)
            pacc[i][j] = (f32x4)(0.0f);
    const ushort_t* Wb = wpf + (size_t)(h * 2) * 24 * 128 + m16 * 8;
    for (int ks = 0; ks < 192; ks += 32) {
        bf16x8 af[4], wv[2];
        #pragma unroll
        for (int i = 0; i < 4; ++i)
            af[i] = *(const bf16x8*)&AoT[16 * i + m16][quad * 8 + ks];
        #pragma unroll
        for (int j = 0; j < 2; ++j)
            wv[j] = *(const bf16x8*)(Wb + (size_t)(j * 24 + (ks >> 3) + quad) * 128);
        #pragma unroll
        for (int i = 0; i < 4; ++i)
            #pragma unroll
            for (int j = 0; j < 2; ++j)
                pacc[i][j] = __builtin_amdgcn_mfma_f32_16x16x32_bf16(wv[j], af[i], pacc[i][j], 0, 0, 0);
    }

    // ---- per i-group: stage C^T (+bias) into Cwi[16][36]; store x2 with
    //      full 128-B-granule coverage per instruction. ----
    const float4 bj0 = *(const float4*)&proj_b[h * 32 + quad * 4];
    const float4 bj1 = *(const float4*)&proj_b[h * 32 + 16 + quad * 4];
    #pragma unroll
    for (int i = 0; i < 4; ++i) {
        f32x4 v0 = pacc[i][0], v1 = pacc[i][1];
        v0[0] += bj0.x; v0[1] += bj0.y; v0[2] += bj0.z; v0[3] += bj0.w;
        v1[0] += bj1.x; v1[1] += bj1.y; v1[2] += bj1.z; v1[3] += bj1.w;
        *(f32x4*)&Cwi[m16 * 36 + quad * 4]      = v0;
        *(f32x4*)&Cwi[m16 * 36 + 16 + quad * 4] = v1;
        #pragma unroll
        for (int q = 0; q < 2; ++q) {
            const int row = 8 * q + r8;
            const int tok = 16 * i + row;
            const int tt = wb + ((tok >> 3) << 6) + (tok & 7);
            float4 vv = *(const float4*)&Cwi[row * 36 + c4];
            const uint2 rr = rv[i][q];
            vv.x += b2f((ushort_t)(rr.x & 0xffffu));
            vv.y += b2f((ushort_t)(rr.x >> 16));
            vv.z += b2f((ushort_t)(rr.y & 0xffffu));
            vv.w += b2f((ushort_t)(rr.y >> 16));
            *(float4*)&x2[(size_t)tt * DIM + h * 32 + c4] = vv;
        }
    }
}

// ---------------------------------------------------------------------------
// FUSED MLP v2: one block = 128 tokens, 12 waves (768 thr), grid 256 = 1/CU.
// Applies the v3 attn lesson: single resident mega-block -> 3 waves/SIMD by
// construction (old mlp: 256-thr blocks, 43 KB LDS, scheduler likely refused
// co-residency -> 1 wave/SIMD, barrier-latency-bound).
// Wave = (token-half: 64 tokens) x (32-out group).  fc1 in 4 chunks of 192
// outs (a1c[128][200] bf16); fc2 K=768 accumulated across chunks into
// persistent acc2[4][2].  8 GEMM barriers (vs 12), each amortized over 12
// waves.  Per-thread GELU work 192 -> 128 evals.
// LDS: h_h[128][200] 51200 | a1c[128][200] 51200 | gs/bs 1536 = 103936 B.
// Cw epilogue staging ([32][36] f32 per wave, 12x4608=55296 B) overlays the
// then-dead h_h/a1c region after the final barrier.
__global__ __launch_bounds__(768, 3) void mlp_fused(
    const float* __restrict__ x2, const ushort_t* __restrict__ w1f,
    const ushort_t* __restrict__ w2f, const float* __restrict__ fc1_b,
    const float* __restrict__ fc2_b, const float* __restrict__ g2,
    const float* __restrict__ b2, float* __restrict__ outp)
{
    __shared__ __align__(16) char smem[103936];
    ushort_t (*h_h)[200] = (ushort_t(*)[200])smem;             // [128][200]
    ushort_t (*a1c)[200] = (ushort_t(*)[200])(smem + 51200);   // [128][200]
    float* gs = (float*)(smem + 102400);
    float* bs = gs + 192;

    const int tid  = threadIdx.x;
    const int wave = tid >> 6, lane = tid & 63;
    const int m16 = lane & 15, quad = lane >> 4;
    const int half = wave / 6, ow = wave - 6 * half;   // token-half, out-group
    const int t0  = blockIdx.x * 128;
    const int b   = t0 >> 12;
    const int hw0 = t0 & 4095;

    if (tid < 192) { gs[tid] = g2[tid]; bs[tid] = b2[tid]; }
    __syncthreads();
    if (tid < 512) {
        const int tok = tid >> 2, p = tid & 3;
        const float* rp = x2 + (size_t)(t0 + tok) * DIM + p * 48;
        float xv[48];
        #pragma unroll
        for (int c4 = 0; c4 < 12; ++c4)
            *(float4*)&xv[c4 * 4] = *(const float4*)(rp + c4 * 4);
        float sum = 0.f;
        #pragma unroll
        for (int c = 0; c < 48; ++c) sum += xv[c];
        sum += __shfl_xor(sum, 1);
        sum += __shfl_xor(sum, 2);
        const float m = sum * (1.0f / 192.0f);
        float ss = 0.f;
        #pragma unroll
        for (int c = 0; c < 48; ++c) { float d = xv[c] - m; ss += d * d; }
        ss += __shfl_xor(ss, 1);
        ss += __shfl_xor(ss, 2);
        const float rs = 1.0f / sqrtf(ss * (1.0f / 192.0f) + 1e-5f);
        ushort_t* hp = &h_h[tok][p * 48];
        #pragma unroll
        for (int c2 = 0; c2 < 24; ++c2) {
            float v0 = (xv[2*c2]   - m) * rs * gs[p * 48 + 2*c2]   + bs[p * 48 + 2*c2];
            float v1 = (xv[2*c2+1] - m) * rs * gs[p * 48 + 2*c2+1] + bs[p * 48 + 2*c2+1];
            *(unsigned*)(hp + 2 * c2) = pk2(v0, v1);
        }
    }
    __syncthreads();

    f32x4 acc2[4][2];
    #pragma unroll
    for (int i = 0; i < 4; ++i)
        #pragma unroll
        for (int j = 0; j < 2; ++j)
            acc2[i][j] = (f32x4)(0.0f);

    for (int c = 0; c < 4; ++c) {                 // 4 chunks of 192 fc1-outs
        f32x4 acc1[4][2];
        #pragma unroll
        for (int i = 0; i < 4; ++i)
            #pragma unroll
            for (int j = 0; j < 2; ++j)
                acc1[i][j] = (f32x4)(0.0f);
        const ushort_t* Wb1 = w1f + (size_t)(c * 12 + ow * 2) * 3072 + m16 * 8;
        for (int ks = 0; ks < 192; ks += 32) {
            bf16x8 af[4], wv[2];
            #pragma unroll
            for (int i = 0; i < 4; ++i)
                af[i] = *(const bf16x8*)&h_h[half * 64 + 16 * i + m16][quad * 8 + ks];
            #pragma unroll
            for (int j = 0; j < 2; ++j)
                wv[j] = *(const bf16x8*)(Wb1 + (size_t)(j * 24 + (ks >> 3) + quad) * 128);
            #pragma unroll
            for (int i = 0; i < 4; ++i)
                #pragma unroll
                for (int j = 0; j < 2; ++j)
                    acc1[i][j] = __builtin_amdgcn_mfma_f32_16x16x32_bf16(wv[j], af[i], acc1[i][j], 0, 0, 0);
        }
        #pragma unroll
        for (int j = 0; j < 2; ++j) {
            const int o = c * 192 + ow * 32 + 16 * j + quad * 4;
            const float4 bv = *(const float4*)&fc1_b[o];
            #pragma unroll
            for (int i = 0; i < 4; ++i) {
                f32x4 v = acc1[i][j];
                v[0] += bv.x; v[1] += bv.y; v[2] += bv.z; v[3] += bv.w;
                #pragma unroll
                for (int r = 0; r < 4; ++r) {
                    float xg = v[r];
                    float e1 = __expf(xg * (1.5957691f + 0.0713548f * xg * xg)) + 1.0f;
                    v[r] = xg - xg * __builtin_amdgcn_rcpf(e1);
                }
                uint2 pkd;
                pkd.x = pk2(v[0], v[1]); pkd.y = pk2(v[2], v[3]);
                *(uint2*)&a1c[half * 64 + 16 * i + m16][ow * 32 + 16 * j + quad * 4] = pkd;
            }
        }
        __syncthreads();
        const ushort_t* Wb2 = w2f + (size_t)(ow * 2) * 12288 + m16 * 8;
        for (int ks = 0; ks < 192; ks += 32) {
            bf16x8 af2[4], wv2[2];
            #pragma unroll
            for (int i = 0; i < 4; ++i)
                af2[i] = *(const bf16x8*)&a1c[half * 64 + 16 * i + m16][quad * 8 + ks];
            #pragma unroll
            for (int j = 0; j < 2; ++j)
                wv2[j] = *(const bf16x8*)(Wb2 + (size_t)(j * 96 + c * 24 + (ks >> 3) + quad) * 128);
            #pragma unroll
            for (int i = 0; i < 4; ++i)
                #pragma unroll
                for (int j = 0; j < 2; ++j)
                    acc2[i][j] = __builtin_amdgcn_mfma_f32_16x16x32_bf16(wv2[j], af2[i], acc2[i][j], 0, 0, 0);
        }
        __syncthreads();
    }

    // ---- epilogue: stage [32 tok][32 outs] per pass, write NCHW with
    //      full 128-B-granule runs (64-token-consecutive per channel). ----
    float* Cw = (float*)(smem + wave * 4608);      // [32][36] f32, overlay
    float4 b2j[2];
    #pragma unroll
    for (int j = 0; j < 2; ++j)
        b2j[j] = *(const float4*)&fc2_b[ow * 32 + 16 * j + quad * 4];
    #pragma unroll
    for (int p = 0; p < 2; ++p) {
        #pragma unroll
        for (int ih = 0; ih < 2; ++ih) {
            const int i = 2 * p + ih;
            #pragma unroll
            for (int j = 0; j < 2; ++j) {
                f32x4 v = acc2[i][j];
                v[0] += b2j[j].x; v[1] += b2j[j].y; v[2] += b2j[j].z; v[3] += b2j[j].w;
                *(f32x4*)&Cw[(ih * 16 + m16) * 36 + 16 * j + quad * 4] = v;
            }
        }
        #pragma unroll
        for (int q = 0; q < 4; ++q) {
            const int idx = q * 64 + lane;
            const int cc = idx >> 3, t4 = (idx & 7) * 4;
            const int o  = ow * 32 + cc;
            const int tb = t0 + half * 64 + p * 32 + t4;
            float4 vv;
            vv.x = Cw[(t4 + 0) * 36 + cc] + x2[(size_t)(tb + 0) * DIM + o];
            vv.y = Cw[(t4 + 1) * 36 + cc] + x2[(size_t)(tb + 1) * DIM + o];
            vv.z = Cw[(t4 + 2) * 36 + cc] + x2[(size_t)(tb + 2) * DIM + o];
            vv.w = Cw[(t4 + 3) * 36 + cc] + x2[(size_t)(tb + 3) * DIM + o];
            *(float4*)&outp[(size_t)b * (DIM * 4096) + (size_t)o * 4096
                            + hw0 + half * 64 + p * 32 + t4] = vv;
        }
    }
}

// ---------------------------------------------------------------------------
extern "C" void kernel_launch(void* const* d_in, const int* in_sizes, int n_in,
                              void* d_out, int out_size, void* d_ws, size_t ws_size,
                              hipStream_t stream)
{
    const float* x        = (const float*)d_in[0];
    const float* norm1_g  = (const float*)d_in[1];
    const float* norm1_b  = (const float*)d_in[2];
    const float* qkv_w    = (const float*)d_in[3];
    const float* qkv_b    = (const float*)d_in[4];
    const float* proj_w   = (const float*)d_in[5];
    const float* proj_b   = (const float*)d_in[6];
    const float* rpbt     = (const float*)d_in[7];
    const float* temp     = (const float*)d_in[8];
    const float* norm2_g  = (const float*)d_in[9];
    const float* norm2_b  = (const float*)d_in[10];
    const float* fc1_w    = (const float*)d_in[11];
    const float* fc1_b    = (const float*)d_in[12];
    const float* fc2_w    = (const float*)d_in[13];
    const float* fc2_b    = (const float*)d_in[14];
    float* out = (float*)d_out;

    // ws layout (bytes):
    //   [0,        12582912)  shortcut bf16 (LN1 out)
    //   [12582912, 37748736)  x2 f32
    //   [125829120,...)       weights bf16 (fragment order; qkv Q/K permuted)
    char* wsb = (char*)d_ws;
    ushort_t* shortcut_h = (ushort_t*)wsb;
    float*    x2         = (float*)(wsb + 12582912);
    ushort_t* wq  = (ushort_t*)(wsb + 125829120);      // 576x192 = 110592
    ushort_t* wp  = wq + 110592;                       // 192x192 = 36864
    ushort_t* w1  = wp + 36864;                        // 768x192 = 147456
    ushort_t* w2  = w1 + 147456;                       // 192x768 = 147456

    // 0. merged weight conversions into fragment order, one launch
    hipLaunchKernelGGL(cvt_all_kernel, dim3(432), dim3(256), 0, stream,
                       qkv_w, proj_w, fc1_w, fc2_w, wq, wp, w1, w2);

    // 1. LN1 + transpose -> shortcut bf16
    hipLaunchKernelGGL(ln1_kernel, dim3(TTOT / 64), dim3(256), 0, stream,
                       x, norm1_g, norm1_b, shortcut_h);
    // 2. fused qkv + attention + proj + residual -> x2 (2 windows/block)
    hipLaunchKernelGGL(attn_fused, dim3(NWIN / 2), dim3(768), 0, stream,
                       shortcut_h, wq, qkv_b, rpbt, temp, wp, proj_b, x2);
    // 3. fused LN2 + fc1 + GELU + fc2 + residual + NCHW transpose
    //    (v2: 128 tokens/block, 12 waves, grid 256 = 1 block/CU)
    hipLaunchKernelGGL(mlp_fused, dim3(TTOT / 128), dim3(768), 0, stream,
                       x2, w1, w2, fc1_b, fc2_b, norm2_g, norm2_b, out);
}

// Round 6
// 190.837 us; speedup vs baseline: 1.1823x; 1.0062x over previous
//
#include <hip/hip_runtime.h>
#include <hip/hip_bf16.h>
#include <math.h>

// Problem constants
#define DIM     192
#define HEADS   6
#define HEAD_DIM 32
#define NTOK    64          // tokens per window
#define IN_CC   16
#define TTOT    32768       // 8 * 64 * 64 tokens
#define NWIN    512

using bf16x8 = __attribute__((ext_vector_type(8))) short;
using f32x4  = __attribute__((ext_vector_type(4))) float;
typedef unsigned short ushort_t;

// fp32 -> bf16 round-to-nearest-even (finite inputs)
__device__ __forceinline__ ushort_t f2b(float f) {
    unsigned u = __float_as_uint(f);
    u += 0x7fffu + ((u >> 16) & 1u);
    return (ushort_t)(u >> 16);
}
__device__ __forceinline__ unsigned pk2(float a, float b) {
    return (unsigned)f2b(a) | ((unsigned)f2b(b) << 16);
}
__device__ __forceinline__ float b2f(ushort_t u) {
    return __uint_as_float(((unsigned)u) << 16);
}
__device__ __forceinline__ float m3(float a, float b, float c) {
    return fmaxf(fmaxf(a, b), c);     // clang fuses to v_max3_f32
}

// ---------------------------------------------------------------------------
// Merged weight fp32 -> bf16 conversion INTO MFMA FRAGMENT ORDER.
// W (NxK row-major) -> W' where element (o,k) lives at
//   frag = (o/16)*(K/8) + (k/8);  W'[frag*128 + (o%16)*8 + (k%8)]
// qkv weight ONLY: Q and K parts (rows [0,384)) get a within-head output-row
// permutation so the qkv GEMM's C-fragment IS the QK^T MFMA A/B fragment
// (slot s=16j+4q+r holds natural channel c=8q+4j+r). QK^T is invariant under
// a common channel permutation of q and k.
__global__ __launch_bounds__(256) void cvt_all_kernel(
    const float* __restrict__ s0, const float* __restrict__ s1,
    const float* __restrict__ s2, const float* __restrict__ s3,
    ushort_t* __restrict__ d0, ushort_t* __restrict__ d1,
    ushort_t* __restrict__ d2, ushort_t* __restrict__ d3)
{
    const int bid = blockIdx.x;
    const float* src; ushort_t* dst; int off, K; bool perm = false;
    if (bid < 108)      { src = s0; dst = d0; off = bid;       K = 192; perm = true; }
    else if (bid < 144) { src = s1; dst = d1; off = bid - 108; K = 192; }
    else if (bid < 288) { src = s2; dst = d2; off = bid - 144; K = 192; }
    else                { src = s3; dst = d3; off = bid - 288; K = 768; }
    const int K8 = K >> 3;
    const int d  = (off * 256 + threadIdx.x) * 4;
    const int frag = d >> 7, win = d & 127;
    const int m16w = win >> 3, k7 = win & 7;
    const int oblk = frag / K8, kblk = frag - oblk * K8;
    const int o = oblk * 16 + m16w, k = kblk * 8 + k7;
    int so = o;
    if (perm && o < 384) {
        const int s = o & 31;                           // slot within head block
        const int c = (((s >> 2) & 3) << 3) | (((s >> 4) & 1) << 2) | (s & 3);
        so = (o & ~31) | c;                             // natural channel row
    }
    float4 v = *(const float4*)(src + (size_t)so * K + k);
    ushort4 ov;
    ov.x = f2b(v.x); ov.y = f2b(v.y); ov.z = f2b(v.z); ov.w = f2b(v.w);
    *(ushort4*)(dst + d) = ov;
}

// ---------------------------------------------------------------------------
// Kernel 1: LayerNorm1 fused with (B,C,H,W) -> (T,C) transpose. bf16 out only.
__global__ __launch_bounds__(256) void ln1_kernel(
    const float* __restrict__ x, const float* __restrict__ g,
    const float* __restrict__ bb, ushort_t* __restrict__ outh)
{
    __shared__ float xs[64][193];
    __shared__ float mu_s[64], rs_s[64];
    __shared__ float gs[192], bs[192];
    const int tid = threadIdx.x;
    const int t0  = blockIdx.x * 64;
    const int b   = t0 >> 12;
    const int hw0 = t0 & 4095;
    if (tid < 192) { gs[tid] = g[tid]; bs[tid] = bb[tid]; }
    const int tok = tid & 63, qq = tid >> 6;
    const float* xb = x + (size_t)b * (DIM * 4096) + hw0 + tok;
    #pragma unroll
    for (int it = 0; it < 48; ++it) {
        int c = it * 4 + qq;
        xs[tok][c] = xb[(size_t)c * 4096];
    }
    __syncthreads();
    const int tok2 = tid >> 2, p = tid & 3;
    float sum = 0.f;
    #pragma unroll
    for (int c = 0; c < 48; ++c) sum += xs[tok2][p * 48 + c];
    sum += __shfl_xor(sum, 1);
    sum += __shfl_xor(sum, 2);
    const float m = sum * (1.0f / 192.0f);
    float ss = 0.f;
    #pragma unroll
    for (int c = 0; c < 48; ++c) { float d = xs[tok2][p * 48 + c] - m; ss += d * d; }
    ss += __shfl_xor(ss, 1);
    ss += __shfl_xor(ss, 2);
    if (p == 0) {
        mu_s[tok2] = m;
        rs_s[tok2] = 1.0f / sqrtf(ss * (1.0f / 192.0f) + 1e-5f);
    }
    __syncthreads();
    ushort_t* obh = outh + (size_t)t0 * DIM;
    #pragma unroll
    for (int it = 0; it < 48; ++it) {
        int idx = it * 256 + tid;
        int tk = idx / 192, c = idx % 192;
        obh[idx] = f2b((xs[tk][c] - mu_s[tk]) * rs_s[tk] * gs[c] + bs[c]);
    }
}

// ---------------------------------------------------------------------------
// MEGA-FUSED attention v5: = v4 with the residual prefetch moved OUT of the
// long live range.  Evidence: every min-waves=3 build spilled ~20 regs to
// scratch (+17 MB HBM write vs baseline's exact-25.2-MB x2 traffic).  The
// rv[4][2] prefetch (16 regs) was live from phase 1 to the epilogue, pushing
// the unified-file live set past the 168/wave cap.  It now loads after the
// B4 barrier (small live set), still ~1000 cy ahead of use under proj GEMM.
__global__ __launch_bounds__(768, 3) void attn_fused(
    const ushort_t* __restrict__ sc_h, const ushort_t* __restrict__ wqf,
    const float* __restrict__ qkv_b, const float* __restrict__ rpb_table,
    const float* __restrict__ temp, const ushort_t* __restrict__ wpf,
    const float* __restrict__ proj_b, float* __restrict__ x2)
{
    __shared__ __align__(16) char smem[127680];
    const int tid  = threadIdx.x;
    const int wave = tid >> 6, n = tid & 63;

    char* Rb = smem + wave * 4608;
    float*    Ssq = (float*)Rb;                  // [16][68] f32 transpose qtr
    ushort_t* Ph  = (ushort_t*)Rb;               // [32][72] bf16 P half (ovl)
    char* Ab = smem + 55296 + wave * 5120;
    ushort_t* Vt  = (ushort_t*)Ab;               // [32][72] V^T slot-permuted
    float*    ksb = (float*)(Ab + 4608);         // [64] slot-ordered 1/||k||
    float*    qnb = (float*)(Ab + 4864);         // [64] ssq of q per token
    float*    rpb = (float*)(smem + 116736) + wave * 228;

    const int wloc = (wave >= 6) ? 1 : 0;        // window within block
    const int h    = wave - 6 * wloc;            // head
    ushort_t* tile = (ushort_t*)(smem + wloc * 25600);       // [64][200] bf16
    ushort_t (*AoT)[200] = (ushort_t(*)[200])(smem + wloc * 25600);
    float* Cwi = (float*)(smem + 55296 + wave * 2304);       // [16][36] f32

    const int win = blockIdx.x * 2 + wloc;
    const int b   = win >> 6;
    const int wh  = (win >> 3) & 7, ww = win & 7;
    const int wb  = b * 4096 + wh * 512 + ww * 8;
    const int i1  = n >> 3, j1 = n & 7;
    const int m16 = n & 15, quad = n >> 4;

    for (int r = n; r < 225; r += 64) rpb[r] = rpb_table[r * 6 + h];

    // ---- phase 0: stage this window's shortcut tile into LDS (once) ----
    #pragma unroll
    for (int l = 0; l < 4; ++l) {
        const int g = h * 256 + l * 64 + n;
        const int t = (g * 2731) >> 16;          // g / 24
        const int r = g - t * 24;
        const int tt = wb + ((t >> 3) << 6) + (t & 7);
        uint4 v = *(const uint4*)(sc_h + (size_t)tt * 192 + r * 8);
        *(uint4*)(tile + t * 200 + r * 8) = v;
    }
    __syncthreads();                              // B1: tile ready

    // ---- phase 1a: q & k GEMMs sharing af fragments (all LDS reads) ----
    const ushort_t* tb = tile + m16 * 200 + quad * 8;
    f32x4 pq[4][2], pk[4][2];
    #pragma unroll
    for (int i = 0; i < 4; ++i)
        #pragma unroll
        for (int j = 0; j < 2; ++j) { pq[i][j] = (f32x4)(0.0f); pk[i][j] = (f32x4)(0.0f); }
    {
        const ushort_t* WbQ = wqf + (size_t)(2 * h) * 3072 + m16 * 8;
        const ushort_t* WbK = wqf + (size_t)(12 + 2 * h) * 3072 + m16 * 8;
        for (int ks = 0; ks < 192; ks += 32) {
            bf16x8 af[4], wq2[2], wk2[2];
            #pragma unroll
            for (int i = 0; i < 4; ++i)
                af[i] = *(const bf16x8*)(tb + i * 3200 + ks);
            #pragma unroll
            for (int j = 0; j < 2; ++j) {
                wq2[j] = *(const bf16x8*)(WbQ + (size_t)(j * 24 + (ks >> 3) + quad) * 128);
                wk2[j] = *(const bf16x8*)(WbK + (size_t)(j * 24 + (ks >> 3) + quad) * 128);
            }
            #pragma unroll
            for (int i = 0; i < 4; ++i)
                #pragma unroll
                for (int j = 0; j < 2; ++j) {
                    pq[i][j] = __builtin_amdgcn_mfma_f32_16x16x32_bf16(wq2[j], af[i], pq[i][j], 0, 0, 0);
                    pk[i][j] = __builtin_amdgcn_mfma_f32_16x16x32_bf16(wk2[j], af[i], pk[i][j], 0, 0, 0);
                }
        }
    }
    // q/k epilogue: bias, ssq, pack to QK^T fragments (permuted slots)
    bf16x8 qA[4], kB[4];
    #pragma unroll
    for (int part = 0; part < 2; ++part) {
        const int o0 = part * 192 + h * 32;
        const float4 bv0 = *(const float4*)&qkv_b[o0 + 8 * quad];
        const float4 bv1 = *(const float4*)&qkv_b[o0 + 8 * quad + 4];
        float ssq[4];
        #pragma unroll
        for (int i = 0; i < 4; ++i) {
            f32x4 v0 = part ? pk[i][0] : pq[i][0];
            f32x4 v1 = part ? pk[i][1] : pq[i][1];
            v0[0] += bv0.x; v0[1] += bv0.y; v0[2] += bv0.z; v0[3] += bv0.w;
            v1[0] += bv1.x; v1[1] += bv1.y; v1[2] += bv1.z; v1[3] += bv1.w;
            float sq = 0.f;
            #pragma unroll
            for (int r = 0; r < 4; ++r) sq += v0[r] * v0[r] + v1[r] * v1[r];
            ssq[i] = sq;
            bf16x8 fr;
            fr[0] = (short)f2b(v0[0]); fr[1] = (short)f2b(v0[1]);
            fr[2] = (short)f2b(v0[2]); fr[3] = (short)f2b(v0[3]);
            fr[4] = (short)f2b(v1[0]); fr[5] = (short)f2b(v1[1]);
            fr[6] = (short)f2b(v1[2]); fr[7] = (short)f2b(v1[3]);
            if (part == 0) qA[i] = fr; else kB[i] = fr;
        }
        #pragma unroll
        for (int i = 0; i < 4; ++i) {
            ssq[i] += __shfl_xor(ssq[i], 16);
            ssq[i] += __shfl_xor(ssq[i], 32);
        }
        if (quad == 0) {
            #pragma unroll
            for (int i = 0; i < 4; ++i) {
                if (part == 0) qnb[16 * i + m16] = ssq[i];
                else           ksb[4 * m16 + i]  = 1.0f / fmaxf(sqrtf(ssq[i]), 1e-12f);
            }
        }
    }

    // ---- phase 2: QK^T, register-to-register (V GEMM fills the shadow) ----
    f32x4 acc[4][4];
    #pragma unroll
    for (int i = 0; i < 4; ++i)
        #pragma unroll
        for (int j = 0; j < 4; ++j)
            acc[i][j] = __builtin_amdgcn_mfma_f32_16x16x32_bf16(qA[i], kB[j], (f32x4)(0.0f), 0, 0, 0);

    // ---- phase 1b: v GEMM (af re-read from LDS) ----
    {
        f32x4 pv[4][2];
        #pragma unroll
        for (int i = 0; i < 4; ++i)
            #pragma unroll
            for (int j = 0; j < 2; ++j) pv[i][j] = (f32x4)(0.0f);
        const ushort_t* WbV = wqf + (size_t)(24 + 2 * h) * 3072 + m16 * 8;
        for (int ks = 0; ks < 192; ks += 32) {
            bf16x8 af[4], wv2[2];
            #pragma unroll
            for (int i = 0; i < 4; ++i)
                af[i] = *(const bf16x8*)(tb + i * 3200 + ks);
            #pragma unroll
            for (int j = 0; j < 2; ++j)
                wv2[j] = *(const bf16x8*)(WbV + (size_t)(j * 24 + (ks >> 3) + quad) * 128);
            #pragma unroll
            for (int i = 0; i < 4; ++i)
                #pragma unroll
                for (int j = 0; j < 2; ++j)
                    pv[i][j] = __builtin_amdgcn_mfma_f32_16x16x32_bf16(wv2[j], af[i], pv[i][j], 0, 0, 0);
        }
        const int o0 = 384 + h * 32;
        const float4 bv0 = *(const float4*)&qkv_b[o0 + quad * 4];
        const float4 bv1 = *(const float4*)&qkv_b[o0 + 16 + quad * 4];
        #pragma unroll
        for (int i = 0; i < 4; ++i) {
            f32x4 v0 = pv[i][0], v1 = pv[i][1];
            v0[0] += bv0.x; v0[1] += bv0.y; v0[2] += bv0.z; v0[3] += bv0.w;
            v1[0] += bv1.x; v1[1] += bv1.y; v1[2] += bv1.z; v1[3] += bv1.w;
            #pragma unroll
            for (int r = 0; r < 4; ++r) {
                Vt[(quad * 4 + r) * 72 + 4 * m16 + i]      = f2b(v0[r]);
                Vt[(16 + quad * 4 + r) * 72 + 4 * m16 + i] = f2b(v1[r]);
            }
        }
    }

    __syncthreads();                              // B2: tiles dead, R usable

    // ---- transpose S via 16-row quarter buffer (wave-local) ----
    float s[64];
    #pragma unroll
    for (int i = 0; i < 4; ++i) {
        #pragma unroll
        for (int r = 0; r < 4; ++r) {
            f32x4 vv = { acc[i][0][r], acc[i][1][r], acc[i][2][r], acc[i][3][r] };
            *(f32x4*)&Ssq[(4 * quad + r) * 68 + 4 * m16] = vv;
        }
        if ((n >> 4) == i) {
            #pragma unroll
            for (int c = 0; c < 16; ++c)
                *(float4*)&s[4 * c] = *(const float4*)&Ssq[(n & 15) * 68 + 4 * c];
        }
    }

    // ---- cosine scales (positive; preserve top-k ordering) ----
    const float qs = temp[h] / fmaxf(sqrtf(qnb[n]), 1e-12f);
    #pragma unroll
    for (int c = 0; c < 16; ++c) {
        float4 kv = *(const float4*)&ksb[4 * c];
        s[4*c+0] *= qs * kv.x; s[4*c+1] *= qs * kv.y;
        s[4*c+2] *= qs * kv.z; s[4*c+3] *= qs * kv.w;
    }

    // ---- top-16 threshold via masked v_max3 trees (bit-identical) ----
    float thr = 1e30f;
    for (int it = 0; it < IN_CC; ++it) {
        #define MK(c) ((s[(c)] < thr) ? s[(c)] : -1e30f)
        float w[22];
        #pragma unroll
        for (int g = 0; g < 21; ++g) w[g] = m3(MK(3*g), MK(3*g+1), MK(3*g+2));
        w[21] = MK(63);
        #undef MK
        float y[8];
        #pragma unroll
        for (int g = 0; g < 7; ++g) y[g] = m3(w[3*g], w[3*g+1], w[3*g+2]);
        y[7] = w[21];
        thr = m3(m3(y[0], y[1], y[2]), m3(y[3], y[4], y[5]), fmaxf(y[6], y[7]));
    }

    // ---- mask + rpb + softmax (slot c holds true m = 16*(c&3)+(c>>2)) ----
    const int basen = i1 * 15 + j1;
    float mxp[8];
    #pragma unroll
    for (int c = 0; c < 64; ++c) {
        const int m = 16 * (c & 3) + (c >> 2);
        const int i2 = m >> 3, j2 = m & 7;
        float vv = ((s[c] >= thr) ? s[c] : -100.0f)
                 + rpb[basen + (7 - i2) * 15 + (7 - j2)];
        s[c] = vv;
        if (c < 8) mxp[c] = vv; else mxp[c & 7] = fmaxf(mxp[c & 7], vv);
    }
    const float mx = m3(m3(mxp[0], mxp[1], mxp[2]), m3(mxp[3], mxp[4], mxp[5]),
                        fmaxf(mxp[6], mxp[7]));
    float sum = 0.f;
    #pragma unroll
    for (int c = 0; c < 64; ++c) { float e = __expf(s[c] - mx); s[c] = e; sum += e; }
    const float inv = 1.0f / sum;
    #pragma unroll
    for (int c = 0; c < 64; ++c) s[c] *= inv;

    // ---- PV via MFMA, P staged in two 32-row halves (R overlay) ----
    bf16x8 vb[2][2];
    #pragma unroll
    for (int kh2 = 0; kh2 < 2; ++kh2)
        #pragma unroll
        for (int j2 = 0; j2 < 2; ++j2)
            vb[kh2][j2] = *(const bf16x8*)&Vt[(16 * j2 + m16) * 72 + kh2 * 32 + quad * 8];

    f32x4 o[4][2];
    #pragma unroll
    for (int i = 0; i < 4; ++i)
        #pragma unroll
        for (int j2 = 0; j2 < 2; ++j2)
            o[i][j2] = (f32x4)(0.0f);
    #pragma unroll
    for (int hf = 0; hf < 2; ++hf) {
        if ((n >> 5) == hf) {
            #pragma unroll
            for (int g = 0; g < 8; ++g) {
                uint4 w;
                w.x = pk2(s[8*g+0], s[8*g+1]); w.y = pk2(s[8*g+2], s[8*g+3]);
                w.z = pk2(s[8*g+4], s[8*g+5]); w.w = pk2(s[8*g+6], s[8*g+7]);
                *(uint4*)&Ph[(n & 31) * 72 + 8 * g] = w;
            }
        }
        #pragma unroll
        for (int ih = 0; ih < 2; ++ih) {
            const int i = 2 * hf + ih;
            #pragma unroll
            for (int kh2 = 0; kh2 < 2; ++kh2) {
                bf16x8 pafr = *(const bf16x8*)&Ph[(16 * ih + m16) * 72 + kh2 * 32 + quad * 8];
                o[i][0] = __builtin_amdgcn_mfma_f32_16x16x32_bf16(pafr, vb[kh2][0], o[i][0], 0, 0, 0);
                o[i][1] = __builtin_amdgcn_mfma_f32_16x16x32_bf16(pafr, vb[kh2][1], o[i][1], 0, 0, 0);
            }
        }
    }
    __syncthreads();   // B3: all waves done with arenas -> AoT may overlay

    // ---- O -> shared AoT tile (bf16, token-major, stride 200) ----
    #pragma unroll
    for (int i = 0; i < 4; ++i) {
        #pragma unroll
        for (int r = 0; r < 4; ++r) {
            const int row = 16 * i + 4 * quad + r;
            AoT[row][h * 32 + m16]      = f2b(o[i][0][r]);
            AoT[row][h * 32 + 16 + m16] = f2b(o[i][1][r]);
        }
    }
    __syncthreads();   // B4

    // ---- residual prefetch: AFTER B4, in a low-pressure region; latency
    //      hidden under the proj GEMM (~1000 cy). Lines are L2-warm. ----
    const int r8 = n >> 3, c4 = (n & 7) * 4;
    uint2 rv[4][2];
    #pragma unroll
    for (int i = 0; i < 4; ++i)
        #pragma unroll
        for (int q = 0; q < 2; ++q) {
            const int tok = 16 * i + 8 * q + r8;
            const int tt = wb + ((tok >> 3) << 6) + (tok & 7);
            rv[i][q] = *(const uint2*)(sc_h + (size_t)tt * 192 + h * 32 + c4);
        }

    // ---- proj: wave computes outs [h*32, h*32+32) of its window, K=192 ----
    f32x4 pacc[4][2];
    #pragma unroll
    for (int i = 0; i < 4; ++i)
        #pragma unroll
        for (int j = 0; j < 2; ++j)
            pacc[i][j] = (f32x4)(0.0f);
    const ushort_t* Wb = wpf + (size_t)(h * 2) * 24 * 128 + m16 * 8;
    for (int ks = 0; ks < 192; ks += 32) {
        bf16x8 af[4], wv[2];
        #pragma unroll
        for (int i = 0; i < 4; ++i)
            af[i] = *(const bf16x8*)&AoT[16 * i + m16][quad * 8 + ks];
        #pragma unroll
        for (int j = 0; j < 2; ++j)
            wv[j] = *(const bf16x8*)(Wb + (size_t)(j * 24 + (ks >> 3) + quad) * 128);
        #pragma unroll
        for (int i = 0; i < 4; ++i)
            #pragma unroll
            for (int j = 0; j < 2; ++j)
                pacc[i][j] = __builtin_amdgcn_mfma_f32_16x16x32_bf16(wv[j], af[i], pacc[i][j], 0, 0, 0);
    }

    // ---- per i-group: stage C^T (+bias) into Cwi[16][36]; store x2 with
    //      full 128-B-granule coverage per instruction. ----
    const float4 bj0 = *(const float4*)&proj_b[h * 32 + quad * 4];
    const float4 bj1 = *(const float4*)&proj_b[h * 32 + 16 + quad * 4];
    #pragma unroll
    for (int i = 0; i < 4; ++i) {
        f32x4 v0 = pacc[i][0], v1 = pacc[i][1];
        v0[0] += bj0.x; v0[1] += bj0.y; v0[2] += bj0.z; v0[3] += bj0.w;
        v1[0] += bj1.x; v1[1] += bj1.y; v1[2] += bj1.z; v1[3] += bj1.w;
        *(f32x4*)&Cwi[m16 * 36 + quad * 4]      = v0;
        *(f32x4*)&Cwi[m16 * 36 + 16 + quad * 4] = v1;
        #pragma unroll
        for (int q = 0; q < 2; ++q) {
            const int row = 8 * q + r8;
            const int tok = 16 * i + row;
            const int tt = wb + ((tok >> 3) << 6) + (tok & 7);
            float4 vv = *(const float4*)&Cwi[row * 36 + c4];
            const uint2 rr = rv[i][q];
            vv.x += b2f((ushort_t)(rr.x & 0xffffu));
            vv.y += b2f((ushort_t)(rr.x >> 16));
            vv.z += b2f((ushort_t)(rr.y & 0xffffu));
            vv.w += b2f((ushort_t)(rr.y >> 16));
            *(float4*)&x2[(size_t)tt * DIM + h * 32 + c4] = vv;
        }
    }
}

// ---------------------------------------------------------------------------
// FUSED MLP v2 (kept from round 5): 128 tokens/block, 12 waves, grid 256.
__global__ __launch_bounds__(768, 3) void mlp_fused(
    const float* __restrict__ x2, const ushort_t* __restrict__ w1f,
    const ushort_t* __restrict__ w2f, const float* __restrict__ fc1_b,
    const float* __restrict__ fc2_b, const float* __restrict__ g2,
    const float* __restrict__ b2, float* __restrict__ outp)
{
    __shared__ __align__(16) char smem[103936];
    ushort_t (*h_h)[200] = (ushort_t(*)[200])smem;             // [128][200]
    ushort_t (*a1c)[200] = (ushort_t(*)[200])(smem + 51200);   // [128][200]
    float* gs = (float*)(smem + 102400);
    float* bs = gs + 192;

    const int tid  = threadIdx.x;
    const int wave = tid >> 6, lane = tid & 63;
    const int m16 = lane & 15, quad = lane >> 4;
    const int half = wave / 6, ow = wave - 6 * half;   // token-half, out-group
    const int t0  = blockIdx.x * 128;
    const int b   = t0 >> 12;
    const int hw0 = t0 & 4095;

    if (tid < 192) { gs[tid] = g2[tid]; bs[tid] = b2[tid]; }
    __syncthreads();
    if (tid < 512) {
        const int tok = tid >> 2, p = tid & 3;
        const float* rp = x2 + (size_t)(t0 + tok) * DIM + p * 48;
        float xv[48];
        #pragma unroll
        for (int c4 = 0; c4 < 12; ++c4)
            *(float4*)&xv[c4 * 4] = *(const float4*)(rp + c4 * 4);
        float sum = 0.f;
        #pragma unroll
        for (int c = 0; c < 48; ++c) sum += xv[c];
        sum += __shfl_xor(sum, 1);
        sum += __shfl_xor(sum, 2);
        const float m = sum * (1.0f / 192.0f);
        float ss = 0.f;
        #pragma unroll
        for (int c = 0; c < 48; ++c) { float d = xv[c] - m; ss += d * d; }
        ss += __shfl_xor(ss, 1);
        ss += __shfl_xor(ss, 2);
        const float rs = 1.0f / sqrtf(ss * (1.0f / 192.0f) + 1e-5f);
        ushort_t* hp = &h_h[tok][p * 48];
        #pragma unroll
        for (int c2 = 0; c2 < 24; ++c2) {
            float v0 = (xv[2*c2]   - m) * rs * gs[p * 48 + 2*c2]   + bs[p * 48 + 2*c2];
            float v1 = (xv[2*c2+1] - m) * rs * gs[p * 48 + 2*c2+1] + bs[p * 48 + 2*c2+1];
            *(unsigned*)(hp + 2 * c2) = pk2(v0, v1);
        }
    }
    __syncthreads();

    f32x4 acc2[4][2];
    #pragma unroll
    for (int i = 0; i < 4; ++i)
        #pragma unroll
        for (int j = 0; j < 2; ++j)
            acc2[i][j] = (f32x4)(0.0f);

    for (int c = 0; c < 4; ++c) {                 // 4 chunks of 192 fc1-outs
        f32x4 acc1[4][2];
        #pragma unroll
        for (int i = 0; i < 4; ++i)
            #pragma unroll
            for (int j = 0; j < 2; ++j)
                acc1[i][j] = (f32x4)(0.0f);
        const ushort_t* Wb1 = w1f + (size_t)(c * 12 + ow * 2) * 3072 + m16 * 8;
        for (int ks = 0; ks < 192; ks += 32) {
            bf16x8 af[4], wv[2];
            #pragma unroll
            for (int i = 0; i < 4; ++i)
                af[i] = *(const bf16x8*)&h_h[half * 64 + 16 * i + m16][quad * 8 + ks];
            #pragma unroll
            for (int j = 0; j < 2; ++j)
                wv[j] = *(const bf16x8*)(Wb1 + (size_t)(j * 24 + (ks >> 3) + quad) * 128);
            #pragma unroll
            for (int i = 0; i < 4; ++i)
                #pragma unroll
                for (int j = 0; j < 2; ++j)
                    acc1[i][j] = __builtin_amdgcn_mfma_f32_16x16x32_bf16(wv[j], af[i], acc1[i][j], 0, 0, 0);
        }
        #pragma unroll
        for (int j = 0; j < 2; ++j) {
            const int o = c * 192 + ow * 32 + 16 * j + quad * 4;
            const float4 bv = *(const float4*)&fc1_b[o];
            #pragma unroll
            for (int i = 0; i < 4; ++i) {
                f32x4 v = acc1[i][j];
                v[0] += bv.x; v[1] += bv.y; v[2] += bv.z; v[3] += bv.w;
                #pragma unroll
                for (int r = 0; r < 4; ++r) {
                    float xg = v[r];
                    float e1 = __expf(xg * (1.5957691f + 0.0713548f * xg * xg)) + 1.0f;
                    v[r] = xg - xg * __builtin_amdgcn_rcpf(e1);
                }
                uint2 pkd;
                pkd.x = pk2(v[0], v[1]); pkd.y = pk2(v[2], v[3]);
                *(uint2*)&a1c[half * 64 + 16 * i + m16][ow * 32 + 16 * j + quad * 4] = pkd;
            }
        }
        __syncthreads();
        const ushort_t* Wb2 = w2f + (size_t)(ow * 2) * 12288 + m16 * 8;
        for (int ks = 0; ks < 192; ks += 32) {
            bf16x8 af2[4], wv2[2];
            #pragma unroll
            for (int i = 0; i < 4; ++i)
                af2[i] = *(const bf16x8*)&a1c[half * 64 + 16 * i + m16][quad * 8 + ks];
            #pragma unroll
            for (int j = 0; j < 2; ++j)
                wv2[j] = *(const bf16x8*)(Wb2 + (size_t)(j * 96 + c * 24 + (ks >> 3) + quad) * 128);
            #pragma unroll
            for (int i = 0; i < 4; ++i)
                #pragma unroll
                for (int j = 0; j < 2; ++j)
                    acc2[i][j] = __builtin_amdgcn_mfma_f32_16x16x32_bf16(wv2[j], af2[i], acc2[i][j], 0, 0, 0);
        }
        __syncthreads();
    }

    // ---- epilogue: stage [32 tok][32 outs] per pass, write NCHW with
    //      full 128-B-granule runs (64-token-consecutive per channel). ----
    float* Cw = (float*)(smem + wave * 4608);      // [32][36] f32, overlay
    float4 b2j[2];
    #pragma unroll
    for (int j = 0; j < 2; ++j)
        b2j[j] = *(const float4*)&fc2_b[ow * 32 + 16 * j + quad * 4];
    #pragma unroll
    for (int p = 0; p < 2; ++p) {
        #pragma unroll
        for (int ih = 0; ih < 2; ++ih) {
            const int i = 2 * p + ih;
            #pragma unroll
            for (int j = 0; j < 2; ++j) {
                f32x4 v = acc2[i][j];
                v[0] += b2j[j].x; v[1] += b2j[j].y; v[2] += b2j[j].z; v[3] += b2j[j].w;
                *(f32x4*)&Cw[(ih * 16 + m16) * 36 + 16 * j + quad * 4] = v;
            }
        }
        #pragma unroll
        for (int q = 0; q < 4; ++q) {
            const int idx = q * 64 + lane;
            const int cc = idx >> 3, t4 = (idx & 7) * 4;
            const int o  = ow * 32 + cc;
            const int tb = t0 + half * 64 + p * 32 + t4;
            float4 vv;
            vv.x = Cw[(t4 + 0) * 36 + cc] + x2[(size_t)(tb + 0) * DIM + o];
            vv.y = Cw[(t4 + 1) * 36 + cc] + x2[(size_t)(tb + 1) * DIM + o];
            vv.z = Cw[(t4 + 2) * 36 + cc] + x2[(size_t)(tb + 2) * DIM + o];
            vv.w = Cw[(t4 + 3) * 36 + cc] + x2[(size_t)(tb + 3) * DIM + o];
            *(float4*)&outp[(size_t)b * (DIM * 4096) + (size_t)o * 4096
                            + hw0 + half * 64 + p * 32 + t4] = vv;
        }
    }
}

// ---------------------------------------------------------------------------
extern "C" void kernel_launch(void* const* d_in, const int* in_sizes, int n_in,
                              void* d_out, int out_size, void* d_ws, size_t ws_size,
                              hipStream_t stream)
{
    const float* x        = (const float*)d_in[0];
    const float* norm1_g  = (const float*)d_in[1];
    const float* norm1_b  = (const float*)d_in[2];
    const float* qkv_w    = (const float*)d_in[3];
    const float* qkv_b    = (const float*)d_in[4];
    const float* proj_w   = (const float*)d_in[5];
    const float* proj_b   = (const float*)d_in[6];
    const float* rpbt     = (const float*)d_in[7];
    const float* temp     = (const float*)d_in[8];
    const float* norm2_g  = (const float*)d_in[9];
    const float* norm2_b  = (const float*)d_in[10];
    const float* fc1_w    = (const float*)d_in[11];
    const float* fc1_b    = (const float*)d_in[12];
    const float* fc2_w    = (const float*)d_in[13];
    const float* fc2_b    = (const float*)d_in[14];
    float* out = (float*)d_out;

    // ws layout (bytes):
    //   [0,        12582912)  shortcut bf16 (LN1 out)
    //   [12582912, 37748736)  x2 f32
    //   [125829120,...)       weights bf16 (fragment order; qkv Q/K permuted)
    char* wsb = (char*)d_ws;
    ushort_t* shortcut_h = (ushort_t*)wsb;
    float*    x2         = (float*)(wsb + 12582912);
    ushort_t* wq  = (ushort_t*)(wsb + 125829120);      // 576x192 = 110592
    ushort_t* wp  = wq + 110592;                       // 192x192 = 36864
    ushort_t* w1  = wp + 36864;                        // 768x192 = 147456
    ushort_t* w2  = w1 + 147456;                       // 192x768 = 147456

    // 0. merged weight conversions into fragment order, one launch
    hipLaunchKernelGGL(cvt_all_kernel, dim3(432), dim3(256), 0, stream,
                       qkv_w, proj_w, fc1_w, fc2_w, wq, wp, w1, w2);

    // 1. LN1 + transpose -> shortcut bf16
    hipLaunchKernelGGL(ln1_kernel, dim3(TTOT / 64), dim3(256), 0, stream,
                       x, norm1_g, norm1_b, shortcut_h);
    // 2. fused qkv + attention + proj + residual -> x2 (2 windows/block)
    hipLaunchKernelGGL(attn_fused, dim3(NWIN / 2), dim3(768), 0, stream,
                       shortcut_h, wq, qkv_b, rpbt, temp, wp, proj_b, x2);
    // 3. fused LN2 + fc1 + GELU + fc2 + residual + NCHW transpose
    hipLaunchKernelGGL(mlp_fused, dim3(TTOT / 128), dim3(768), 0, stream,
                       x2, w1, w2, fc1_b, fc2_b, norm2_g, norm2_b, out);
}

// Round 7
// 189.339 us; speedup vs baseline: 1.1917x; 1.0079x over previous
//
#include <hip/hip_runtime.h>
#include <hip/hip_bf16.h>
#include <math.h>

// Problem constants
#define DIM     192
#define HEADS   6
#define HEAD_DIM 32
#define NTOK    64          // tokens per window
#define IN_CC   16
#define TTOT    32768       // 8 * 64 * 64 tokens
#define NWIN    512

using bf16x8 = __attribute__((ext_vector_type(8))) short;
using f32x4  = __attribute__((ext_vector_type(4))) float;
typedef unsigned short ushort_t;

// fp32 -> bf16 RNE via native cast (compiler emits v_cvt_pk_bf16_f32 for
// pairs on gfx950 — guide m240: scalar casts beat both bit-twiddle and
// inline asm).  Bit-identical to the old add-0x7fff trick for finite inputs.
__device__ __forceinline__ ushort_t f2b(float f) {
    __bf16 h = (__bf16)f;
    ushort_t u;
    __builtin_memcpy(&u, &h, 2);
    return u;
}
__device__ __forceinline__ unsigned pk2(float a, float b) {
    return (unsigned)f2b(a) | ((unsigned)f2b(b) << 16);
}
__device__ __forceinline__ float b2f(ushort_t u) {
    return __uint_as_float(((unsigned)u) << 16);
}
__device__ __forceinline__ float m3(float a, float b, float c) {
    return fmaxf(fmaxf(a, b), c);     // clang fuses to v_max3_f32
}
#define F4C(v, r) ((r) == 0 ? (v).x : (r) == 1 ? (v).y : (r) == 2 ? (v).z : (v).w)

// ---------------------------------------------------------------------------
// PREP kernel: weight fp32->bf16 fragment-order conversion (432 blocks)
// MERGED with LN1+transpose (512 blocks).  One launch instead of two; the
// two independent small kernels overlap and fill the machine.
//
// cvt part: W (NxK row-major) -> W' where element (o,k) lives at
//   frag = (o/16)*(K/8) + (k/8);  W'[frag*128 + (o%16)*8 + (k%8)]
// qkv weight ONLY: Q and K parts (rows [0,384)) get a within-head output-row
// permutation so the qkv GEMM's C-fragment IS the QK^T MFMA A/B fragment
// (slot s=16j+4q+r holds natural channel c=8q+4j+r). QK^T is invariant under
// a common channel permutation of q and k.
__global__ __launch_bounds__(256) void prep_kernel(
    const float* __restrict__ s0, const float* __restrict__ s1,
    const float* __restrict__ s2, const float* __restrict__ s3,
    ushort_t* __restrict__ d0, ushort_t* __restrict__ d1,
    ushort_t* __restrict__ d2, ushort_t* __restrict__ d3,
    const float* __restrict__ x, const float* __restrict__ g,
    const float* __restrict__ bb, ushort_t* __restrict__ outh)
{
    __shared__ float xs[64][193];
    __shared__ float mu_s[64], rs_s[64];
    __shared__ float gs[192], bs[192];
    const int bid = blockIdx.x;
    const int tid = threadIdx.x;

    if (bid < 432) {
        // ---------------- weight conversion ----------------
        const float* src; ushort_t* dst; int off, K; bool perm = false;
        if (bid < 108)      { src = s0; dst = d0; off = bid;       K = 192; perm = true; }
        else if (bid < 144) { src = s1; dst = d1; off = bid - 108; K = 192; }
        else if (bid < 288) { src = s2; dst = d2; off = bid - 144; K = 192; }
        else                { src = s3; dst = d3; off = bid - 288; K = 768; }
        const int K8 = K >> 3;
        const int d  = (off * 256 + tid) * 4;
        const int frag = d >> 7, win = d & 127;
        const int m16w = win >> 3, k7 = win & 7;
        const int oblk = frag / K8, kblk = frag - oblk * K8;
        const int o = oblk * 16 + m16w, k = kblk * 8 + k7;
        int so = o;
        if (perm && o < 384) {
            const int s = o & 31;                       // slot within head block
            const int c = (((s >> 2) & 3) << 3) | (((s >> 4) & 1) << 2) | (s & 3);
            so = (o & ~31) | c;                         // natural channel row
        }
        float4 v = *(const float4*)(src + (size_t)so * K + k);
        ushort4 ov;
        ov.x = f2b(v.x); ov.y = f2b(v.y); ov.z = f2b(v.z); ov.w = f2b(v.w);
        *(ushort4*)(dst + d) = ov;
        return;
    }

    // ---------------- LN1 + (B,C,H,W)->(T,C) transpose, bf16 out ----------------
    const int t0  = (bid - 432) * 64;
    const int b   = t0 >> 12;
    const int hw0 = t0 & 4095;
    if (tid < 192) { gs[tid] = g[tid]; bs[tid] = bb[tid]; }
    const int tok = tid & 63, qq = tid >> 6;
    const float* xb = x + (size_t)b * (DIM * 4096) + hw0 + tok;
    #pragma unroll
    for (int it = 0; it < 48; ++it) {
        int c = it * 4 + qq;
        xs[tok][c] = xb[(size_t)c * 4096];
    }
    __syncthreads();
    const int tok2 = tid >> 2, p = tid & 3;
    float sum = 0.f;
    #pragma unroll
    for (int c = 0; c < 48; ++c) sum += xs[tok2][p * 48 + c];
    sum += __shfl_xor(sum, 1);
    sum += __shfl_xor(sum, 2);
    const float m = sum * (1.0f / 192.0f);
    float ss = 0.f;
    #pragma unroll
    for (int c = 0; c < 48; ++c) { float d = xs[tok2][p * 48 + c] - m; ss += d * d; }
    ss += __shfl_xor(ss, 1);
    ss += __shfl_xor(ss, 2);
    if (p == 0) {
        mu_s[tok2] = m;
        rs_s[tok2] = 1.0f / sqrtf(ss * (1.0f / 192.0f) + 1e-5f);
    }
    __syncthreads();
    ushort_t* obh = outh + (size_t)t0 * DIM;
    #pragma unroll
    for (int it = 0; it < 48; ++it) {
        int idx = it * 256 + tid;
        int tk = idx / 192, c = idx % 192;
        obh[idx] = f2b((xs[tk][c] - mu_s[tk]) * rs_s[tk] * gs[c] + bs[c]);
    }
}

// ---------------------------------------------------------------------------
// MEGA-FUSED attention v6: = v5 with
//  - native bf16 converts (f2b/pk2 -> v_cvt_pk path; ~400 fewer VALU ops/lane)
//  - Vt epilogue vectorized: r-outer loop packs 4 i-values per ds_write_b64
//    (32 scalar u16 writes + 32 f2b -> 8 b64 writes + 16 cvt_pk).
__global__ __launch_bounds__(768, 3) void attn_fused(
    const ushort_t* __restrict__ sc_h, const ushort_t* __restrict__ wqf,
    const float* __restrict__ qkv_b, const float* __restrict__ rpb_table,
    const float* __restrict__ temp, const ushort_t* __restrict__ wpf,
    const float* __restrict__ proj_b, float* __restrict__ x2)
{
    __shared__ __align__(16) char smem[127680];
    const int tid  = threadIdx.x;
    const int wave = tid >> 6, n = tid & 63;

    char* Rb = smem + wave * 4608;
    float*    Ssq = (float*)Rb;                  // [16][68] f32 transpose qtr
    ushort_t* Ph  = (ushort_t*)Rb;               // [32][72] bf16 P half (ovl)
    char* Ab = smem + 55296 + wave * 5120;
    ushort_t* Vt  = (ushort_t*)Ab;               // [32][72] V^T slot-permuted
    float*    ksb = (float*)(Ab + 4608);         // [64] slot-ordered 1/||k||
    float*    qnb = (float*)(Ab + 4864);         // [64] ssq of q per token
    float*    rpb = (float*)(smem + 116736) + wave * 228;

    const int wloc = (wave >= 6) ? 1 : 0;        // window within block
    const int h    = wave - 6 * wloc;            // head
    ushort_t* tile = (ushort_t*)(smem + wloc * 25600);       // [64][200] bf16
    ushort_t (*AoT)[200] = (ushort_t(*)[200])(smem + wloc * 25600);
    float* Cwi = (float*)(smem + 55296 + wave * 2304);       // [16][36] f32

    const int win = blockIdx.x * 2 + wloc;
    const int b   = win >> 6;
    const int wh  = (win >> 3) & 7, ww = win & 7;
    const int wb  = b * 4096 + wh * 512 + ww * 8;
    const int i1  = n >> 3, j1 = n & 7;
    const int m16 = n & 15, quad = n >> 4;

    for (int r = n; r < 225; r += 64) rpb[r] = rpb_table[r * 6 + h];

    // ---- phase 0: stage this window's shortcut tile into LDS (once) ----
    #pragma unroll
    for (int l = 0; l < 4; ++l) {
        const int g = h * 256 + l * 64 + n;
        const int t = (g * 2731) >> 16;          // g / 24
        const int r = g - t * 24;
        const int tt = wb + ((t >> 3) << 6) + (t & 7);
        uint4 v = *(const uint4*)(sc_h + (size_t)tt * 192 + r * 8);
        *(uint4*)(tile + t * 200 + r * 8) = v;
    }
    __syncthreads();                              // B1: tile ready

    // ---- phase 1a: q & k GEMMs sharing af fragments (all LDS reads) ----
    const ushort_t* tb = tile + m16 * 200 + quad * 8;
    f32x4 pq[4][2], pk[4][2];
    #pragma unroll
    for (int i = 0; i < 4; ++i)
        #pragma unroll
        for (int j = 0; j < 2; ++j) { pq[i][j] = (f32x4)(0.0f); pk[i][j] = (f32x4)(0.0f); }
    {
        const ushort_t* WbQ = wqf + (size_t)(2 * h) * 3072 + m16 * 8;
        const ushort_t* WbK = wqf + (size_t)(12 + 2 * h) * 3072 + m16 * 8;
        for (int ks = 0; ks < 192; ks += 32) {
            bf16x8 af[4], wq2[2], wk2[2];
            #pragma unroll
            for (int i = 0; i < 4; ++i)
                af[i] = *(const bf16x8*)(tb + i * 3200 + ks);
            #pragma unroll
            for (int j = 0; j < 2; ++j) {
                wq2[j] = *(const bf16x8*)(WbQ + (size_t)(j * 24 + (ks >> 3) + quad) * 128);
                wk2[j] = *(const bf16x8*)(WbK + (size_t)(j * 24 + (ks >> 3) + quad) * 128);
            }
            #pragma unroll
            for (int i = 0; i < 4; ++i)
                #pragma unroll
                for (int j = 0; j < 2; ++j) {
                    pq[i][j] = __builtin_amdgcn_mfma_f32_16x16x32_bf16(wq2[j], af[i], pq[i][j], 0, 0, 0);
                    pk[i][j] = __builtin_amdgcn_mfma_f32_16x16x32_bf16(wk2[j], af[i], pk[i][j], 0, 0, 0);
                }
        }
    }
    // q/k epilogue: bias, ssq, pack to QK^T fragments (permuted slots)
    bf16x8 qA[4], kB[4];
    #pragma unroll
    for (int part = 0; part < 2; ++part) {
        const int o0 = part * 192 + h * 32;
        const float4 bv0 = *(const float4*)&qkv_b[o0 + 8 * quad];
        const float4 bv1 = *(const float4*)&qkv_b[o0 + 8 * quad + 4];
        float ssq[4];
        #pragma unroll
        for (int i = 0; i < 4; ++i) {
            f32x4 v0 = part ? pk[i][0] : pq[i][0];
            f32x4 v1 = part ? pk[i][1] : pq[i][1];
            v0[0] += bv0.x; v0[1] += bv0.y; v0[2] += bv0.z; v0[3] += bv0.w;
            v1[0] += bv1.x; v1[1] += bv1.y; v1[2] += bv1.z; v1[3] += bv1.w;
            float sq = 0.f;
            #pragma unroll
            for (int r = 0; r < 4; ++r) sq += v0[r] * v0[r] + v1[r] * v1[r];
            ssq[i] = sq;
            uint4 uu;
            uu.x = pk2(v0[0], v0[1]); uu.y = pk2(v0[2], v0[3]);
            uu.z = pk2(v1[0], v1[1]); uu.w = pk2(v1[2], v1[3]);
            bf16x8 fr = *(bf16x8*)&uu;
            if (part == 0) qA[i] = fr; else kB[i] = fr;
        }
        #pragma unroll
        for (int i = 0; i < 4; ++i) {
            ssq[i] += __shfl_xor(ssq[i], 16);
            ssq[i] += __shfl_xor(ssq[i], 32);
        }
        if (quad == 0) {
            #pragma unroll
            for (int i = 0; i < 4; ++i) {
                if (part == 0) qnb[16 * i + m16] = ssq[i];
                else           ksb[4 * m16 + i]  = 1.0f / fmaxf(sqrtf(ssq[i]), 1e-12f);
            }
        }
    }

    // ---- phase 2: QK^T, register-to-register (V GEMM fills the shadow) ----
    f32x4 acc[4][4];
    #pragma unroll
    for (int i = 0; i < 4; ++i)
        #pragma unroll
        for (int j = 0; j < 4; ++j)
            acc[i][j] = __builtin_amdgcn_mfma_f32_16x16x32_bf16(qA[i], kB[j], (f32x4)(0.0f), 0, 0, 0);

    // ---- phase 1b: v GEMM (af re-read from LDS) ----
    {
        f32x4 pv[4][2];
        #pragma unroll
        for (int i = 0; i < 4; ++i)
            #pragma unroll
            for (int j = 0; j < 2; ++j) pv[i][j] = (f32x4)(0.0f);
        const ushort_t* WbV = wqf + (size_t)(24 + 2 * h) * 3072 + m16 * 8;
        for (int ks = 0; ks < 192; ks += 32) {
            bf16x8 af[4], wv2[2];
            #pragma unroll
            for (int i = 0; i < 4; ++i)
                af[i] = *(const bf16x8*)(tb + i * 3200 + ks);
            #pragma unroll
            for (int j = 0; j < 2; ++j)
                wv2[j] = *(const bf16x8*)(WbV + (size_t)(j * 24 + (ks >> 3) + quad) * 128);
            #pragma unroll
            for (int i = 0; i < 4; ++i)
                #pragma unroll
                for (int j = 0; j < 2; ++j)
                    pv[i][j] = __builtin_amdgcn_mfma_f32_16x16x32_bf16(wv2[j], af[i], pv[i][j], 0, 0, 0);
        }
        // v epilogue: r-outer, 4 i-values packed per ds_write_b64
        const int o0 = 384 + h * 32;
        const float4 bv0 = *(const float4*)&qkv_b[o0 + quad * 4];
        const float4 bv1 = *(const float4*)&qkv_b[o0 + 16 + quad * 4];
        #pragma unroll
        for (int r = 0; r < 4; ++r) {
            const float b0r = F4C(bv0, r), b1r = F4C(bv1, r);
            ushort4 w0, w1;
            w0.x = f2b(pv[0][0][r] + b0r); w0.y = f2b(pv[1][0][r] + b0r);
            w0.z = f2b(pv[2][0][r] + b0r); w0.w = f2b(pv[3][0][r] + b0r);
            w1.x = f2b(pv[0][1][r] + b1r); w1.y = f2b(pv[1][1][r] + b1r);
            w1.z = f2b(pv[2][1][r] + b1r); w1.w = f2b(pv[3][1][r] + b1r);
            *(ushort4*)&Vt[(quad * 4 + r) * 72 + 4 * m16]        = w0;
            *(ushort4*)&Vt[(16 + quad * 4 + r) * 72 + 4 * m16]   = w1;
        }
    }

    __syncthreads();                              // B2: tiles dead, R usable

    // ---- transpose S via 16-row quarter buffer (wave-local) ----
    float s[64];
    #pragma unroll
    for (int i = 0; i < 4; ++i) {
        #pragma unroll
        for (int r = 0; r < 4; ++r) {
            f32x4 vv = { acc[i][0][r], acc[i][1][r], acc[i][2][r], acc[i][3][r] };
            *(f32x4*)&Ssq[(4 * quad + r) * 68 + 4 * m16] = vv;
        }
        if ((n >> 4) == i) {
            #pragma unroll
            for (int c = 0; c < 16; ++c)
                *(float4*)&s[4 * c] = *(const float4*)&Ssq[(n & 15) * 68 + 4 * c];
        }
    }

    // ---- cosine scales (positive; preserve top-k ordering) ----
    const float qs = temp[h] / fmaxf(sqrtf(qnb[n]), 1e-12f);
    #pragma unroll
    for (int c = 0; c < 16; ++c) {
        float4 kv = *(const float4*)&ksb[4 * c];
        s[4*c+0] *= qs * kv.x; s[4*c+1] *= qs * kv.y;
        s[4*c+2] *= qs * kv.z; s[4*c+3] *= qs * kv.w;
    }

    // ---- top-16 threshold via masked v_max3 trees (bit-identical) ----
    float thr = 1e30f;
    for (int it = 0; it < IN_CC; ++it) {
        #define MK(c) ((s[(c)] < thr) ? s[(c)] : -1e30f)
        float w[22];
        #pragma unroll
        for (int g = 0; g < 21; ++g) w[g] = m3(MK(3*g), MK(3*g+1), MK(3*g+2));
        w[21] = MK(63);
        #undef MK
        float y[8];
        #pragma unroll
        for (int g = 0; g < 7; ++g) y[g] = m3(w[3*g], w[3*g+1], w[3*g+2]);
        y[7] = w[21];
        thr = m3(m3(y[0], y[1], y[2]), m3(y[3], y[4], y[5]), fmaxf(y[6], y[7]));
    }

    // ---- mask + rpb + softmax (slot c holds true m = 16*(c&3)+(c>>2)) ----
    const int basen = i1 * 15 + j1;
    float mxp[8];
    #pragma unroll
    for (int c = 0; c < 64; ++c) {
        const int m = 16 * (c & 3) + (c >> 2);
        const int i2 = m >> 3, j2 = m & 7;
        float vv = ((s[c] >= thr) ? s[c] : -100.0f)
                 + rpb[basen + (7 - i2) * 15 + (7 - j2)];
        s[c] = vv;
        if (c < 8) mxp[c] = vv; else mxp[c & 7] = fmaxf(mxp[c & 7], vv);
    }
    const float mx = m3(m3(mxp[0], mxp[1], mxp[2]), m3(mxp[3], mxp[4], mxp[5]),
                        fmaxf(mxp[6], mxp[7]));
    float sum = 0.f;
    #pragma unroll
    for (int c = 0; c < 64; ++c) { float e = __expf(s[c] - mx); s[c] = e; sum += e; }
    const float inv = 1.0f / sum;
    #pragma unroll
    for (int c = 0; c < 64; ++c) s[c] *= inv;

    // ---- PV via MFMA, P staged in two 32-row halves (R overlay) ----
    bf16x8 vb[2][2];
    #pragma unroll
    for (int kh2 = 0; kh2 < 2; ++kh2)
        #pragma unroll
        for (int j2 = 0; j2 < 2; ++j2)
            vb[kh2][j2] = *(const bf16x8*)&Vt[(16 * j2 + m16) * 72 + kh2 * 32 + quad * 8];

    f32x4 o[4][2];
    #pragma unroll
    for (int i = 0; i < 4; ++i)
        #pragma unroll
        for (int j2 = 0; j2 < 2; ++j2)
            o[i][j2] = (f32x4)(0.0f);
    #pragma unroll
    for (int hf = 0; hf < 2; ++hf) {
        if ((n >> 5) == hf) {
            #pragma unroll
            for (int g = 0; g < 8; ++g) {
                uint4 w;
                w.x = pk2(s[8*g+0], s[8*g+1]); w.y = pk2(s[8*g+2], s[8*g+3]);
                w.z = pk2(s[8*g+4], s[8*g+5]); w.w = pk2(s[8*g+6], s[8*g+7]);
                *(uint4*)&Ph[(n & 31) * 72 + 8 * g] = w;
            }
        }
        #pragma unroll
        for (int ih = 0; ih < 2; ++ih) {
            const int i = 2 * hf + ih;
            #pragma unroll
            for (int kh2 = 0; kh2 < 2; ++kh2) {
                bf16x8 pafr = *(const bf16x8*)&Ph[(16 * ih + m16) * 72 + kh2 * 32 + quad * 8];
                o[i][0] = __builtin_amdgcn_mfma_f32_16x16x32_bf16(pafr, vb[kh2][0], o[i][0], 0, 0, 0);
                o[i][1] = __builtin_amdgcn_mfma_f32_16x16x32_bf16(pafr, vb[kh2][1], o[i][1], 0, 0, 0);
            }
        }
    }
    __syncthreads();   // B3: all waves done with arenas -> AoT may overlay

    // ---- O -> shared AoT tile (bf16, token-major, stride 200) ----
    #pragma unroll
    for (int i = 0; i < 4; ++i) {
        #pragma unroll
        for (int r = 0; r < 4; ++r) {
            const int row = 16 * i + 4 * quad + r;
            AoT[row][h * 32 + m16]      = f2b(o[i][0][r]);
            AoT[row][h * 32 + 16 + m16] = f2b(o[i][1][r]);
        }
    }
    __syncthreads();   // B4

    // ---- residual prefetch: AFTER B4, low-pressure region; latency hidden
    //      under the proj GEMM. Lines are L2-warm. ----
    const int r8 = n >> 3, c4 = (n & 7) * 4;
    uint2 rv[4][2];
    #pragma unroll
    for (int i = 0; i < 4; ++i)
        #pragma unroll
        for (int q = 0; q < 2; ++q) {
            const int tok = 16 * i + 8 * q + r8;
            const int tt = wb + ((tok >> 3) << 6) + (tok & 7);
            rv[i][q] = *(const uint2*)(sc_h + (size_t)tt * 192 + h * 32 + c4);
        }

    // ---- proj: wave computes outs [h*32, h*32+32) of its window, K=192 ----
    f32x4 pacc[4][2];
    #pragma unroll
    for (int i = 0; i < 4; ++i)
        #pragma unroll
        for (int j = 0; j < 2; ++j)
            pacc[i][j] = (f32x4)(0.0f);
    const ushort_t* Wb = wpf + (size_t)(h * 2) * 24 * 128 + m16 * 8;
    for (int ks = 0; ks < 192; ks += 32) {
        bf16x8 af[4], wv[2];
        #pragma unroll
        for (int i = 0; i < 4; ++i)
            af[i] = *(const bf16x8*)&AoT[16 * i + m16][quad * 8 + ks];
        #pragma unroll
        for (int j = 0; j < 2; ++j)
            wv[j] = *(const bf16x8*)(Wb + (size_t)(j * 24 + (ks >> 3) + quad) * 128);
        #pragma unroll
        for (int i = 0; i < 4; ++i)
            #pragma unroll
            for (int j = 0; j < 2; ++j)
                pacc[i][j] = __builtin_amdgcn_mfma_f32_16x16x32_bf16(wv[j], af[i], pacc[i][j], 0, 0, 0);
    }

    // ---- per i-group: stage C^T (+bias) into Cwi[16][36]; store x2 with
    //      full 128-B-granule coverage per instruction. ----
    const float4 bj0 = *(const float4*)&proj_b[h * 32 + quad * 4];
    const float4 bj1 = *(const float4*)&proj_b[h * 32 + 16 + quad * 4];
    #pragma unroll
    for (int i = 0; i < 4; ++i) {
        f32x4 v0 = pacc[i][0], v1 = pacc[i][1];
        v0[0] += bj0.x; v0[1] += bj0.y; v0[2] += bj0.z; v0[3] += bj0.w;
        v1[0] += bj1.x; v1[1] += bj1.y; v1[2] += bj1.z; v1[3] += bj1.w;
        *(f32x4*)&Cwi[m16 * 36 + quad * 4]      = v0;
        *(f32x4*)&Cwi[m16 * 36 + 16 + quad * 4] = v1;
        #pragma unroll
        for (int q = 0; q < 2; ++q) {
            const int row = 8 * q + r8;
            const int tok = 16 * i + row;
            const int tt = wb + ((tok >> 3) << 6) + (tok & 7);
            float4 vv = *(const float4*)&Cwi[row * 36 + c4];
            const uint2 rr = rv[i][q];
            vv.x += b2f((ushort_t)(rr.x & 0xffffu));
            vv.y += b2f((ushort_t)(rr.x >> 16));
            vv.z += b2f((ushort_t)(rr.y & 0xffffu));
            vv.w += b2f((ushort_t)(rr.y >> 16));
            *(float4*)&x2[(size_t)tt * DIM + h * 32 + c4] = vv;
        }
    }
}

// ---------------------------------------------------------------------------
// FUSED MLP v2 (kept): 128 tokens/block, 12 waves, grid 256.
// Native bf16 converts inherited via f2b/pk2.
__global__ __launch_bounds__(768, 3) void mlp_fused(
    const float* __restrict__ x2, const ushort_t* __restrict__ w1f,
    const ushort_t* __restrict__ w2f, const float* __restrict__ fc1_b,
    const float* __restrict__ fc2_b, const float* __restrict__ g2,
    const float* __restrict__ b2, float* __restrict__ outp)
{
    __shared__ __align__(16) char smem[103936];
    ushort_t (*h_h)[200] = (ushort_t(*)[200])smem;             // [128][200]
    ushort_t (*a1c)[200] = (ushort_t(*)[200])(smem + 51200);   // [128][200]
    float* gs = (float*)(smem + 102400);
    float* bs = gs + 192;

    const int tid  = threadIdx.x;
    const int wave = tid >> 6, lane = tid & 63;
    const int m16 = lane & 15, quad = lane >> 4;
    const int half = wave / 6, ow = wave - 6 * half;   // token-half, out-group
    const int t0  = blockIdx.x * 128;
    const int b   = t0 >> 12;
    const int hw0 = t0 & 4095;

    if (tid < 192) { gs[tid] = g2[tid]; bs[tid] = b2[tid]; }
    __syncthreads();
    if (tid < 512) {
        const int tok = tid >> 2, p = tid & 3;
        const float* rp = x2 + (size_t)(t0 + tok) * DIM + p * 48;
        float xv[48];
        #pragma unroll
        for (int c4 = 0; c4 < 12; ++c4)
            *(float4*)&xv[c4 * 4] = *(const float4*)(rp + c4 * 4);
        float sum = 0.f;
        #pragma unroll
        for (int c = 0; c < 48; ++c) sum += xv[c];
        sum += __shfl_xor(sum, 1);
        sum += __shfl_xor(sum, 2);
        const float m = sum * (1.0f / 192.0f);
        float ss = 0.f;
        #pragma unroll
        for (int c = 0; c < 48; ++c) { float d = xv[c] - m; ss += d * d; }
        ss += __shfl_xor(ss, 1);
        ss += __shfl_xor(ss, 2);
        const float rs = 1.0f / sqrtf(ss * (1.0f / 192.0f) + 1e-5f);
        ushort_t* hp = &h_h[tok][p * 48];
        #pragma unroll
        for (int c2 = 0; c2 < 24; ++c2) {
            float v0 = (xv[2*c2]   - m) * rs * gs[p * 48 + 2*c2]   + bs[p * 48 + 2*c2];
            float v1 = (xv[2*c2+1] - m) * rs * gs[p * 48 + 2*c2+1] + bs[p * 48 + 2*c2+1];
            *(unsigned*)(hp + 2 * c2) = pk2(v0, v1);
        }
    }
    __syncthreads();

    f32x4 acc2[4][2];
    #pragma unroll
    for (int i = 0; i < 4; ++i)
        #pragma unroll
        for (int j = 0; j < 2; ++j)
            acc2[i][j] = (f32x4)(0.0f);

    for (int c = 0; c < 4; ++c) {                 // 4 chunks of 192 fc1-outs
        f32x4 acc1[4][2];
        #pragma unroll
        for (int i = 0; i < 4; ++i)
            #pragma unroll
            for (int j = 0; j < 2; ++j)
                acc1[i][j] = (f32x4)(0.0f);
        const ushort_t* Wb1 = w1f + (size_t)(c * 12 + ow * 2) * 3072 + m16 * 8;
        for (int ks = 0; ks < 192; ks += 32) {
            bf16x8 af[4], wv[2];
            #pragma unroll
            for (int i = 0; i < 4; ++i)
                af[i] = *(const bf16x8*)&h_h[half * 64 + 16 * i + m16][quad * 8 + ks];
            #pragma unroll
            for (int j = 0; j < 2; ++j)
                wv[j] = *(const bf16x8*)(Wb1 + (size_t)(j * 24 + (ks >> 3) + quad) * 128);
            #pragma unroll
            for (int i = 0; i < 4; ++i)
                #pragma unroll
                for (int j = 0; j < 2; ++j)
                    acc1[i][j] = __builtin_amdgcn_mfma_f32_16x16x32_bf16(wv[j], af[i], acc1[i][j], 0, 0, 0);
        }
        #pragma unroll
        for (int j = 0; j < 2; ++j) {
            const int o = c * 192 + ow * 32 + 16 * j + quad * 4;
            const float4 bv = *(const float4*)&fc1_b[o];
            #pragma unroll
            for (int i = 0; i < 4; ++i) {
                f32x4 v = acc1[i][j];
                v[0] += bv.x; v[1] += bv.y; v[2] += bv.z; v[3] += bv.w;
                #pragma unroll
                for (int r = 0; r < 4; ++r) {
                    float xg = v[r];
                    float e1 = __expf(xg * (1.5957691f + 0.0713548f * xg * xg)) + 1.0f;
                    v[r] = xg - xg * __builtin_amdgcn_rcpf(e1);
                }
                uint2 pkd;
                pkd.x = pk2(v[0], v[1]); pkd.y = pk2(v[2], v[3]);
                *(uint2*)&a1c[half * 64 + 16 * i + m16][ow * 32 + 16 * j + quad * 4] = pkd;
            }
        }
        __syncthreads();
        const ushort_t* Wb2 = w2f + (size_t)(ow * 2) * 12288 + m16 * 8;
        for (int ks = 0; ks < 192; ks += 32) {
            bf16x8 af2[4], wv2[2];
            #pragma unroll
            for (int i = 0; i < 4; ++i)
                af2[i] = *(const bf16x8*)&a1c[half * 64 + 16 * i + m16][quad * 8 + ks];
            #pragma unroll
            for (int j = 0; j < 2; ++j)
                wv2[j] = *(const bf16x8*)(Wb2 + (size_t)(j * 96 + c * 24 + (ks >> 3) + quad) * 128);
            #pragma unroll
            for (int i = 0; i < 4; ++i)
                #pragma unroll
                for (int j = 0; j < 2; ++j)
                    acc2[i][j] = __builtin_amdgcn_mfma_f32_16x16x32_bf16(wv2[j], af2[i], acc2[i][j], 0, 0, 0);
        }
        __syncthreads();
    }

    // ---- epilogue: stage [32 tok][32 outs] per pass, write NCHW with
    //      full 128-B-granule runs (64-token-consecutive per channel). ----
    float* Cw = (float*)(smem + wave * 4608);      // [32][36] f32, overlay
    float4 b2j[2];
    #pragma unroll
    for (int j = 0; j < 2; ++j)
        b2j[j] = *(const float4*)&fc2_b[ow * 32 + 16 * j + quad * 4];
    #pragma unroll
    for (int p = 0; p < 2; ++p) {
        #pragma unroll
        for (int ih = 0; ih < 2; ++ih) {
            const int i = 2 * p + ih;
            #pragma unroll
            for (int j = 0; j < 2; ++j) {
                f32x4 v = acc2[i][j];
                v[0] += b2j[j].x; v[1] += b2j[j].y; v[2] += b2j[j].z; v[3] += b2j[j].w;
                *(f32x4*)&Cw[(ih * 16 + m16) * 36 + 16 * j + quad * 4] = v;
            }
        }
        #pragma unroll
        for (int q = 0; q < 4; ++q) {
            const int idx = q * 64 + lane;
            const int cc = idx >> 3, t4 = (idx & 7) * 4;
            const int o  = ow * 32 + cc;
            const int tb = t0 + half * 64 + p * 32 + t4;
            float4 vv;
            vv.x = Cw[(t4 + 0) * 36 + cc] + x2[(size_t)(tb + 0) * DIM + o];
            vv.y = Cw[(t4 + 1) * 36 + cc] + x2[(size_t)(tb + 1) * DIM + o];
            vv.z = Cw[(t4 + 2) * 36 + cc] + x2[(size_t)(tb + 2) * DIM + o];
            vv.w = Cw[(t4 + 3) * 36 + cc] + x2[(size_t)(tb + 3) * DIM + o];
            *(float4*)&outp[(size_t)b * (DIM * 4096) + (size_t)o * 4096
                            + hw0 + half * 64 + p * 32 + t4] = vv;
        }
    }
}

// ---------------------------------------------------------------------------
extern "C" void kernel_launch(void* const* d_in, const int* in_sizes, int n_in,
                              void* d_out, int out_size, void* d_ws, size_t ws_size,
                              hipStream_t stream)
{
    const float* x        = (const float*)d_in[0];
    const float* norm1_g  = (const float*)d_in[1];
    const float* norm1_b  = (const float*)d_in[2];
    const float* qkv_w    = (const float*)d_in[3];
    const float* qkv_b    = (const float*)d_in[4];
    const float* proj_w   = (const float*)d_in[5];
    const float* proj_b   = (const float*)d_in[6];
    const float* rpbt     = (const float*)d_in[7];
    const float* temp     = (const float*)d_in[8];
    const float* norm2_g  = (const float*)d_in[9];
    const float* norm2_b  = (const float*)d_in[10];
    const float* fc1_w    = (const float*)d_in[11];
    const float* fc1_b    = (const float*)d_in[12];
    const float* fc2_w    = (const float*)d_in[13];
    const float* fc2_b    = (const float*)d_in[14];
    float* out = (float*)d_out;

    // ws layout (bytes):
    //   [0,        12582912)  shortcut bf16 (LN1 out)
    //   [12582912, 37748736)  x2 f32
    //   [125829120,...)       weights bf16 (fragment order; qkv Q/K permuted)
    char* wsb = (char*)d_ws;
    ushort_t* shortcut_h = (ushort_t*)wsb;
    float*    x2         = (float*)(wsb + 12582912);
    ushort_t* wq  = (ushort_t*)(wsb + 125829120);      // 576x192 = 110592
    ushort_t* wp  = wq + 110592;                       // 192x192 = 36864
    ushort_t* w1  = wp + 36864;                        // 768x192 = 147456
    ushort_t* w2  = w1 + 147456;                       // 192x768 = 147456

    // 0+1. merged weight conversion (432 blocks) + LN1 transpose (512 blocks)
    hipLaunchKernelGGL(prep_kernel, dim3(432 + TTOT / 64), dim3(256), 0, stream,
                       qkv_w, proj_w, fc1_w, fc2_w, wq, wp, w1, w2,
                       x, norm1_g, norm1_b, shortcut_h);
    // 2. fused qkv + attention + proj + residual -> x2 (2 windows/block)
    hipLaunchKernelGGL(attn_fused, dim3(NWIN / 2), dim3(768), 0, stream,
                       shortcut_h, wq, qkv_b, rpbt, temp, wp, proj_b, x2);
    // 3. fused LN2 + fc1 + GELU + fc2 + residual + NCHW transpose
    hipLaunchKernelGGL(mlp_fused, dim3(TTOT / 128), dim3(768), 0, stream,
                       x2, w1, w2, fc1_b, fc2_b, norm2_g, norm2_b, out);
}

// Round 8
// 187.669 us; speedup vs baseline: 1.2023x; 1.0089x over previous
//
#include <hip/hip_runtime.h>
#include <hip/hip_bf16.h>
#include <math.h>

// Problem constants
#define DIM     192
#define HEADS   6
#define HEAD_DIM 32
#define NTOK    64          // tokens per window
#define IN_CC   16
#define TTOT    32768       // 8 * 64 * 64 tokens
#define NWIN    512

using bf16x8 = __attribute__((ext_vector_type(8))) short;
using f32x4  = __attribute__((ext_vector_type(4))) float;
typedef unsigned short ushort_t;

// ---------------------------------------------------------------------------
// TWO bf16 convert families (same RNE result, different codegen):
//  - f2bt/pk2t: bit-twiddle, short live ranges.  Used in attn_fused, which
//    sits at the 168-reg cap (min-waves=3): round-7 showed the native-cast
//    path (compiler pairs v_cvt_pk_bf16_f32, keeping both f32 sources live)
//    re-triggered ~6 MB of scratch spill there.
//  - f2b/pk2: native casts.  Used in prep/mlp (far from the reg cliff),
//    where fewer VALU ops won round-7's −4 us on the non-attn share.
__device__ __forceinline__ ushort_t f2bt(float f) {
    unsigned u = __float_as_uint(f);
    u += 0x7fffu + ((u >> 16) & 1u);
    return (ushort_t)(u >> 16);
}
__device__ __forceinline__ unsigned pk2t(float a, float b) {
    return (unsigned)f2bt(a) | ((unsigned)f2bt(b) << 16);
}
__device__ __forceinline__ ushort_t f2b(float f) {
    __bf16 h = (__bf16)f;
    ushort_t u;
    __builtin_memcpy(&u, &h, 2);
    return u;
}
__device__ __forceinline__ unsigned pk2(float a, float b) {
    return (unsigned)f2b(a) | ((unsigned)f2b(b) << 16);
}
__device__ __forceinline__ float b2f(ushort_t u) {
    return __uint_as_float(((unsigned)u) << 16);
}
__device__ __forceinline__ float m3(float a, float b, float c) {
    return fmaxf(fmaxf(a, b), c);     // clang fuses to v_max3_f32
}

// ---------------------------------------------------------------------------
// PREP kernel: weight fp32->bf16 fragment-order conversion (432 blocks)
// MERGED with LN1+transpose (512 blocks).
// cvt part: W (NxK row-major) -> W' where element (o,k) lives at
//   frag = (o/16)*(K/8) + (k/8);  W'[frag*128 + (o%16)*8 + (k%8)]
// qkv weight ONLY: Q and K parts (rows [0,384)) get a within-head output-row
// permutation so the qkv GEMM's C-fragment IS the QK^T MFMA A/B fragment
// (slot s=16j+4q+r holds natural channel c=8q+4j+r). QK^T is invariant under
// a common channel permutation of q and k.
__global__ __launch_bounds__(256) void prep_kernel(
    const float* __restrict__ s0, const float* __restrict__ s1,
    const float* __restrict__ s2, const float* __restrict__ s3,
    ushort_t* __restrict__ d0, ushort_t* __restrict__ d1,
    ushort_t* __restrict__ d2, ushort_t* __restrict__ d3,
    const float* __restrict__ x, const float* __restrict__ g,
    const float* __restrict__ bb, ushort_t* __restrict__ outh)
{
    __shared__ float xs[64][193];
    __shared__ float mu_s[64], rs_s[64];
    __shared__ float gs[192], bs[192];
    const int bid = blockIdx.x;
    const int tid = threadIdx.x;

    if (bid < 432) {
        // ---------------- weight conversion ----------------
        const float* src; ushort_t* dst; int off, K; bool perm = false;
        if (bid < 108)      { src = s0; dst = d0; off = bid;       K = 192; perm = true; }
        else if (bid < 144) { src = s1; dst = d1; off = bid - 108; K = 192; }
        else if (bid < 288) { src = s2; dst = d2; off = bid - 144; K = 192; }
        else                { src = s3; dst = d3; off = bid - 288; K = 768; }
        const int K8 = K >> 3;
        const int d  = (off * 256 + tid) * 4;
        const int frag = d >> 7, win = d & 127;
        const int m16w = win >> 3, k7 = win & 7;
        const int oblk = frag / K8, kblk = frag - oblk * K8;
        const int o = oblk * 16 + m16w, k = kblk * 8 + k7;
        int so = o;
        if (perm && o < 384) {
            const int s = o & 31;                       // slot within head block
            const int c = (((s >> 2) & 3) << 3) | (((s >> 4) & 1) << 2) | (s & 3);
            so = (o & ~31) | c;                         // natural channel row
        }
        float4 v = *(const float4*)(src + (size_t)so * K + k);
        ushort4 ov;
        ov.x = f2b(v.x); ov.y = f2b(v.y); ov.z = f2b(v.z); ov.w = f2b(v.w);
        *(ushort4*)(dst + d) = ov;
        return;
    }

    // ---------------- LN1 + (B,C,H,W)->(T,C) transpose, bf16 out ----------------
    const int t0  = (bid - 432) * 64;
    const int b   = t0 >> 12;
    const int hw0 = t0 & 4095;
    if (tid < 192) { gs[tid] = g[tid]; bs[tid] = bb[tid]; }
    const int tok = tid & 63, qq = tid >> 6;
    const float* xb = x + (size_t)b * (DIM * 4096) + hw0 + tok;
    #pragma unroll
    for (int it = 0; it < 48; ++it) {
        int c = it * 4 + qq;
        xs[tok][c] = xb[(size_t)c * 4096];
    }
    __syncthreads();
    const int tok2 = tid >> 2, p = tid & 3;
    float sum = 0.f;
    #pragma unroll
    for (int c = 0; c < 48; ++c) sum += xs[tok2][p * 48 + c];
    sum += __shfl_xor(sum, 1);
    sum += __shfl_xor(sum, 2);
    const float m = sum * (1.0f / 192.0f);
    float ss = 0.f;
    #pragma unroll
    for (int c = 0; c < 48; ++c) { float d = xs[tok2][p * 48 + c] - m; ss += d * d; }
    ss += __shfl_xor(ss, 1);
    ss += __shfl_xor(ss, 2);
    if (p == 0) {
        mu_s[tok2] = m;
        rs_s[tok2] = 1.0f / sqrtf(ss * (1.0f / 192.0f) + 1e-5f);
    }
    __syncthreads();
    ushort_t* obh = outh + (size_t)t0 * DIM;
    #pragma unroll
    for (int it = 0; it < 48; ++it) {
        int idx = it * 256 + tid;
        int tk = idx / 192, c = idx % 192;
        obh[idx] = f2b((xs[tk][c] - mu_s[tk]) * rs_s[tk] * gs[c] + bs[c]);
    }
}

// ---------------------------------------------------------------------------
// MEGA-FUSED attention — round-6 version restored verbatim (48.8 us,
// WRITE 31.5 MB): bit-twiddle converts (f2bt/pk2t), scalar Vt writes.
__global__ __launch_bounds__(768, 3) void attn_fused(
    const ushort_t* __restrict__ sc_h, const ushort_t* __restrict__ wqf,
    const float* __restrict__ qkv_b, const float* __restrict__ rpb_table,
    const float* __restrict__ temp, const ushort_t* __restrict__ wpf,
    const float* __restrict__ proj_b, float* __restrict__ x2)
{
    __shared__ __align__(16) char smem[127680];
    const int tid  = threadIdx.x;
    const int wave = tid >> 6, n = tid & 63;

    char* Rb = smem + wave * 4608;
    float*    Ssq = (float*)Rb;                  // [16][68] f32 transpose qtr
    ushort_t* Ph  = (ushort_t*)Rb;               // [32][72] bf16 P half (ovl)
    char* Ab = smem + 55296 + wave * 5120;
    ushort_t* Vt  = (ushort_t*)Ab;               // [32][72] V^T slot-permuted
    float*    ksb = (float*)(Ab + 4608);         // [64] slot-ordered 1/||k||
    float*    qnb = (float*)(Ab + 4864);         // [64] ssq of q per token
    float*    rpb = (float*)(smem + 116736) + wave * 228;

    const int wloc = (wave >= 6) ? 1 : 0;        // window within block
    const int h    = wave - 6 * wloc;            // head
    ushort_t* tile = (ushort_t*)(smem + wloc * 25600);       // [64][200] bf16
    ushort_t (*AoT)[200] = (ushort_t(*)[200])(smem + wloc * 25600);
    float* Cwi = (float*)(smem + 55296 + wave * 2304);       // [16][36] f32

    const int win = blockIdx.x * 2 + wloc;
    const int b   = win >> 6;
    const int wh  = (win >> 3) & 7, ww = win & 7;
    const int wb  = b * 4096 + wh * 512 + ww * 8;
    const int i1  = n >> 3, j1 = n & 7;
    const int m16 = n & 15, quad = n >> 4;

    for (int r = n; r < 225; r += 64) rpb[r] = rpb_table[r * 6 + h];

    // ---- phase 0: stage this window's shortcut tile into LDS (once) ----
    #pragma unroll
    for (int l = 0; l < 4; ++l) {
        const int g = h * 256 + l * 64 + n;
        const int t = (g * 2731) >> 16;          // g / 24
        const int r = g - t * 24;
        const int tt = wb + ((t >> 3) << 6) + (t & 7);
        uint4 v = *(const uint4*)(sc_h + (size_t)tt * 192 + r * 8);
        *(uint4*)(tile + t * 200 + r * 8) = v;
    }
    __syncthreads();                              // B1: tile ready

    // ---- phase 1a: q & k GEMMs sharing af fragments (all LDS reads) ----
    const ushort_t* tb = tile + m16 * 200 + quad * 8;
    f32x4 pq[4][2], pk[4][2];
    #pragma unroll
    for (int i = 0; i < 4; ++i)
        #pragma unroll
        for (int j = 0; j < 2; ++j) { pq[i][j] = (f32x4)(0.0f); pk[i][j] = (f32x4)(0.0f); }
    {
        const ushort_t* WbQ = wqf + (size_t)(2 * h) * 3072 + m16 * 8;
        const ushort_t* WbK = wqf + (size_t)(12 + 2 * h) * 3072 + m16 * 8;
        for (int ks = 0; ks < 192; ks += 32) {
            bf16x8 af[4], wq2[2], wk2[2];
            #pragma unroll
            for (int i = 0; i < 4; ++i)
                af[i] = *(const bf16x8*)(tb + i * 3200 + ks);
            #pragma unroll
            for (int j = 0; j < 2; ++j) {
                wq2[j] = *(const bf16x8*)(WbQ + (size_t)(j * 24 + (ks >> 3) + quad) * 128);
                wk2[j] = *(const bf16x8*)(WbK + (size_t)(j * 24 + (ks >> 3) + quad) * 128);
            }
            #pragma unroll
            for (int i = 0; i < 4; ++i)
                #pragma unroll
                for (int j = 0; j < 2; ++j) {
                    pq[i][j] = __builtin_amdgcn_mfma_f32_16x16x32_bf16(wq2[j], af[i], pq[i][j], 0, 0, 0);
                    pk[i][j] = __builtin_amdgcn_mfma_f32_16x16x32_bf16(wk2[j], af[i], pk[i][j], 0, 0, 0);
                }
        }
    }
    // q/k epilogue: bias, ssq, pack to QK^T fragments (permuted slots)
    bf16x8 qA[4], kB[4];
    #pragma unroll
    for (int part = 0; part < 2; ++part) {
        const int o0 = part * 192 + h * 32;
        const float4 bv0 = *(const float4*)&qkv_b[o0 + 8 * quad];
        const float4 bv1 = *(const float4*)&qkv_b[o0 + 8 * quad + 4];
        float ssq[4];
        #pragma unroll
        for (int i = 0; i < 4; ++i) {
            f32x4 v0 = part ? pk[i][0] : pq[i][0];
            f32x4 v1 = part ? pk[i][1] : pq[i][1];
            v0[0] += bv0.x; v0[1] += bv0.y; v0[2] += bv0.z; v0[3] += bv0.w;
            v1[0] += bv1.x; v1[1] += bv1.y; v1[2] += bv1.z; v1[3] += bv1.w;
            float sq = 0.f;
            #pragma unroll
            for (int r = 0; r < 4; ++r) sq += v0[r] * v0[r] + v1[r] * v1[r];
            ssq[i] = sq;
            bf16x8 fr;
            fr[0] = (short)f2bt(v0[0]); fr[1] = (short)f2bt(v0[1]);
            fr[2] = (short)f2bt(v0[2]); fr[3] = (short)f2bt(v0[3]);
            fr[4] = (short)f2bt(v1[0]); fr[5] = (short)f2bt(v1[1]);
            fr[6] = (short)f2bt(v1[2]); fr[7] = (short)f2bt(v1[3]);
            if (part == 0) qA[i] = fr; else kB[i] = fr;
        }
        #pragma unroll
        for (int i = 0; i < 4; ++i) {
            ssq[i] += __shfl_xor(ssq[i], 16);
            ssq[i] += __shfl_xor(ssq[i], 32);
        }
        if (quad == 0) {
            #pragma unroll
            for (int i = 0; i < 4; ++i) {
                if (part == 0) qnb[16 * i + m16] = ssq[i];
                else           ksb[4 * m16 + i]  = 1.0f / fmaxf(sqrtf(ssq[i]), 1e-12f);
            }
        }
    }

    // ---- phase 2: QK^T, register-to-register (V GEMM fills the shadow) ----
    f32x4 acc[4][4];
    #pragma unroll
    for (int i = 0; i < 4; ++i)
        #pragma unroll
        for (int j = 0; j < 4; ++j)
            acc[i][j] = __builtin_amdgcn_mfma_f32_16x16x32_bf16(qA[i], kB[j], (f32x4)(0.0f), 0, 0, 0);

    // ---- phase 1b: v GEMM (af re-read from LDS) ----
    {
        f32x4 pv[4][2];
        #pragma unroll
        for (int i = 0; i < 4; ++i)
            #pragma unroll
            for (int j = 0; j < 2; ++j) pv[i][j] = (f32x4)(0.0f);
        const ushort_t* WbV = wqf + (size_t)(24 + 2 * h) * 3072 + m16 * 8;
        for (int ks = 0; ks < 192; ks += 32) {
            bf16x8 af[4], wv2[2];
            #pragma unroll
            for (int i = 0; i < 4; ++i)
                af[i] = *(const bf16x8*)(tb + i * 3200 + ks);
            #pragma unroll
            for (int j = 0; j < 2; ++j)
                wv2[j] = *(const bf16x8*)(WbV + (size_t)(j * 24 + (ks >> 3) + quad) * 128);
            #pragma unroll
            for (int i = 0; i < 4; ++i)
                #pragma unroll
                for (int j = 0; j < 2; ++j)
                    pv[i][j] = __builtin_amdgcn_mfma_f32_16x16x32_bf16(wv2[j], af[i], pv[i][j], 0, 0, 0);
        }
        const int o0 = 384 + h * 32;
        const float4 bv0 = *(const float4*)&qkv_b[o0 + quad * 4];
        const float4 bv1 = *(const float4*)&qkv_b[o0 + 16 + quad * 4];
        #pragma unroll
        for (int i = 0; i < 4; ++i) {
            f32x4 v0 = pv[i][0], v1 = pv[i][1];
            v0[0] += bv0.x; v0[1] += bv0.y; v0[2] += bv0.z; v0[3] += bv0.w;
            v1[0] += bv1.x; v1[1] += bv1.y; v1[2] += bv1.z; v1[3] += bv1.w;
            #pragma unroll
            for (int r = 0; r < 4; ++r) {
                Vt[(quad * 4 + r) * 72 + 4 * m16 + i]      = f2bt(v0[r]);
                Vt[(16 + quad * 4 + r) * 72 + 4 * m16 + i] = f2bt(v1[r]);
            }
        }
    }

    __syncthreads();                              // B2: tiles dead, R usable

    // ---- transpose S via 16-row quarter buffer (wave-local) ----
    float s[64];
    #pragma unroll
    for (int i = 0; i < 4; ++i) {
        #pragma unroll
        for (int r = 0; r < 4; ++r) {
            f32x4 vv = { acc[i][0][r], acc[i][1][r], acc[i][2][r], acc[i][3][r] };
            *(f32x4*)&Ssq[(4 * quad + r) * 68 + 4 * m16] = vv;
        }
        if ((n >> 4) == i) {
            #pragma unroll
            for (int c = 0; c < 16; ++c)
                *(float4*)&s[4 * c] = *(const float4*)&Ssq[(n & 15) * 68 + 4 * c];
        }
    }

    // ---- cosine scales (positive; preserve top-k ordering) ----
    const float qs = temp[h] / fmaxf(sqrtf(qnb[n]), 1e-12f);
    #pragma unroll
    for (int c = 0; c < 16; ++c) {
        float4 kv = *(const float4*)&ksb[4 * c];
        s[4*c+0] *= qs * kv.x; s[4*c+1] *= qs * kv.y;
        s[4*c+2] *= qs * kv.z; s[4*c+3] *= qs * kv.w;
    }

    // ---- top-16 threshold via masked v_max3 trees (bit-identical) ----
    float thr = 1e30f;
    for (int it = 0; it < IN_CC; ++it) {
        #define MK(c) ((s[(c)] < thr) ? s[(c)] : -1e30f)
        float w[22];
        #pragma unroll
        for (int g = 0; g < 21; ++g) w[g] = m3(MK(3*g), MK(3*g+1), MK(3*g+2));
        w[21] = MK(63);
        #undef MK
        float y[8];
        #pragma unroll
        for (int g = 0; g < 7; ++g) y[g] = m3(w[3*g], w[3*g+1], w[3*g+2]);
        y[7] = w[21];
        thr = m3(m3(y[0], y[1], y[2]), m3(y[3], y[4], y[5]), fmaxf(y[6], y[7]));
    }

    // ---- mask + rpb + softmax (slot c holds true m = 16*(c&3)+(c>>2)) ----
    const int basen = i1 * 15 + j1;
    float mxp[8];
    #pragma unroll
    for (int c = 0; c < 64; ++c) {
        const int m = 16 * (c & 3) + (c >> 2);
        const int i2 = m >> 3, j2 = m & 7;
        float vv = ((s[c] >= thr) ? s[c] : -100.0f)
                 + rpb[basen + (7 - i2) * 15 + (7 - j2)];
        s[c] = vv;
        if (c < 8) mxp[c] = vv; else mxp[c & 7] = fmaxf(mxp[c & 7], vv);
    }
    const float mx = m3(m3(mxp[0], mxp[1], mxp[2]), m3(mxp[3], mxp[4], mxp[5]),
                        fmaxf(mxp[6], mxp[7]));
    float sum = 0.f;
    #pragma unroll
    for (int c = 0; c < 64; ++c) { float e = __expf(s[c] - mx); s[c] = e; sum += e; }
    const float inv = 1.0f / sum;
    #pragma unroll
    for (int c = 0; c < 64; ++c) s[c] *= inv;

    // ---- PV via MFMA, P staged in two 32-row halves (R overlay) ----
    bf16x8 vb[2][2];
    #pragma unroll
    for (int kh2 = 0; kh2 < 2; ++kh2)
        #pragma unroll
        for (int j2 = 0; j2 < 2; ++j2)
            vb[kh2][j2] = *(const bf16x8*)&Vt[(16 * j2 + m16) * 72 + kh2 * 32 + quad * 8];

    f32x4 o[4][2];
    #pragma unroll
    for (int i = 0; i < 4; ++i)
        #pragma unroll
        for (int j2 = 0; j2 < 2; ++j2)
            o[i][j2] = (f32x4)(0.0f);
    #pragma unroll
    for (int hf = 0; hf < 2; ++hf) {
        if ((n >> 5) == hf) {
            #pragma unroll
            for (int g = 0; g < 8; ++g) {
                uint4 w;
                w.x = pk2t(s[8*g+0], s[8*g+1]); w.y = pk2t(s[8*g+2], s[8*g+3]);
                w.z = pk2t(s[8*g+4], s[8*g+5]); w.w = pk2t(s[8*g+6], s[8*g+7]);
                *(uint4*)&Ph[(n & 31) * 72 + 8 * g] = w;
            }
        }
        #pragma unroll
        for (int ih = 0; ih < 2; ++ih) {
            const int i = 2 * hf + ih;
            #pragma unroll
            for (int kh2 = 0; kh2 < 2; ++kh2) {
                bf16x8 pafr = *(const bf16x8*)&Ph[(16 * ih + m16) * 72 + kh2 * 32 + quad * 8];
                o[i][0] = __builtin_amdgcn_mfma_f32_16x16x32_bf16(pafr, vb[kh2][0], o[i][0], 0, 0, 0);
                o[i][1] = __builtin_amdgcn_mfma_f32_16x16x32_bf16(pafr, vb[kh2][1], o[i][1], 0, 0, 0);
            }
        }
    }
    __syncthreads();   // B3: all waves done with arenas -> AoT may overlay

    // ---- O -> shared AoT tile (bf16, token-major, stride 200) ----
    #pragma unroll
    for (int i = 0; i < 4; ++i) {
        #pragma unroll
        for (int r = 0; r < 4; ++r) {
            const int row = 16 * i + 4 * quad + r;
            AoT[row][h * 32 + m16]      = f2bt(o[i][0][r]);
            AoT[row][h * 32 + 16 + m16] = f2bt(o[i][1][r]);
        }
    }
    __syncthreads();   // B4

    // ---- residual prefetch: AFTER B4, low-pressure region; latency hidden
    //      under the proj GEMM. Lines are L2-warm. ----
    const int r8 = n >> 3, c4 = (n & 7) * 4;
    uint2 rv[4][2];
    #pragma unroll
    for (int i = 0; i < 4; ++i)
        #pragma unroll
        for (int q = 0; q < 2; ++q) {
            const int tok = 16 * i + 8 * q + r8;
            const int tt = wb + ((tok >> 3) << 6) + (tok & 7);
            rv[i][q] = *(const uint2*)(sc_h + (size_t)tt * 192 + h * 32 + c4);
        }

    // ---- proj: wave computes outs [h*32, h*32+32) of its window, K=192 ----
    f32x4 pacc[4][2];
    #pragma unroll
    for (int i = 0; i < 4; ++i)
        #pragma unroll
        for (int j = 0; j < 2; ++j)
            pacc[i][j] = (f32x4)(0.0f);
    const ushort_t* Wb = wpf + (size_t)(h * 2) * 24 * 128 + m16 * 8;
    for (int ks = 0; ks < 192; ks += 32) {
        bf16x8 af[4], wv[2];
        #pragma unroll
        for (int i = 0; i < 4; ++i)
            af[i] = *(const bf16x8*)&AoT[16 * i + m16][quad * 8 + ks];
        #pragma unroll
        for (int j = 0; j < 2; ++j)
            wv[j] = *(const bf16x8*)(Wb + (size_t)(j * 24 + (ks >> 3) + quad) * 128);
        #pragma unroll
        for (int i = 0; i < 4; ++i)
            #pragma unroll
            for (int j = 0; j < 2; ++j)
                pacc[i][j] = __builtin_amdgcn_mfma_f32_16x16x32_bf16(wv[j], af[i], pacc[i][j], 0, 0, 0);
    }

    // ---- per i-group: stage C^T (+bias) into Cwi[16][36]; store x2 with
    //      full 128-B-granule coverage per instruction. ----
    const float4 bj0 = *(const float4*)&proj_b[h * 32 + quad * 4];
    const float4 bj1 = *(const float4*)&proj_b[h * 32 + 16 + quad * 4];
    #pragma unroll
    for (int i = 0; i < 4; ++i) {
        f32x4 v0 = pacc[i][0], v1 = pacc[i][1];
        v0[0] += bj0.x; v0[1] += bj0.y; v0[2] += bj0.z; v0[3] += bj0.w;
        v1[0] += bj1.x; v1[1] += bj1.y; v1[2] += bj1.z; v1[3] += bj1.w;
        *(f32x4*)&Cwi[m16 * 36 + quad * 4]      = v0;
        *(f32x4*)&Cwi[m16 * 36 + 16 + quad * 4] = v1;
        #pragma unroll
        for (int q = 0; q < 2; ++q) {
            const int row = 8 * q + r8;
            const int tok = 16 * i + row;
            const int tt = wb + ((tok >> 3) << 6) + (tok & 7);
            float4 vv = *(const float4*)&Cwi[row * 36 + c4];
            const uint2 rr = rv[i][q];
            vv.x += b2f((ushort_t)(rr.x & 0xffffu));
            vv.y += b2f((ushort_t)(rr.x >> 16));
            vv.z += b2f((ushort_t)(rr.y & 0xffffu));
            vv.w += b2f((ushort_t)(rr.y >> 16));
            *(float4*)&x2[(size_t)tt * DIM + h * 32 + c4] = vv;
        }
    }
}

// ---------------------------------------------------------------------------
// FUSED MLP v2 (kept): 128 tokens/block, 12 waves, grid 256.
// Native bf16 converts (f2b/pk2) — mlp is far from the register cliff.
__global__ __launch_bounds__(768, 3) void mlp_fused(
    const float* __restrict__ x2, const ushort_t* __restrict__ w1f,
    const ushort_t* __restrict__ w2f, const float* __restrict__ fc1_b,
    const float* __restrict__ fc2_b, const float* __restrict__ g2,
    const float* __restrict__ b2, float* __restrict__ outp)
{
    __shared__ __align__(16) char smem[103936];
    ushort_t (*h_h)[200] = (ushort_t(*)[200])smem;             // [128][200]
    ushort_t (*a1c)[200] = (ushort_t(*)[200])(smem + 51200);   // [128][200]
    float* gs = (float*)(smem + 102400);
    float* bs = gs + 192;

    const int tid  = threadIdx.x;
    const int wave = tid >> 6, lane = tid & 63;
    const int m16 = lane & 15, quad = lane >> 4;
    const int half = wave / 6, ow = wave - 6 * half;   // token-half, out-group
    const int t0  = blockIdx.x * 128;
    const int b   = t0 >> 12;
    const int hw0 = t0 & 4095;

    if (tid < 192) { gs[tid] = g2[tid]; bs[tid] = b2[tid]; }
    __syncthreads();
    if (tid < 512) {
        const int tok = tid >> 2, p = tid & 3;
        const float* rp = x2 + (size_t)(t0 + tok) * DIM + p * 48;
        float xv[48];
        #pragma unroll
        for (int c4 = 0; c4 < 12; ++c4)
            *(float4*)&xv[c4 * 4] = *(const float4*)(rp + c4 * 4);
        float sum = 0.f;
        #pragma unroll
        for (int c = 0; c < 48; ++c) sum += xv[c];
        sum += __shfl_xor(sum, 1);
        sum += __shfl_xor(sum, 2);
        const float m = sum * (1.0f / 192.0f);
        float ss = 0.f;
        #pragma unroll
        for (int c = 0; c < 48; ++c) { float d = xv[c] - m; ss += d * d; }
        ss += __shfl_xor(ss, 1);
        ss += __shfl_xor(ss, 2);
        const float rs = 1.0f / sqrtf(ss * (1.0f / 192.0f) + 1e-5f);
        ushort_t* hp = &h_h[tok][p * 48];
        #pragma unroll
        for (int c2 = 0; c2 < 24; ++c2) {
            float v0 = (xv[2*c2]   - m) * rs * gs[p * 48 + 2*c2]   + bs[p * 48 + 2*c2];
            float v1 = (xv[2*c2+1] - m) * rs * gs[p * 48 + 2*c2+1] + bs[p * 48 + 2*c2+1];
            *(unsigned*)(hp + 2 * c2) = pk2(v0, v1);
        }
    }
    __syncthreads();

    f32x4 acc2[4][2];
    #pragma unroll
    for (int i = 0; i < 4; ++i)
        #pragma unroll
        for (int j = 0; j < 2; ++j)
            acc2[i][j] = (f32x4)(0.0f);

    for (int c = 0; c < 4; ++c) {                 // 4 chunks of 192 fc1-outs
        f32x4 acc1[4][2];
        #pragma unroll
        for (int i = 0; i < 4; ++i)
            #pragma unroll
            for (int j = 0; j < 2; ++j)
                acc1[i][j] = (f32x4)(0.0f);
        const ushort_t* Wb1 = w1f + (size_t)(c * 12 + ow * 2) * 3072 + m16 * 8;
        for (int ks = 0; ks < 192; ks += 32) {
            bf16x8 af[4], wv[2];
            #pragma unroll
            for (int i = 0; i < 4; ++i)
                af[i] = *(const bf16x8*)&h_h[half * 64 + 16 * i + m16][quad * 8 + ks];
            #pragma unroll
            for (int j = 0; j < 2; ++j)
                wv[j] = *(const bf16x8*)(Wb1 + (size_t)(j * 24 + (ks >> 3) + quad) * 128);
            #pragma unroll
            for (int i = 0; i < 4; ++i)
                #pragma unroll
                for (int j = 0; j < 2; ++j)
                    acc1[i][j] = __builtin_amdgcn_mfma_f32_16x16x32_bf16(wv[j], af[i], acc1[i][j], 0, 0, 0);
        }
        #pragma unroll
        for (int j = 0; j < 2; ++j) {
            const int o = c * 192 + ow * 32 + 16 * j + quad * 4;
            const float4 bv = *(const float4*)&fc1_b[o];
            #pragma unroll
            for (int i = 0; i < 4; ++i) {
                f32x4 v = acc1[i][j];
                v[0] += bv.x; v[1] += bv.y; v[2] += bv.z; v[3] += bv.w;
                #pragma unroll
                for (int r = 0; r < 4; ++r) {
                    float xg = v[r];
                    float e1 = __expf(xg * (1.5957691f + 0.0713548f * xg * xg)) + 1.0f;
                    v[r] = xg - xg * __builtin_amdgcn_rcpf(e1);
                }
                uint2 pkd;
                pkd.x = pk2(v[0], v[1]); pkd.y = pk2(v[2], v[3]);
                *(uint2*)&a1c[half * 64 + 16 * i + m16][ow * 32 + 16 * j + quad * 4] = pkd;
            }
        }
        __syncthreads();
        const ushort_t* Wb2 = w2f + (size_t)(ow * 2) * 12288 + m16 * 8;
        for (int ks = 0; ks < 192; ks += 32) {
            bf16x8 af2[4], wv2[2];
            #pragma unroll
            for (int i = 0; i < 4; ++i)
                af2[i] = *(const bf16x8*)&a1c[half * 64 + 16 * i + m16][quad * 8 + ks];
            #pragma unroll
            for (int j = 0; j < 2; ++j)
                wv2[j] = *(const bf16x8*)(Wb2 + (size_t)(j * 96 + c * 24 + (ks >> 3) + quad) * 128);
            #pragma unroll
            for (int i = 0; i < 4; ++i)
                #pragma unroll
                for (int j = 0; j < 2; ++j)
                    acc2[i][j] = __builtin_amdgcn_mfma_f32_16x16x32_bf16(wv2[j], af2[i], acc2[i][j], 0, 0, 0);
        }
        __syncthreads();
    }

    // ---- epilogue: stage [32 tok][32 outs] per pass, write NCHW with
    //      full 128-B-granule runs (64-token-consecutive per channel). ----
    float* Cw = (float*)(smem + wave * 4608);      // [32][36] f32, overlay
    float4 b2j[2];
    #pragma unroll
    for (int j = 0; j < 2; ++j)
        b2j[j] = *(const float4*)&fc2_b[ow * 32 + 16 * j + quad * 4];
    #pragma unroll
    for (int p = 0; p < 2; ++p) {
        #pragma unroll
        for (int ih = 0; ih < 2; ++ih) {
            const int i = 2 * p + ih;
            #pragma unroll
            for (int j = 0; j < 2; ++j) {
                f32x4 v = acc2[i][j];
                v[0] += b2j[j].x; v[1] += b2j[j].y; v[2] += b2j[j].z; v[3] += b2j[j].w;
                *(f32x4*)&Cw[(ih * 16 + m16) * 36 + 16 * j + quad * 4] = v;
            }
        }
        #pragma unroll
        for (int q = 0; q < 4; ++q) {
            const int idx = q * 64 + lane;
            const int cc = idx >> 3, t4 = (idx & 7) * 4;
            const int o  = ow * 32 + cc;
            const int tb = t0 + half * 64 + p * 32 + t4;
            float4 vv;
            vv.x = Cw[(t4 + 0) * 36 + cc] + x2[(size_t)(tb + 0) * DIM + o];
            vv.y = Cw[(t4 + 1) * 36 + cc] + x2[(size_t)(tb + 1) * DIM + o];
            vv.z = Cw[(t4 + 2) * 36 + cc] + x2[(size_t)(tb + 2) * DIM + o];
            vv.w = Cw[(t4 + 3) * 36 + cc] + x2[(size_t)(tb + 3) * DIM + o];
            *(float4*)&outp[(size_t)b * (DIM * 4096) + (size_t)o * 4096
                            + hw0 + half * 64 + p * 32 + t4] = vv;
        }
    }
}

// ---------------------------------------------------------------------------
extern "C" void kernel_launch(void* const* d_in, const int* in_sizes, int n_in,
                              void* d_out, int out_size, void* d_ws, size_t ws_size,
                              hipStream_t stream)
{
    const float* x        = (const float*)d_in[0];
    const float* norm1_g  = (const float*)d_in[1];
    const float* norm1_b  = (const float*)d_in[2];
    const float* qkv_w    = (const float*)d_in[3];
    const float* qkv_b    = (const float*)d_in[4];
    const float* proj_w   = (const float*)d_in[5];
    const float* proj_b   = (const float*)d_in[6];
    const float* rpbt     = (const float*)d_in[7];
    const float* temp     = (const float*)d_in[8];
    const float* norm2_g  = (const float*)d_in[9];
    const float* norm2_b  = (const float*)d_in[10];
    const float* fc1_w    = (const float*)d_in[11];
    const float* fc1_b    = (const float*)d_in[12];
    const float* fc2_w    = (const float*)d_in[13];
    const float* fc2_b    = (const float*)d_in[14];
    float* out = (float*)d_out;

    // ws layout (bytes):
    //   [0,        12582912)  shortcut bf16 (LN1 out)
    //   [12582912, 37748736)  x2 f32
    //   [125829120,...)       weights bf16 (fragment order; qkv Q/K permuted)
    char* wsb = (char*)d_ws;
    ushort_t* shortcut_h = (ushort_t*)wsb;
    float*    x2         = (float*)(wsb + 12582912);
    ushort_t* wq  = (ushort_t*)(wsb + 125829120);      // 576x192 = 110592
    ushort_t* wp  = wq + 110592;                       // 192x192 = 36864
    ushort_t* w1  = wp + 36864;                        // 768x192 = 147456
    ushort_t* w2  = w1 + 147456;                       // 192x768 = 147456

    // 0+1. merged weight conversion (432 blocks) + LN1 transpose (512 blocks)
    hipLaunchKernelGGL(prep_kernel, dim3(432 + TTOT / 64), dim3(256), 0, stream,
                       qkv_w, proj_w, fc1_w, fc2_w, wq, wp, w1, w2,
                       x, norm1_g, norm1_b, shortcut_h);
    // 2. fused qkv + attention + proj + residual -> x2 (2 windows/block)
    hipLaunchKernelGGL(attn_fused, dim3(NWIN / 2), dim3(768), 0, stream,
                       shortcut_h, wq, qkv_b, rpbt, temp, wp, proj_b, x2);
    // 3. fused LN2 + fc1 + GELU + fc2 + residual + NCHW transpose
    hipLaunchKernelGGL(mlp_fused, dim3(TTOT / 128), dim3(768), 0, stream,
                       x2, w1, w2, fc1_b, fc2_b, norm2_g, norm2_b, out);
}